// Round 1
// baseline (1322.103 us; speedup 1.0000x reference)
//
#include <hip/hip_runtime.h>

#define INF30 1e30f
#define INV_TAU 0.08838834764831845f

typedef unsigned short ushort_t;
typedef __attribute__((ext_vector_type(8))) short bf16x8;
typedef __attribute__((ext_vector_type(4))) float f32x4;
typedef __attribute__((ext_vector_type(8))) unsigned short us8;

__device__ __forceinline__ float4 ld4(const float* p) { return *(const float4*)p; }

__device__ __forceinline__ unsigned short bf16_rne(float x) {
    unsigned int u = __float_as_uint(x);
    unsigned int r = u + 0x7fffu + ((u >> 16) & 1u);
    return (unsigned short)(r >> 16);
}
__device__ __forceinline__ float bf16_tof(unsigned short h) {
    return __uint_as_float(((unsigned int)h) << 16);
}
__device__ __forceinline__ bf16x8 ldb8(const ushort_t* p) { return *(const bf16x8*)p; }

#define MFMA16(a, b, c) __builtin_amdgcn_mfma_f32_16x16x32_bf16((a), (b), (c), 0, 0, 0)

// ---------------- LayerNorm over DM=1024 ----------------
__global__ __launch_bounds__(256) void ln_dm_kernel(const float* __restrict__ x, float* __restrict__ y) {
    size_t row = blockIdx.x;
    const float4* xr = (const float4*)(x + row * 1024);
    float4 v = xr[threadIdx.x];
    float s  = v.x + v.y + v.z + v.w;
    float ss = v.x*v.x + v.y*v.y + v.z*v.z + v.w*v.w;
#pragma unroll
    for (int off = 32; off > 0; off >>= 1) {
        s  += __shfl_down(s, off);
        ss += __shfl_down(ss, off);
    }
    __shared__ float rs[4], rss[4];
    int wv = threadIdx.x >> 6, ln = threadIdx.x & 63;
    if (ln == 0) { rs[wv] = s; rss[wv] = ss; }
    __syncthreads();
    s  = rs[0] + rs[1] + rs[2] + rs[3];
    ss = rss[0] + rss[1] + rss[2] + rss[3];
    float mu  = s * (1.0f/1024.0f);
    float var = ss * (1.0f/1024.0f) - mu*mu;
    float r = rsqrtf(var + 1e-6f);
    float4 o;
    o.x = (v.x - mu) * r; o.y = (v.y - mu) * r; o.z = (v.z - mu) * r; o.w = (v.w - mu) * r;
    ((float4*)(y + row * 1024))[threadIdx.x] = o;
}

// ---------------- fp32 tiled GEMM (k-columns only: argmin-critical path) ----------------
__global__ __launch_bounds__(256) void gemm_kernel(const float* __restrict__ A, const float* __restrict__ W,
                                                   int N, int mode,
                                                   float* __restrict__ o0, float* __restrict__ o1,
                                                   float* __restrict__ o2) {
    __shared__ float As[16][64];
    __shared__ float Bs[16][64];
    int t = threadIdx.x;
    int col0 = blockIdx.x << 6;
    int row0 = blockIdx.y << 6;
    int tx = t & 15, ty = t >> 4;
    int arow = t >> 2, akq = t & 3;
    int bkr = t >> 4, bcq = t & 15;
    const float* Ap = A + (size_t)(row0 + arow) * 1024 + akq * 4;
    const float* Wp = W + (size_t)bkr * N + col0 + bcq * 4;
    float acc[4][4];
#pragma unroll
    for (int i = 0; i < 4; ++i)
#pragma unroll
        for (int j = 0; j < 4; ++j) acc[i][j] = 0.0f;

    for (int kt = 0; kt < 64; ++kt) {
        float4 a4 = ld4(Ap + kt * 16);
        float4 b4 = ld4(Wp + (size_t)kt * 16 * N);
        __syncthreads();
        As[akq*4+0][arow] = a4.x;
        As[akq*4+1][arow] = a4.y;
        As[akq*4+2][arow] = a4.z;
        As[akq*4+3][arow] = a4.w;
        *(float4*)&Bs[bkr][bcq*4] = b4;
        __syncthreads();
#pragma unroll
        for (int kk = 0; kk < 16; ++kk) {
            float4 av = *(float4*)&As[kk][ty*4];
            float4 bv = *(float4*)&Bs[kk][tx*4];
            acc[0][0] += av.x*bv.x; acc[0][1] += av.x*bv.y; acc[0][2] += av.x*bv.z; acc[0][3] += av.x*bv.w;
            acc[1][0] += av.y*bv.x; acc[1][1] += av.y*bv.y; acc[1][2] += av.y*bv.z; acc[1][3] += av.y*bv.w;
            acc[2][0] += av.z*bv.x; acc[2][1] += av.z*bv.y; acc[2][2] += av.z*bv.z; acc[2][3] += av.z*bv.w;
            acc[3][0] += av.w*bv.x; acc[3][1] += av.w*bv.y; acc[3][2] += av.w*bv.z; acc[3][3] += av.w*bv.w;
        }
    }

#pragma unroll
    for (int i = 0; i < 4; ++i) {
        int rr = row0 + ty*4 + i;
        int b = rr >> 9, l = rr & 511;
#pragma unroll
        for (int j = 0; j < 4; ++j) {
            int cc = col0 + tx*4 + j;
            float vv = acc[i][j];
            if (mode == 0) {
                o0[((size_t)((b<<3) + (cc>>7)) * 512 + l) * 128 + (cc & 127)] = vv;
            } else if (mode == 1) {
                if (cc < 1024) {
                    o0[((size_t)((b<<3) + (cc>>7)) * 512 + l) * 128 + (cc & 127)] = vv;
                } else if (cc < 2048) {
                    int c2 = cc - 1024;
                    o1[((size_t)((b<<3) + (c2>>7)) * 512 + l) * 128 + (c2 & 127)] = vv;
                } else {
                    o2[(size_t)rr * 1024 + (cc - 2048)] = vv / (1.0f + __expf(-vv));
                }
            } else {
                o0[(size_t)rr * 1024 + cc] = vv;
            }
        }
    }
}

// ---------------- weight transpose + bf16 hi/lo split ----------------
__global__ __launch_bounds__(256) void wtsplit_kernel(const float* __restrict__ W, int Ntot, int c0,
                                                      ushort_t* __restrict__ th, ushort_t* __restrict__ tl) {
    __shared__ float T[64][68];
    int n0 = blockIdx.x << 6, k0 = blockIdx.y << 6, t = threadIdx.x;
    for (int i = t; i < 1024; i += 256) {
        int kk = i >> 4, nn4 = (i & 15) << 2;
        *(float4*)&T[kk][nn4] = ld4(W + (size_t)(k0 + kk) * Ntot + c0 + n0 + nn4);
    }
    __syncthreads();
    for (int i = t; i < 512; i += 256) {
        int nn = i >> 3, kc = (i & 7) << 3;
        us8 h8, l8;
#pragma unroll
        for (int j = 0; j < 8; ++j) {
            float x = T[kc + j][nn];
            unsigned short hh = bf16_rne(x);
            h8[j] = hh; l8[j] = bf16_rne(x - bf16_tof(hh));
        }
        size_t off = (size_t)(n0 + nn) * 1024 + k0 + kc;
        *(us8*)(th + off) = h8;
        *(us8*)(tl + off) = l8;
    }
}

// ---------------- bf16 3-term split GEMM ----------------
#define GSTRIDE 40
__global__ __launch_bounds__(256) void gemm_bf16_kernel(
        const ushort_t* __restrict__ Ah, const ushort_t* __restrict__ Al,
        const ushort_t* __restrict__ Bth, const ushort_t* __restrict__ Btl,
        int mode, float* __restrict__ o0, float* __restrict__ o1) {
    __shared__ ushort_t LA[2][128 * GSTRIDE];
    __shared__ ushort_t LB[2][128 * GSTRIDE];
    int t = threadIdx.x;
    int col0 = blockIdx.x << 7, row0 = blockIdx.y << 7;
    int wvid = t >> 6, ln = t & 63;
    int lcol = ln & 15, quad = ln >> 4;
    int qm = wvid >> 1, qn = wvid & 1;

    f32x4 C[4][4];
#pragma unroll
    for (int i = 0; i < 4; ++i)
#pragma unroll
        for (int j = 0; j < 4; ++j) C[i][j] = (f32x4){0.f, 0.f, 0.f, 0.f};

    for (int k0 = 0; k0 < 1024; k0 += 32) {
        us8 ra[2][2], rb[2][2];
#pragma unroll
        for (int v = 0; v < 2; ++v) {
            int cid = t + 256 * v;
            int row = cid >> 2, ch = cid & 3;
            size_t ga = (size_t)(row0 + row) * 1024 + k0 + ch * 8;
            size_t gb = (size_t)(col0 + row) * 1024 + k0 + ch * 8;
            ra[v][0] = *(const us8*)(Ah + ga);
            ra[v][1] = *(const us8*)(Al + ga);
            rb[v][0] = *(const us8*)(Bth + gb);
            rb[v][1] = *(const us8*)(Btl + gb);
        }
        __syncthreads();
#pragma unroll
        for (int v = 0; v < 2; ++v) {
            int cid = t + 256 * v;
            int row = cid >> 2, ch = cid & 3;
            *(us8*)&LA[0][row * GSTRIDE + ch * 8] = ra[v][0];
            *(us8*)&LA[1][row * GSTRIDE + ch * 8] = ra[v][1];
            *(us8*)&LB[0][row * GSTRIDE + ch * 8] = rb[v][0];
            *(us8*)&LB[1][row * GSTRIDE + ch * 8] = rb[v][1];
        }
        __syncthreads();
        bf16x8 afh[4], afl[4], bfh[4], bfl[4];
#pragma unroll
        for (int i = 0; i < 4; ++i) {
            int r = qm * 64 + i * 16 + lcol;
            afh[i] = *(const bf16x8*)&LA[0][r * GSTRIDE + quad * 8];
            afl[i] = *(const bf16x8*)&LA[1][r * GSTRIDE + quad * 8];
            int c = qn * 64 + i * 16 + lcol;
            bfh[i] = *(const bf16x8*)&LB[0][c * GSTRIDE + quad * 8];
            bfl[i] = *(const bf16x8*)&LB[1][c * GSTRIDE + quad * 8];
        }
#pragma unroll
        for (int i = 0; i < 4; ++i)
#pragma unroll
            for (int j = 0; j < 4; ++j) {
                C[i][j] = MFMA16(afh[i], bfh[j], C[i][j]);
                C[i][j] = MFMA16(afl[i], bfh[j], C[i][j]);
                C[i][j] = MFMA16(afh[i], bfl[j], C[i][j]);
            }
    }

#pragma unroll
    for (int i = 0; i < 4; ++i) {
#pragma unroll
        for (int r = 0; r < 4; ++r) {
            int rr = row0 + qm * 64 + 16 * i + quad * 4 + r;
            int b = rr >> 9, l = rr & 511;
#pragma unroll
            for (int j = 0; j < 4; ++j) {
                int cc = col0 + qn * 64 + 16 * j + lcol;
                float vv = C[i][j][r];
                if (mode == 0) {
                    o0[((size_t)((b<<3) + (cc>>7)) * 512 + l) * 128 + (cc & 127)] = vv;
                } else if (mode == 1) {
                    if (cc < 1024) o0[((size_t)((b<<3) + (cc>>7)) * 512 + l) * 128 + (cc & 127)] = vv;
                    else o1[(size_t)rr * 1024 + (cc - 1024)] = vv / (1.0f + __expf(-vv));
                } else {
                    o0[(size_t)rr * 1024 + cc] = vv;
                }
            }
        }
    }
}

// ---------------- LayerNorm over last dim 128 for q and k, in place ----------------
__global__ __launch_bounds__(256) void ln128_kernel(float* __restrict__ qb, float* __restrict__ kb) {
    int wv = threadIdx.x >> 6, ln = threadIdx.x & 63;
    int gw = (blockIdx.x << 2) + wv;
    float* base = (gw < 32768) ? qb : kb;
    int row = gw & 32767;
    float2 x = *(float2*)(base + (size_t)row * 128 + (ln << 1));
    float s  = x.x + x.y;
    float ss = x.x*x.x + x.y*x.y;
#pragma unroll
    for (int m = 32; m > 0; m >>= 1) { s += __shfl_xor(s, m); ss += __shfl_xor(ss, m); }
    float mu  = s * (1.0f/128.0f);
    float var = ss * (1.0f/128.0f) - mu*mu;
    float r = rsqrtf(var + 1e-6f);
    x.x = (x.x - mu) * r; x.y = (x.y - mu) * r;
    *(float2*)(base + (size_t)row * 128 + (ln << 1)) = x;
}

// ---------------- codebook transpose + norms ----------------
__global__ __launch_bounds__(256) void cbt_kernel(const float* __restrict__ cb, float* __restrict__ cT) {
    int idx = blockIdx.x * 256 + threadIdx.x;
    int h = idx >> 16, s = (idx >> 7) & 511, d = idx & 127;
    cT[((size_t)((h << 7) + d)) * 512 + s] = cb[idx];
}

__global__ __launch_bounds__(256) void cnorm_kernel(const float* __restrict__ cb, float* __restrict__ cn) {
    int wv = threadIdx.x >> 6, ln = threadIdx.x & 63;
    int row = (blockIdx.x << 2) + wv;
    float2 x = *(const float2*)(cb + (size_t)row * 128 + (ln << 1));
    float ss = x.x*x.x + x.y*x.y;
#pragma unroll
    for (int m = 32; m > 0; m >>= 1) ss += __shfl_xor(ss, m);
    if (ln == 0) cn[row] = ss;
}

// ---------------- VQ argmin (fp32) ----------------
__global__ __launch_bounds__(256) void vq_kernel(float* __restrict__ kb, const float* __restrict__ cT,
                                                 const float* __restrict__ cn, const float* __restrict__ cb) {
    __shared__ float sK[4][4][128];
    int wv = threadIdx.x >> 6, ln = threadIdx.x & 63;
    int gw = (blockIdx.x << 2) + wv;
    int bh = gw >> 7;
    int l4 = (gw & 127) << 2;
    int h = bh & 7;
    size_t r0 = ((size_t)bh << 9) + l4;
#pragma unroll
    for (int i = 0; i < 4; ++i) {
        float2 kx = *(const float2*)(kb + (r0 + i) * 128 + (ln << 1));
        sK[wv][i][(ln<<1)]   = kx.x;
        sK[wv][i][(ln<<1)+1] = kx.y;
    }
    __syncthreads();
    const float* ct = cT + ((size_t)h << 7) * 512;
    int s0 = ln << 3;
    float dt[4][8];
#pragma unroll
    for (int i = 0; i < 4; ++i)
#pragma unroll
        for (int j = 0; j < 8; ++j) dt[i][j] = 0.0f;

    for (int dc = 0; dc < 4; ++dc) {
        float ch[4][8];
#pragma unroll
        for (int i = 0; i < 4; ++i)
#pragma unroll
            for (int j = 0; j < 8; ++j) ch[i][j] = 0.0f;
#pragma unroll 4
        for (int d = dc * 32; d < dc * 32 + 32; ++d) {
            float4 c0 = ld4(ct + (size_t)d * 512 + s0);
            float4 c1 = ld4(ct + (size_t)d * 512 + s0 + 4);
#pragma unroll
            for (int i = 0; i < 4; ++i) {
                float kd = sK[wv][i][d];
                ch[i][0] += kd * c0.x; ch[i][1] += kd * c0.y; ch[i][2] += kd * c0.z; ch[i][3] += kd * c0.w;
                ch[i][4] += kd * c1.x; ch[i][5] += kd * c1.y; ch[i][6] += kd * c1.z; ch[i][7] += kd * c1.w;
            }
        }
#pragma unroll
        for (int i = 0; i < 4; ++i)
#pragma unroll
            for (int j = 0; j < 8; ++j) dt[i][j] += ch[i][j];
    }
    const float* cnh = cn + (h << 9);
#pragma unroll
    for (int i = 0; i < 4; ++i) {
        float bestv = cnh[s0] - 2.0f * dt[i][0];
        int bestz = s0;
#pragma unroll
        for (int j = 1; j < 8; ++j) {
            float scv = cnh[s0 + j] - 2.0f * dt[i][j];
            if (scv < bestv) { bestv = scv; bestz = s0 + j; }
        }
#pragma unroll
        for (int m = 32; m > 0; m >>= 1) {
            float ov = __shfl_xor(bestv, m);
            int   oz = __shfl_xor(bestz, m);
            if (ov < bestv || (ov == bestv && oz < bestz)) { bestv = ov; bestz = oz; }
        }
        float2 cz = *(const float2*)(cb + ((size_t)(h << 9) + bestz) * 128 + (ln << 1));
        *(float2*)(kb + (r0 + i) * 128 + (ln << 1)) = cz;
    }
}

// ---------------- prep kernels ----------------
__global__ __launch_bounds__(256) void split_q_kernel(const float* __restrict__ q,
        const float* __restrict__ xu, const float* __restrict__ xv,
        ushort_t* __restrict__ quh, ushort_t* __restrict__ qul,
        ushort_t* __restrict__ qvh) {
    int idx = blockIdx.x * 256 + threadIdx.x;
    int d = idx & 127;
    int h = (idx >> 16) & 7;
    float qv = q[idx];
    float a = qv + xu[(h << 7) + d];
    unsigned short ah = bf16_rne(a);
    quh[idx] = ah; qul[idx] = bf16_rne(a - bf16_tof(ah));
    float b = qv + xv[(h << 7) + d];
    qvh[idx] = bf16_rne(b);
}

__global__ __launch_bounds__(256) void split_plain_kernel(const float* __restrict__ src,
        ushort_t* __restrict__ hi, ushort_t* __restrict__ lo) {
    int idx = blockIdx.x * 256 + threadIdx.x;
    float x = src[idx];
    unsigned short h = bf16_rne(x);
    hi[idx] = h; lo[idx] = bf16_rne(x - bf16_tof(h));
}

__global__ __launch_bounds__(256) void cvt_hi_kernel(const float* __restrict__ src,
        ushort_t* __restrict__ hi) {
    int idx = blockIdx.x * 256 + threadIdx.x;
    hi[idx] = bf16_rne(src[idx]);
}

__global__ __launch_bounds__(256) void split_koff_kernel(const float* __restrict__ src,
        ushort_t* __restrict__ hi, ushort_t* __restrict__ lo, int rowoff) {
    int idx = blockIdx.x * 256 + threadIdx.x;
    int bh = idx >> 16, rem = idx & 65535;
    size_t dst = ((size_t)bh << 17) + ((size_t)rowoff << 7) + rem;
    float x = src[idx];
    unsigned short h = bf16_rne(x);
    hi[dst] = h; lo[dst] = bf16_rne(x - bf16_tof(h));
}

__global__ __launch_bounds__(256) void vtsplit_kernel(const float* __restrict__ srcA,
        const float* __restrict__ srcB, ushort_t* __restrict__ hi, ushort_t* __restrict__ lo, int NK) {
    __shared__ float T[64][132];
    int bh = blockIdx.x, kt = blockIdx.y, t = threadIdx.x;
    for (int i = t; i < 2048; i += 256) {
        int r = i >> 5, c4 = (i & 31) << 2;
        int key = (kt << 6) + r;
        const float* s = (key < 512) ? (srcA + ((size_t)bh * 512 + key) * 128 + c4)
                                     : (srcB + ((size_t)bh * 512 + (key - 512)) * 128 + c4);
        *(float4*)&T[r][c4] = ld4(s);
    }
    __syncthreads();
    for (int i = t; i < 1024; i += 256) {
        int vc = i >> 3, kk = (i & 7) << 3;
        us8 h8, l8;
#pragma unroll
        for (int j = 0; j < 8; ++j) {
            float x = T[kk + j][vc];
            unsigned short hh = bf16_rne(x);
            h8[j] = hh; l8[j] = bf16_rne(x - bf16_tof(hh));
        }
        size_t off = ((size_t)bh * 128 + vc) * NK + (kt << 6) + kk;
        *(us8*)(hi + off) = h8;
        *(us8*)(lo + off) = l8;
    }
}

__global__ __launch_bounds__(256) void cbias_kernel(const float* __restrict__ al, float* __restrict__ cb) {
    int idx = blockIdx.x * 256 + threadIdx.x;
    float v = al[idx];
    cb[idx] = (v > 0.0f) ? __logf(fmaxf(v, 1e-30f)) : -INF30;
}

// ---------------- attn6: XCD-swizzled, one q-tile-pair per block, split-K-4 ----------------
// 1024 blocks x 4 waves. bh = 8*(idx>>4) + (blk&7) pins all 16 blocks of a bh to one XCD.
// Each block owns pair {j, 31-j}; weighted total work W = 64 + nt2A + nt2B == 81 for EVERY
// pair (nt2A+nt2B == 17), so split-K-4 boundaries are static: ti in [0,10)/[10,20)/[20,30)/
// [30,Tt) with weights 20/20/20/21 (iters with both tiles active count double).
// LDS: combine buffer Oc (33.8 KB, post-loop only) unions with P buffers (20.5 KB, in-loop
// only) -> 34.3 KB/block -> 4 blocks/CU (was 2). Combine is 2-stage: waves 1,3 -> 0,2; 2 -> 0.
#define PSTR 40
__global__ __launch_bounds__(256, 4) void attn6_kernel(
        const ushort_t* __restrict__ Qu_hi, const ushort_t* __restrict__ Qu_lo,
        const ushort_t* __restrict__ Qv_hi,
        const ushort_t* __restrict__ K_hi,  const ushort_t* __restrict__ K_lo,
        const ushort_t* __restrict__ C_hi,  const ushort_t* __restrict__ C_lo,
        const ushort_t* __restrict__ Vt_hi, const ushort_t* __restrict__ Vt_lo,
        const ushort_t* __restrict__ At_hi, const ushort_t* __restrict__ At_lo,
        const ushort_t* __restrict__ R_hi,
        const float* __restrict__ cbias, const float* __restrict__ gbuf,
        float* __restrict__ wvg) {
    // union layout: [0,20480) Phs+Pls (loop) / [0,33792) Oc (combine); [33792,34304) mc,lc
    __shared__ __align__(16) unsigned char smem[33792 + 512];
    typedef ushort_t PBuf[2][16 * PSTR];
    PBuf* Phs = (PBuf*)smem;                              // 4 x 2 x 640 ushort = 10240 B
    PBuf* Pls = (PBuf*)(smem + 10240);                    // 10240 B
    float (*Oc)[16 * 132] = (float (*)[16 * 132])smem;    // 4 x 2112 f32 = 33792 B (overlaps P)
    float* mc = (float*)(smem + 33792);                   // [4][16]
    float* lc = mc + 64;                                  // [4][16]

    int t = threadIdx.x;
    int wvid = t >> 6, ln = t & 63;
    int col = ln & 15, quad = ln >> 4;
    int blk = blockIdx.x;
    int xcd = blk & 7, idx = blk >> 3;
    int bh = ((idx >> 4) << 3) + xcd;
    int pairj = idx & 15;
    int q = wvid;                    // split-K-4 lane
    int l0[2];
    l0[0] = pairj << 4;
    l0[1] = (31 - pairj) << 4;
    int h = bh & 7, b = bh >> 3;

    // persistent Qu A-frags for both tiles
    bf16x8 quh[2][4], qul[2][4];
#pragma unroll
    for (int tt = 0; tt < 2; ++tt) {
        size_t base = ((size_t)bh * 512 + l0[tt] + col) * 128 + quad * 8;
#pragma unroll
        for (int s = 0; s < 4; ++s) {
            quh[tt][s] = ldb8(Qu_hi + base + 32 * s);
            qul[tt][s] = ldb8(Qu_lo + base + 32 * s);
        }
    }

    f32x4 O[2][8];
#pragma unroll
    for (int tt = 0; tt < 2; ++tt)
#pragma unroll
        for (int u = 0; u < 8; ++u) O[tt][u] = (f32x4){0.f, 0.f, 0.f, 0.f};
    float mrun[2][4], lrun[2][4];
#pragma unroll
    for (int tt = 0; tt < 2; ++tt)
#pragma unroll
        for (int r = 0; r < 4; ++r) { mrun[tt][r] = -INF30; lrun[tt][r] = 0.0f; }

    int nt2A = (l0[0] + 47) >> 5;
    int nt2B = (l0[1] + 47) >> 5;
    int Tt = 32 + nt2B;
    int ti0 = q * 10;
    int ti1 = (q == 3) ? Tt : (q + 1) * 10;

    for (int ti = ti0; ti < ti1; ++ti) {
        int seg, w0;
        if (ti < 16)      { seg = 0; w0 = ti << 5; }
        else if (ti < 32) { seg = 1; w0 = (ti - 16) << 5; }
        else              { seg = 2; w0 = (ti - 32) << 5; }
        bool actA = (seg != 2) || ((ti - 32) < nt2A);

        // ---- rel G tiles in registers (seg 0/2); qv frags reloaded from L2 ----
        f32x4 Gacc[2][3];
        if (seg != 1) {
#pragma unroll
            for (int tt = 0; tt < 2; ++tt) {
                if (tt == 0 && !actA) continue;
                size_t qb_ = ((size_t)bh * 512 + l0[tt] + col) * 128 + quad * 8;
                bf16x8 qv0 = ldb8(Qv_hi + qb_);
                bf16x8 qv1 = ldb8(Qv_hi + qb_ + 32);
                bf16x8 qv2 = ldb8(Qv_hi + qb_ + 64);
                bf16x8 qv3 = ldb8(Qv_hi + qb_ + 96);
                int jt0 = ((seg == 0) ? w0 : (512 + w0)) + 496 - l0[tt];
#pragma unroll
                for (int u = 0; u < 3; ++u) {
                    int j = jt0 + 16 * u + col;
                    j = (j > 1023) ? 1023 : j;
                    const ushort_t* rp = R_hi + ((size_t)(h << 10) + j) * 128 + quad * 8;
                    f32x4 acc = (f32x4){0.f, 0.f, 0.f, 0.f};
                    acc = MFMA16(qv0, ldb8(rp), acc);
                    acc = MFMA16(qv1, ldb8(rp + 32), acc);
                    acc = MFMA16(qv2, ldb8(rp + 64), acc);
                    acc = MFMA16(qv3, ldb8(rp + 96), acc);
                    Gacc[tt][u] = acc;
                }
            }
        }

        // ---- shared K frags + scores for both tiles ----
        const ushort_t *khb, *klb;
        if (seg == 0)      { khb = K_hi + ((size_t)bh * 1024 + w0) * 128;
                             klb = K_lo + ((size_t)bh * 1024 + w0) * 128; }
        else if (seg == 1) { khb = C_hi + ((size_t)(h << 9) + w0) * 128;
                             klb = C_lo + ((size_t)(h << 9) + w0) * 128; }
        else               { khb = K_hi + ((size_t)bh * 1024 + 512 + w0) * 128;
                             klb = K_lo + ((size_t)bh * 1024 + 512 + w0) * 128; }
        f32x4 S[2][2];
#pragma unroll
        for (int t2 = 0; t2 < 2; ++t2) {
            const ushort_t* kph = khb + (size_t)(16 * t2 + col) * 128 + quad * 8;
            const ushort_t* kpl = klb + (size_t)(16 * t2 + col) * 128 + quad * 8;
            bf16x8 bhf[4], blf[4];
#pragma unroll
            for (int s = 0; s < 4; ++s) { bhf[s] = ldb8(kph + 32 * s); blf[s] = ldb8(kpl + 32 * s); }
#pragma unroll
            for (int tt = 0; tt < 2; ++tt) {
                if (tt == 0 && !actA) continue;
                f32x4 acc = (f32x4){0.f, 0.f, 0.f, 0.f};
#pragma unroll
                for (int s = 0; s < 4; ++s) {
                    acc = MFMA16(quh[tt][s], bhf[s], acc);
                    acc = MFMA16(qul[tt][s], bhf[s], acc);
                    acc = MFMA16(quh[tt][s], blf[s], acc);
                }
                S[tt][t2] = acc;
            }
        }

        // ---- fixup + online softmax + P frags per tile ----
        float bias0 = 0.f, bias1 = 0.f;
        if (seg == 1) {
            bias0 = cbias[(size_t)(bh << 9) + w0 + col];
            bias1 = cbias[(size_t)(bh << 9) + w0 + 16 + col];
        }
        bf16x8 pah[2], pal[2];
#pragma unroll
        for (int tt = 0; tt < 2; ++tt) {
            if (tt == 0 && !actA) continue;
            ushort_t* Ph = Phs[wvid][tt];
            ushort_t* Pl = Pls[wvid][tt];
#pragma unroll
            for (int t2 = 0; t2 < 2; ++t2) {
#pragma unroll
                for (int r = 0; r < 4; ++r) {
                    int row = 4 * quad + r;
                    float sv = S[tt][t2][r];
                    if (seg != 1) {
                        int d = col + 15 - row;
                        int src = quad * 16 + (d & 15);
                        float g0 = __shfl(Gacc[tt][t2][r], src);
                        float g1 = __shfl(Gacc[tt][t2 + 1][r], src);
                        float gv = (d >= 16) ? g1 : g0;
                        sv = (sv + gv) * INV_TAU;
                        if (seg == 2 && (w0 + 16 * t2 + col > l0[tt] + row)) sv = -INF30;
                    } else {
                        sv = sv * INV_TAU + ((t2 == 0) ? bias0 : bias1);
                    }
                    S[tt][t2][r] = sv;
                }
            }
#pragma unroll
            for (int r = 0; r < 4; ++r) {
                float mv = fmaxf(S[tt][0][r], S[tt][1][r]);
#pragma unroll
                for (int m = 8; m > 0; m >>= 1) mv = fmaxf(mv, __shfl_xor(mv, m));
                float mnew = fmaxf(mrun[tt][r], mv);
                float alpha = __expf(mrun[tt][r] - mnew);
                mrun[tt][r] = mnew;
                float p0 = __expf(S[tt][0][r] - mnew);
                float p1 = __expf(S[tt][1][r] - mnew);
                float ps = p0 + p1;
#pragma unroll
                for (int m = 8; m > 0; m >>= 1) ps += __shfl_xor(ps, m);
                lrun[tt][r] = lrun[tt][r] * alpha + ps;
#pragma unroll
                for (int u = 0; u < 8; ++u) O[tt][u][r] *= alpha;
                int row = 4 * quad + r;
                unsigned short h0 = bf16_rne(p0);
                Ph[row * PSTR + col] = h0;
                Pl[row * PSTR + col] = bf16_rne(p0 - bf16_tof(h0));
                unsigned short h1 = bf16_rne(p1);
                Ph[row * PSTR + 16 + col] = h1;
                Pl[row * PSTR + 16 + col] = bf16_rne(p1 - bf16_tof(h1));
            }
            pah[tt] = *(const bf16x8*)&Ph[col * PSTR + quad * 8];
            pal[tt] = *(const bf16x8*)&Pl[col * PSTR + quad * 8];
        }

        // ---- PV with shared V frags ----
        const ushort_t *vh, *vl;
        size_t vstr;
        int wbase;
        if (seg == 0)      { vh = Vt_hi + ((size_t)bh << 17); vl = Vt_lo + ((size_t)bh << 17); vstr = 1024; wbase = w0; }
        else if (seg == 1) { vh = At_hi + ((size_t)bh << 16); vl = At_lo + ((size_t)bh << 16); vstr = 512;  wbase = w0; }
        else               { vh = Vt_hi + ((size_t)bh << 17); vl = Vt_lo + ((size_t)bh << 17); vstr = 1024; wbase = 512 + w0; }
#pragma unroll
        for (int u = 0; u < 8; ++u) {
            int vcol = 16 * u + col;
            bf16x8 vbh = ldb8(vh + (size_t)vcol * vstr + wbase + quad * 8);
            bf16x8 vbl = ldb8(vl + (size_t)vcol * vstr + wbase + quad * 8);
#pragma unroll
            for (int tt = 0; tt < 2; ++tt) {
                if (tt == 0 && !actA) continue;
                O[tt][u] = MFMA16(pah[tt], vbh, O[tt][u]);
                O[tt][u] = MFMA16(pal[tt], vbh, O[tt][u]);
                O[tt][u] = MFMA16(pah[tt], vbl, O[tt][u]);
            }
        }
    }

    // ---- split-K-4 combine, 2-stage (P buffers dead from here; Oc overlays them) ----
    __syncthreads();
    if (q & 1) {   // waves 1,3 publish partials: q=1 -> slots 0,1 ; q=3 -> slots 2,3
#pragma unroll
        for (int tt = 0; tt < 2; ++tt) {
            int sid = ((q >> 1) << 1) | tt;
#pragma unroll
            for (int u = 0; u < 8; ++u)
#pragma unroll
                for (int r = 0; r < 4; ++r)
                    Oc[sid][(quad * 4 + r) * 132 + 16 * u + col] = O[tt][u][r];
            if (col == 0) {
#pragma unroll
                for (int r = 0; r < 4; ++r) {
                    mc[sid * 16 + quad * 4 + r] = mrun[tt][r];
                    lc[sid * 16 + quad * 4 + r] = lrun[tt][r];
                }
            }
        }
    }
    __syncthreads();
    if (!(q & 1)) { // waves 0,2 merge: q=0 reads slots 0,1 ; q=2 reads slots 2,3
#pragma unroll
        for (int tt = 0; tt < 2; ++tt) {
            int sid = q | tt;
#pragma unroll
            for (int r = 0; r < 4; ++r) {
                int row = quad * 4 + r;
                float m1 = mc[sid * 16 + row], l1 = lc[sid * 16 + row];
                float mm = fmaxf(mrun[tt][r], m1);
                float a0 = __expf(mrun[tt][r] - mm);
                float a1 = __expf(m1 - mm);
                mrun[tt][r] = mm;
                lrun[tt][r] = lrun[tt][r] * a0 + l1 * a1;
#pragma unroll
                for (int u = 0; u < 8; ++u)
                    O[tt][u][r] = O[tt][u][r] * a0 + Oc[sid][row * 132 + 16 * u + col] * a1;
            }
        }
    }
    if (q == 2) {   // wave 2 republishes its merged half into slots 2,3
#pragma unroll
        for (int tt = 0; tt < 2; ++tt) {
            int sid = 2 | tt;
#pragma unroll
            for (int u = 0; u < 8; ++u)
#pragma unroll
                for (int r = 0; r < 4; ++r)
                    Oc[sid][(quad * 4 + r) * 132 + 16 * u + col] = O[tt][u][r];
            if (col == 0) {
#pragma unroll
                for (int r = 0; r < 4; ++r) {
                    mc[sid * 16 + quad * 4 + r] = mrun[tt][r];
                    lc[sid * 16 + quad * 4 + r] = lrun[tt][r];
                }
            }
        }
    }
    __syncthreads();
    if (q == 0) {   // wave 0: final merge + gated write-out
#pragma unroll
        for (int tt = 0; tt < 2; ++tt) {
            int sid = 2 | tt;
#pragma unroll
            for (int r = 0; r < 4; ++r) {
                int row = quad * 4 + r;
                float m1 = mc[sid * 16 + row], l1 = lc[sid * 16 + row];
                float mm = fmaxf(mrun[tt][r], m1);
                float a0 = __expf(mrun[tt][r] - mm);
                float a1 = __expf(m1 - mm);
                float linv = 1.0f / (lrun[tt][r] * a0 + l1 * a1);
#pragma unroll
                for (int u = 0; u < 8; ++u) {
                    size_t gi = ((size_t)b * 512 + l0[tt] + row) * 1024 + (h << 7) + 16 * u + col;
                    float val = (O[tt][u][r] * a0 + Oc[sid][row * 132 + 16 * u + col] * a1) * linv;
                    wvg[gi] = val * gbuf[gi];
                }
            }
        }
    }
}

extern "C" void kernel_launch(void* const* d_in, const int* in_sizes, int n_in,
                              void* d_out, int out_size, void* d_ws, size_t ws_size,
                              hipStream_t stream) {
    const float* x_in  = (const float*)d_in[0];
    const float* xl_k  = (const float*)d_in[2];
    const float* xl_v  = (const float*)d_in[3];
    const float* agg_u = (const float*)d_in[4];
    const float* agg_l = (const float*)d_in[5];
    const float* W_q   = (const float*)d_in[6];
    const float* W_kvg = (const float*)d_in[7];
    const float* W_res = (const float*)d_in[8];
    const float* x_u   = (const float*)d_in[9];
    const float* x_v   = (const float*)d_in[10];
    const float* xl_r  = (const float*)d_in[11];
    const float* cbk   = (const float*)d_in[12];
    float* out = (float*)d_out;
    char* wb = (char*)d_ws;

    float*  x_t   = (float*)(wb);                       // 16 MB [alias: K_hi; later Awh/Awl]
    float*  qbuf  = (float*)(wb + 16777216ul);          // 16 MB [alias: Vt_lo]
    float*  kbuf  = (float*)(wb + 33554432ul);          // 16 MB [alias: Vt_hi]
    float*  vbuf  = (float*)(wb + 50331648ul);          // 16 MB [alias: At_hi+At_lo]
    float*  gbuf  = (float*)(wb + 67108864ul);          // 16 MB
    float*  wvg   = (float*)(wb + 83886080ul);          // 16 MB [alias: Ah+Al pre-attn]
    float*  cT    = (float*)(wb + 100663296ul);         // 2 MB  [alias: C_hi+C_lo]
    float*  cnm   = (float*)(wb + 102760448ul);         // 16 KB
    ushort_t* Qu_hi = (ushort_t*)(wb + 102776832ul);    // 8 MB  [alias: Wtq pre-split]
    ushort_t* Qu_lo = (ushort_t*)(wb + 111165440ul);    // 8 MB  [alias: Wtvg pre-split]
    ushort_t* Qv_hi = (ushort_t*)(wb + 119554048ul);    // 8 MB  [alias: Wtres post-attn]
    ushort_t* K_lo  = (ushort_t*)(wb + 136331264ul);    // 16 MB
    ushort_t* R_hi  = (ushort_t*)(wb + 153108480ul);    // 2 MB
    float*  cbias   = (float*)(wb + 157302784ul);       // 128 KB

    ushort_t* K_hi  = (ushort_t*)x_t;
    ushort_t* Vt_hi = (ushort_t*)kbuf;
    ushort_t* Vt_lo = (ushort_t*)qbuf;
    ushort_t* At_hi = (ushort_t*)vbuf;
    ushort_t* At_lo = (ushort_t*)(wb + 50331648ul + 8388608ul);
    ushort_t* C_hi  = (ushort_t*)cT;
    ushort_t* C_lo  = (ushort_t*)(wb + 100663296ul + 1048576ul);

    ushort_t* Ah      = (ushort_t*)wvg;
    ushort_t* Al      = (ushort_t*)(wb + 83886080ul + 8388608ul);
    ushort_t* Wtq_hi  = (ushort_t*)Qu_hi;
    ushort_t* Wtq_lo  = (ushort_t*)(wb + 102776832ul + 2097152ul);
    ushort_t* Wtvg_hi = (ushort_t*)Qu_lo;
    ushort_t* Wtvg_lo = (ushort_t*)(wb + 111165440ul + 4194304ul);
    ushort_t* Wtres_hi = (ushort_t*)Qv_hi;
    ushort_t* Wtres_lo = (ushort_t*)(wb + 119554048ul + 2097152ul);
    ushort_t* Awh     = (ushort_t*)x_t;
    ushort_t* Awl     = (ushort_t*)(wb + 8388608ul);

    // 1) input LN
    ln_dm_kernel<<<4096, 256, 0, stream>>>(x_in, x_t);
    // 2) split activations + weights for bf16 GEMMs
    split_plain_kernel<<<16384, 256, 0, stream>>>(x_t, Ah, Al);
    wtsplit_kernel<<<dim3(16, 16), 256, 0, stream>>>(W_q, 1024, 0, Wtq_hi, Wtq_lo);
    wtsplit_kernel<<<dim3(32, 16), 256, 0, stream>>>(W_kvg, 3072, 1024, Wtvg_hi, Wtvg_lo);
    // 3) GEMMs: q (bf16), v+g (bf16), k (fp32 — argmin-critical)
    gemm_bf16_kernel<<<dim3(8, 32), 256, 0, stream>>>(Ah, Al, Wtq_hi, Wtq_lo, 0, qbuf, nullptr);
    gemm_bf16_kernel<<<dim3(16, 32), 256, 0, stream>>>(Ah, Al, Wtvg_hi, Wtvg_lo, 1, vbuf, gbuf);
    gemm_kernel<<<dim3(16, 64), 256, 0, stream>>>(x_t, W_kvg, 3072, 0, kbuf, nullptr, nullptr);
    // 4) LN(q), LN(k); VQ
    ln128_kernel<<<16384, 256, 0, stream>>>(qbuf, kbuf);
    cbt_kernel<<<2048, 256, 0, stream>>>(cbk, cT);
    cnorm_kernel<<<1024, 256, 0, stream>>>(cbk, cnm);
    vq_kernel<<<2048, 256, 0, stream>>>(kbuf, cT, cnm, cbk);
    // 5) attention preps
    split_q_kernel<<<16384, 256, 0, stream>>>(qbuf, x_u, x_v, Qu_hi, Qu_lo, Qv_hi);
    split_koff_kernel<<<16384, 256, 0, stream>>>(xl_k, K_hi, K_lo, 0);
    split_koff_kernel<<<16384, 256, 0, stream>>>(kbuf, K_hi, K_lo, 512);
    split_plain_kernel<<<2048, 256, 0, stream>>>(cbk, C_hi, C_lo);
    cvt_hi_kernel<<<4096, 256, 0, stream>>>(xl_r, R_hi);
    vtsplit_kernel<<<dim3(64, 16), 256, 0, stream>>>(xl_v, vbuf, Vt_hi, Vt_lo, 1024);
    vtsplit_kernel<<<dim3(64, 8), 256, 0, stream>>>(agg_u, agg_u, At_hi, At_lo, 512);
    cbias_kernel<<<128, 256, 0, stream>>>(agg_l, cbias);
    // 6) XCD-swizzled split-K-4 fused attention, 4 blocks/CU
    attn6_kernel<<<1024, 256, 0, stream>>>(Qu_hi, Qu_lo, Qv_hi, K_hi, K_lo, C_hi, C_lo,
                                           Vt_hi, Vt_lo, At_hi, At_lo, R_hi,
                                           cbias, gbuf, wvg);
    // 7) output GEMM (bf16)
    split_plain_kernel<<<16384, 256, 0, stream>>>(wvg, Awh, Awl);
    wtsplit_kernel<<<dim3(16, 16), 256, 0, stream>>>(W_res, 1024, 0, Wtres_hi, Wtres_lo);
    gemm_bf16_kernel<<<dim3(8, 32), 256, 0, stream>>>(Awh, Awl, Wtres_hi, Wtres_lo, 2, out, nullptr);
}

// Round 2
// 1028.484 us; speedup vs baseline: 1.2855x; 1.2855x over previous
//
#include <hip/hip_runtime.h>

#define INF30 1e30f
#define INV_TAU 0.08838834764831845f

typedef unsigned short ushort_t;
typedef __attribute__((ext_vector_type(8))) short bf16x8;
typedef __attribute__((ext_vector_type(4))) float f32x4;
typedef __attribute__((ext_vector_type(8))) unsigned short us8;

__device__ __forceinline__ float4 ld4(const float* p) { return *(const float4*)p; }

__device__ __forceinline__ unsigned short bf16_rne(float x) {
    unsigned int u = __float_as_uint(x);
    unsigned int r = u + 0x7fffu + ((u >> 16) & 1u);
    return (unsigned short)(r >> 16);
}
__device__ __forceinline__ float bf16_tof(unsigned short h) {
    return __uint_as_float(((unsigned int)h) << 16);
}
__device__ __forceinline__ bf16x8 ldb8(const ushort_t* p) { return *(const bf16x8*)p; }

#define MFMA16(a, b, c) __builtin_amdgcn_mfma_f32_16x16x32_bf16((a), (b), (c), 0, 0, 0)

// ---------------- LayerNorm over DM=1024 ----------------
__global__ __launch_bounds__(256) void ln_dm_kernel(const float* __restrict__ x, float* __restrict__ y) {
    size_t row = blockIdx.x;
    const float4* xr = (const float4*)(x + row * 1024);
    float4 v = xr[threadIdx.x];
    float s  = v.x + v.y + v.z + v.w;
    float ss = v.x*v.x + v.y*v.y + v.z*v.z + v.w*v.w;
#pragma unroll
    for (int off = 32; off > 0; off >>= 1) {
        s  += __shfl_down(s, off);
        ss += __shfl_down(ss, off);
    }
    __shared__ float rs[4], rss[4];
    int wv = threadIdx.x >> 6, ln = threadIdx.x & 63;
    if (ln == 0) { rs[wv] = s; rss[wv] = ss; }
    __syncthreads();
    s  = rs[0] + rs[1] + rs[2] + rs[3];
    ss = rss[0] + rss[1] + rss[2] + rss[3];
    float mu  = s * (1.0f/1024.0f);
    float var = ss * (1.0f/1024.0f) - mu*mu;
    float r = rsqrtf(var + 1e-6f);
    float4 o;
    o.x = (v.x - mu) * r; o.y = (v.y - mu) * r; o.z = (v.z - mu) * r; o.w = (v.w - mu) * r;
    ((float4*)(y + row * 1024))[threadIdx.x] = o;
}

// ---------------- fp32 tiled GEMM (k-columns only: argmin-critical path) ----------------
__global__ __launch_bounds__(256) void gemm_kernel(const float* __restrict__ A, const float* __restrict__ W,
                                                   int N, int mode,
                                                   float* __restrict__ o0, float* __restrict__ o1,
                                                   float* __restrict__ o2) {
    __shared__ float As[16][64];
    __shared__ float Bs[16][64];
    int t = threadIdx.x;
    int col0 = blockIdx.x << 6;
    int row0 = blockIdx.y << 6;
    int tx = t & 15, ty = t >> 4;
    int arow = t >> 2, akq = t & 3;
    int bkr = t >> 4, bcq = t & 15;
    const float* Ap = A + (size_t)(row0 + arow) * 1024 + akq * 4;
    const float* Wp = W + (size_t)bkr * N + col0 + bcq * 4;
    float acc[4][4];
#pragma unroll
    for (int i = 0; i < 4; ++i)
#pragma unroll
        for (int j = 0; j < 4; ++j) acc[i][j] = 0.0f;

    for (int kt = 0; kt < 64; ++kt) {
        float4 a4 = ld4(Ap + kt * 16);
        float4 b4 = ld4(Wp + (size_t)kt * 16 * N);
        __syncthreads();
        As[akq*4+0][arow] = a4.x;
        As[akq*4+1][arow] = a4.y;
        As[akq*4+2][arow] = a4.z;
        As[akq*4+3][arow] = a4.w;
        *(float4*)&Bs[bkr][bcq*4] = b4;
        __syncthreads();
#pragma unroll
        for (int kk = 0; kk < 16; ++kk) {
            float4 av = *(float4*)&As[kk][ty*4];
            float4 bv = *(float4*)&Bs[kk][tx*4];
            acc[0][0] += av.x*bv.x; acc[0][1] += av.x*bv.y; acc[0][2] += av.x*bv.z; acc[0][3] += av.x*bv.w;
            acc[1][0] += av.y*bv.x; acc[1][1] += av.y*bv.y; acc[1][2] += av.y*bv.z; acc[1][3] += av.y*bv.w;
            acc[2][0] += av.z*bv.x; acc[2][1] += av.z*bv.y; acc[2][2] += av.z*bv.z; acc[2][3] += av.z*bv.w;
            acc[3][0] += av.w*bv.x; acc[3][1] += av.w*bv.y; acc[3][2] += av.w*bv.z; acc[3][3] += av.w*bv.w;
        }
    }

#pragma unroll
    for (int i = 0; i < 4; ++i) {
        int rr = row0 + ty*4 + i;
        int b = rr >> 9, l = rr & 511;
#pragma unroll
        for (int j = 0; j < 4; ++j) {
            int cc = col0 + tx*4 + j;
            float vv = acc[i][j];
            if (mode == 0) {
                o0[((size_t)((b<<3) + (cc>>7)) * 512 + l) * 128 + (cc & 127)] = vv;
            } else if (mode == 1) {
                if (cc < 1024) {
                    o0[((size_t)((b<<3) + (cc>>7)) * 512 + l) * 128 + (cc & 127)] = vv;
                } else if (cc < 2048) {
                    int c2 = cc - 1024;
                    o1[((size_t)((b<<3) + (c2>>7)) * 512 + l) * 128 + (c2 & 127)] = vv;
                } else {
                    o2[(size_t)rr * 1024 + (cc - 2048)] = vv / (1.0f + __expf(-vv));
                }
            } else {
                o0[(size_t)rr * 1024 + cc] = vv;
            }
        }
    }
}

// ---------------- weight transpose + bf16 hi/lo split ----------------
__global__ __launch_bounds__(256) void wtsplit_kernel(const float* __restrict__ W, int Ntot, int c0,
                                                      ushort_t* __restrict__ th, ushort_t* __restrict__ tl) {
    __shared__ float T[64][68];
    int n0 = blockIdx.x << 6, k0 = blockIdx.y << 6, t = threadIdx.x;
    for (int i = t; i < 1024; i += 256) {
        int kk = i >> 4, nn4 = (i & 15) << 2;
        *(float4*)&T[kk][nn4] = ld4(W + (size_t)(k0 + kk) * Ntot + c0 + n0 + nn4);
    }
    __syncthreads();
    for (int i = t; i < 512; i += 256) {
        int nn = i >> 3, kc = (i & 7) << 3;
        us8 h8, l8;
#pragma unroll
        for (int j = 0; j < 8; ++j) {
            float x = T[kc + j][nn];
            unsigned short hh = bf16_rne(x);
            h8[j] = hh; l8[j] = bf16_rne(x - bf16_tof(hh));
        }
        size_t off = (size_t)(n0 + nn) * 1024 + k0 + kc;
        *(us8*)(th + off) = h8;
        *(us8*)(tl + off) = l8;
    }
}

// ---------------- bf16 3-term split GEMM ----------------
#define GSTRIDE 40
__global__ __launch_bounds__(256) void gemm_bf16_kernel(
        const ushort_t* __restrict__ Ah, const ushort_t* __restrict__ Al,
        const ushort_t* __restrict__ Bth, const ushort_t* __restrict__ Btl,
        int mode, float* __restrict__ o0, float* __restrict__ o1) {
    __shared__ ushort_t LA[2][128 * GSTRIDE];
    __shared__ ushort_t LB[2][128 * GSTRIDE];
    int t = threadIdx.x;
    int col0 = blockIdx.x << 7, row0 = blockIdx.y << 7;
    int wvid = t >> 6, ln = t & 63;
    int lcol = ln & 15, quad = ln >> 4;
    int qm = wvid >> 1, qn = wvid & 1;

    f32x4 C[4][4];
#pragma unroll
    for (int i = 0; i < 4; ++i)
#pragma unroll
        for (int j = 0; j < 4; ++j) C[i][j] = (f32x4){0.f, 0.f, 0.f, 0.f};

    for (int k0 = 0; k0 < 1024; k0 += 32) {
        us8 ra[2][2], rb[2][2];
#pragma unroll
        for (int v = 0; v < 2; ++v) {
            int cid = t + 256 * v;
            int row = cid >> 2, ch = cid & 3;
            size_t ga = (size_t)(row0 + row) * 1024 + k0 + ch * 8;
            size_t gb = (size_t)(col0 + row) * 1024 + k0 + ch * 8;
            ra[v][0] = *(const us8*)(Ah + ga);
            ra[v][1] = *(const us8*)(Al + ga);
            rb[v][0] = *(const us8*)(Bth + gb);
            rb[v][1] = *(const us8*)(Btl + gb);
        }
        __syncthreads();
#pragma unroll
        for (int v = 0; v < 2; ++v) {
            int cid = t + 256 * v;
            int row = cid >> 2, ch = cid & 3;
            *(us8*)&LA[0][row * GSTRIDE + ch * 8] = ra[v][0];
            *(us8*)&LA[1][row * GSTRIDE + ch * 8] = ra[v][1];
            *(us8*)&LB[0][row * GSTRIDE + ch * 8] = rb[v][0];
            *(us8*)&LB[1][row * GSTRIDE + ch * 8] = rb[v][1];
        }
        __syncthreads();
        bf16x8 afh[4], afl[4], bfh[4], bfl[4];
#pragma unroll
        for (int i = 0; i < 4; ++i) {
            int r = qm * 64 + i * 16 + lcol;
            afh[i] = *(const bf16x8*)&LA[0][r * GSTRIDE + quad * 8];
            afl[i] = *(const bf16x8*)&LA[1][r * GSTRIDE + quad * 8];
            int c = qn * 64 + i * 16 + lcol;
            bfh[i] = *(const bf16x8*)&LB[0][c * GSTRIDE + quad * 8];
            bfl[i] = *(const bf16x8*)&LB[1][c * GSTRIDE + quad * 8];
        }
#pragma unroll
        for (int i = 0; i < 4; ++i)
#pragma unroll
            for (int j = 0; j < 4; ++j) {
                C[i][j] = MFMA16(afh[i], bfh[j], C[i][j]);
                C[i][j] = MFMA16(afl[i], bfh[j], C[i][j]);
                C[i][j] = MFMA16(afh[i], bfl[j], C[i][j]);
            }
    }

#pragma unroll
    for (int i = 0; i < 4; ++i) {
#pragma unroll
        for (int r = 0; r < 4; ++r) {
            int rr = row0 + qm * 64 + 16 * i + quad * 4 + r;
            int b = rr >> 9, l = rr & 511;
#pragma unroll
            for (int j = 0; j < 4; ++j) {
                int cc = col0 + qn * 64 + 16 * j + lcol;
                float vv = C[i][j][r];
                if (mode == 0) {
                    o0[((size_t)((b<<3) + (cc>>7)) * 512 + l) * 128 + (cc & 127)] = vv;
                } else if (mode == 1) {
                    if (cc < 1024) o0[((size_t)((b<<3) + (cc>>7)) * 512 + l) * 128 + (cc & 127)] = vv;
                    else o1[(size_t)rr * 1024 + (cc - 1024)] = vv / (1.0f + __expf(-vv));
                } else {
                    o0[(size_t)rr * 1024 + cc] = vv;
                }
            }
        }
    }
}

// ---------------- LayerNorm over last dim 128 for q and k, in place ----------------
__global__ __launch_bounds__(256) void ln128_kernel(float* __restrict__ qb, float* __restrict__ kb) {
    int wv = threadIdx.x >> 6, ln = threadIdx.x & 63;
    int gw = (blockIdx.x << 2) + wv;
    float* base = (gw < 32768) ? qb : kb;
    int row = gw & 32767;
    float2 x = *(float2*)(base + (size_t)row * 128 + (ln << 1));
    float s  = x.x + x.y;
    float ss = x.x*x.x + x.y*x.y;
#pragma unroll
    for (int m = 32; m > 0; m >>= 1) { s += __shfl_xor(s, m); ss += __shfl_xor(ss, m); }
    float mu  = s * (1.0f/128.0f);
    float var = ss * (1.0f/128.0f) - mu*mu;
    float r = rsqrtf(var + 1e-6f);
    x.x = (x.x - mu) * r; x.y = (x.y - mu) * r;
    *(float2*)(base + (size_t)row * 128 + (ln << 1)) = x;
}

// ---------------- codebook transpose + norms ----------------
__global__ __launch_bounds__(256) void cbt_kernel(const float* __restrict__ cb, float* __restrict__ cT) {
    int idx = blockIdx.x * 256 + threadIdx.x;
    int h = idx >> 16, s = (idx >> 7) & 511, d = idx & 127;
    cT[((size_t)((h << 7) + d)) * 512 + s] = cb[idx];
}

__global__ __launch_bounds__(256) void cnorm_kernel(const float* __restrict__ cb, float* __restrict__ cn) {
    int wv = threadIdx.x >> 6, ln = threadIdx.x & 63;
    int row = (blockIdx.x << 2) + wv;
    float2 x = *(const float2*)(cb + (size_t)row * 128 + (ln << 1));
    float ss = x.x*x.x + x.y*x.y;
#pragma unroll
    for (int m = 32; m > 0; m >>= 1) ss += __shfl_xor(ss, m);
    if (ln == 0) cn[row] = ss;
}

// ---------------- VQ argmin (fp32) ----------------
__global__ __launch_bounds__(256) void vq_kernel(float* __restrict__ kb, const float* __restrict__ cT,
                                                 const float* __restrict__ cn, const float* __restrict__ cb) {
    __shared__ float sK[4][4][128];
    int wv = threadIdx.x >> 6, ln = threadIdx.x & 63;
    int gw = (blockIdx.x << 2) + wv;
    int bh = gw >> 7;
    int l4 = (gw & 127) << 2;
    int h = bh & 7;
    size_t r0 = ((size_t)bh << 9) + l4;
#pragma unroll
    for (int i = 0; i < 4; ++i) {
        float2 kx = *(const float2*)(kb + (r0 + i) * 128 + (ln << 1));
        sK[wv][i][(ln<<1)]   = kx.x;
        sK[wv][i][(ln<<1)+1] = kx.y;
    }
    __syncthreads();
    const float* ct = cT + ((size_t)h << 7) * 512;
    int s0 = ln << 3;
    float dt[4][8];
#pragma unroll
    for (int i = 0; i < 4; ++i)
#pragma unroll
        for (int j = 0; j < 8; ++j) dt[i][j] = 0.0f;

    for (int dc = 0; dc < 4; ++dc) {
        float ch[4][8];
#pragma unroll
        for (int i = 0; i < 4; ++i)
#pragma unroll
            for (int j = 0; j < 8; ++j) ch[i][j] = 0.0f;
#pragma unroll 4
        for (int d = dc * 32; d < dc * 32 + 32; ++d) {
            float4 c0 = ld4(ct + (size_t)d * 512 + s0);
            float4 c1 = ld4(ct + (size_t)d * 512 + s0 + 4);
#pragma unroll
            for (int i = 0; i < 4; ++i) {
                float kd = sK[wv][i][d];
                ch[i][0] += kd * c0.x; ch[i][1] += kd * c0.y; ch[i][2] += kd * c0.z; ch[i][3] += kd * c0.w;
                ch[i][4] += kd * c1.x; ch[i][5] += kd * c1.y; ch[i][6] += kd * c1.z; ch[i][7] += kd * c1.w;
            }
        }
#pragma unroll
        for (int i = 0; i < 4; ++i)
#pragma unroll
            for (int j = 0; j < 8; ++j) dt[i][j] += ch[i][j];
    }
    const float* cnh = cn + (h << 9);
#pragma unroll
    for (int i = 0; i < 4; ++i) {
        float bestv = cnh[s0] - 2.0f * dt[i][0];
        int bestz = s0;
#pragma unroll
        for (int j = 1; j < 8; ++j) {
            float scv = cnh[s0 + j] - 2.0f * dt[i][j];
            if (scv < bestv) { bestv = scv; bestz = s0 + j; }
        }
#pragma unroll
        for (int m = 32; m > 0; m >>= 1) {
            float ov = __shfl_xor(bestv, m);
            int   oz = __shfl_xor(bestz, m);
            if (ov < bestv || (ov == bestv && oz < bestz)) { bestv = ov; bestz = oz; }
        }
        float2 cz = *(const float2*)(cb + ((size_t)(h << 9) + bestz) * 128 + (ln << 1));
        *(float2*)(kb + (r0 + i) * 128 + (ln << 1)) = cz;
    }
}

// ---------------- prep kernels ----------------
__global__ __launch_bounds__(256) void split_q_kernel(const float* __restrict__ q,
        const float* __restrict__ xu, const float* __restrict__ xv,
        ushort_t* __restrict__ quh, ushort_t* __restrict__ qul,
        ushort_t* __restrict__ qvh) {
    int idx = blockIdx.x * 256 + threadIdx.x;
    int d = idx & 127;
    int h = (idx >> 16) & 7;
    float qv = q[idx];
    float a = qv + xu[(h << 7) + d];
    unsigned short ah = bf16_rne(a);
    quh[idx] = ah; qul[idx] = bf16_rne(a - bf16_tof(ah));
    float b = qv + xv[(h << 7) + d];
    qvh[idx] = bf16_rne(b);
}

__global__ __launch_bounds__(256) void split_plain_kernel(const float* __restrict__ src,
        ushort_t* __restrict__ hi, ushort_t* __restrict__ lo) {
    int idx = blockIdx.x * 256 + threadIdx.x;
    float x = src[idx];
    unsigned short h = bf16_rne(x);
    hi[idx] = h; lo[idx] = bf16_rne(x - bf16_tof(h));
}

__global__ __launch_bounds__(256) void cvt_hi_kernel(const float* __restrict__ src,
        ushort_t* __restrict__ hi) {
    int idx = blockIdx.x * 256 + threadIdx.x;
    hi[idx] = bf16_rne(src[idx]);
}

__global__ __launch_bounds__(256) void split_koff_kernel(const float* __restrict__ src,
        ushort_t* __restrict__ hi, ushort_t* __restrict__ lo, int rowoff) {
    int idx = blockIdx.x * 256 + threadIdx.x;
    int bh = idx >> 16, rem = idx & 65535;
    size_t dst = ((size_t)bh << 17) + ((size_t)rowoff << 7) + rem;
    float x = src[idx];
    unsigned short h = bf16_rne(x);
    hi[dst] = h; lo[dst] = bf16_rne(x - bf16_tof(h));
}

__global__ __launch_bounds__(256) void vtsplit_kernel(const float* __restrict__ srcA,
        const float* __restrict__ srcB, ushort_t* __restrict__ hi, ushort_t* __restrict__ lo, int NK) {
    __shared__ float T[64][132];
    int bh = blockIdx.x, kt = blockIdx.y, t = threadIdx.x;
    for (int i = t; i < 2048; i += 256) {
        int r = i >> 5, c4 = (i & 31) << 2;
        int key = (kt << 6) + r;
        const float* s = (key < 512) ? (srcA + ((size_t)bh * 512 + key) * 128 + c4)
                                     : (srcB + ((size_t)bh * 512 + (key - 512)) * 128 + c4);
        *(float4*)&T[r][c4] = ld4(s);
    }
    __syncthreads();
    for (int i = t; i < 1024; i += 256) {
        int vc = i >> 3, kk = (i & 7) << 3;
        us8 h8, l8;
#pragma unroll
        for (int j = 0; j < 8; ++j) {
            float x = T[kk + j][vc];
            unsigned short hh = bf16_rne(x);
            h8[j] = hh; l8[j] = bf16_rne(x - bf16_tof(hh));
        }
        size_t off = ((size_t)bh * 128 + vc) * NK + (kt << 6) + kk;
        *(us8*)(hi + off) = h8;
        *(us8*)(lo + off) = l8;
    }
}

__global__ __launch_bounds__(256) void cbias_kernel(const float* __restrict__ al, float* __restrict__ cb) {
    int idx = blockIdx.x * 256 + threadIdx.x;
    float v = al[idx];
    cb[idx] = (v > 0.0f) ? __logf(fmaxf(v, 1e-30f)) : -INF30;
}

// ---------------- attn7: one tile per WAVE, streamed Qu, split-K-2 per tile ----------------
// 1024 blocks x 4 waves; bh = 8*(idx>>4) + (blk&7) pins each bh's 16 blocks to one XCD.
// Block owns pair {j, 31-j}. Wave wvid: tt = wvid&1 (tile), kh = wvid>>1 (K-half).
// Per-wave state halved vs attn6 (O[8]=32 regs, no persistent Qu frags -> streamed from
// L1/L2 in the QK s-loop): target <=128 regs total so __launch_bounds__(256,4) does NOT
// spill (round-1 failure mode: demand ~190 vs cap 128 -> 2.4 GB scratch traffic).
// Weighted K-split: seg1 iters cost 3 units (no G-phase), seg0/2 cost 4; Ht picked so both
// halves carry ~equal units. LDS: P bufs 10.2 KB (loop) union Oc 16.9 KB (combine) = 17.2 KB.
#define PSTR 40
__global__ __launch_bounds__(256, 4) void attn7_kernel(
        const ushort_t* __restrict__ Qu_hi, const ushort_t* __restrict__ Qu_lo,
        const ushort_t* __restrict__ Qv_hi,
        const ushort_t* __restrict__ K_hi,  const ushort_t* __restrict__ K_lo,
        const ushort_t* __restrict__ C_hi,  const ushort_t* __restrict__ C_lo,
        const ushort_t* __restrict__ Vt_hi, const ushort_t* __restrict__ Vt_lo,
        const ushort_t* __restrict__ At_hi, const ushort_t* __restrict__ At_lo,
        const ushort_t* __restrict__ R_hi,
        const float* __restrict__ cbias, const float* __restrict__ gbuf,
        float* __restrict__ wvg) {
    // union: [0,10240) Phs / [10240,20480) Pls (loop)  ||  [0,16896) Oc (combine)
    __shared__ __align__(16) unsigned char smem[20480 + 256];
    typedef ushort_t PB[16 * PSTR];
    PB* Phs = (PB*)smem;                                  // 4 x 1280 B
    PB* Pls = (PB*)(smem + 10240);                        // 4 x 1280 B
    float (*Oc)[16 * 132] = (float (*)[16 * 132])smem;    // 2 x 8448 B (overlays P)
    float* mc = (float*)(smem + 20480);                   // [2][16]
    float* lc = mc + 32;                                  // [2][16]

    int t = threadIdx.x;
    int wvid = t >> 6, ln = t & 63;
    int col = ln & 15, quad = ln >> 4;
    int blk = blockIdx.x;
    int xcd = blk & 7, idx = blk >> 3;
    int bh = ((idx >> 4) << 3) + xcd;
    int pairj = idx & 15;
    int tt = wvid & 1;               // which tile of the pair
    int kh = wvid >> 1;              // which K-half
    int l0 = (tt == 0) ? (pairj << 4) : ((31 - pairj) << 4);
    int h = bh & 7, b = bh >> 3;

    f32x4 O[8];
#pragma unroll
    for (int u = 0; u < 8; ++u) O[u] = (f32x4){0.f, 0.f, 0.f, 0.f};
    float mrun[4], lrun[4];
#pragma unroll
    for (int r = 0; r < 4; ++r) { mrun[r] = -INF30; lrun[r] = 0.0f; }

    int nt2 = (l0 + 47) >> 5;
    int Tt = 32 + nt2;
    // weighted midpoint: units = 4*min(ti,16)+3*clamp(ti-16,0,16)+4*max(ti-32,0)
    int Ht = (nt2 <= 4) ? (14 + ((nt2 + 1) >> 1)) : (16 + (2 * nt2 - 6) / 3);
    int ti0 = kh ? Ht : 0;
    int ti1 = kh ? Tt : Ht;

    size_t qb = ((size_t)bh * 512 + l0 + col) * 128 + quad * 8;
    ushort_t* Ph = Phs[wvid];
    ushort_t* Pl = Pls[wvid];

    for (int ti = ti0; ti < ti1; ++ti) {
        int seg, w0;
        if (ti < 16)      { seg = 0; w0 = ti << 5; }
        else if (ti < 32) { seg = 1; w0 = (ti - 16) << 5; }
        else              { seg = 2; w0 = (ti - 32) << 5; }

        // ---- rel G tiles (seg 0/2); qv frags reloaded from L1/L2 ----
        f32x4 Gacc[3];
        if (seg != 1) {
            bf16x8 qv0 = ldb8(Qv_hi + qb);
            bf16x8 qv1 = ldb8(Qv_hi + qb + 32);
            bf16x8 qv2 = ldb8(Qv_hi + qb + 64);
            bf16x8 qv3 = ldb8(Qv_hi + qb + 96);
            int jt0 = ((seg == 0) ? w0 : (512 + w0)) + 496 - l0;
#pragma unroll
            for (int u = 0; u < 3; ++u) {
                int j = jt0 + 16 * u + col;
                j = (j > 1023) ? 1023 : j;
                const ushort_t* rp = R_hi + ((size_t)(h << 10) + j) * 128 + quad * 8;
                f32x4 acc = (f32x4){0.f, 0.f, 0.f, 0.f};
                acc = MFMA16(qv0, ldb8(rp), acc);
                acc = MFMA16(qv1, ldb8(rp + 32), acc);
                acc = MFMA16(qv2, ldb8(rp + 64), acc);
                acc = MFMA16(qv3, ldb8(rp + 96), acc);
                Gacc[u] = acc;
            }
        }

        // ---- QK^T: streamed Qu + K frags (6 loads + 6 MFMAs per s-slice) ----
        const ushort_t *khb, *klb;
        if (seg == 0)      { khb = K_hi + ((size_t)bh * 1024 + w0) * 128;
                             klb = K_lo + ((size_t)bh * 1024 + w0) * 128; }
        else if (seg == 1) { khb = C_hi + ((size_t)(h << 9) + w0) * 128;
                             klb = C_lo + ((size_t)(h << 9) + w0) * 128; }
        else               { khb = K_hi + ((size_t)bh * 1024 + 512 + w0) * 128;
                             klb = K_lo + ((size_t)bh * 1024 + 512 + w0) * 128; }
        const ushort_t* kp0h = khb + (size_t)col * 128 + quad * 8;
        const ushort_t* kp0l = klb + (size_t)col * 128 + quad * 8;
        const ushort_t* kp1h = kp0h + 16 * 128;
        const ushort_t* kp1l = kp0l + 16 * 128;
        f32x4 S[2];
        S[0] = (f32x4){0.f, 0.f, 0.f, 0.f};
        S[1] = (f32x4){0.f, 0.f, 0.f, 0.f};
#pragma unroll
        for (int s = 0; s < 4; ++s) {
            bf16x8 qh = ldb8(Qu_hi + qb + 32 * s);
            bf16x8 ql = ldb8(Qu_lo + qb + 32 * s);
            bf16x8 k0h = ldb8(kp0h + 32 * s);
            bf16x8 k0l = ldb8(kp0l + 32 * s);
            bf16x8 k1h = ldb8(kp1h + 32 * s);
            bf16x8 k1l = ldb8(kp1l + 32 * s);
            S[0] = MFMA16(qh, k0h, S[0]);
            S[0] = MFMA16(ql, k0h, S[0]);
            S[0] = MFMA16(qh, k0l, S[0]);
            S[1] = MFMA16(qh, k1h, S[1]);
            S[1] = MFMA16(ql, k1h, S[1]);
            S[1] = MFMA16(qh, k1l, S[1]);
        }

        // ---- fixup + online softmax + P frags ----
        float bias0 = 0.f, bias1 = 0.f;
        if (seg == 1) {
            bias0 = cbias[(size_t)(bh << 9) + w0 + col];
            bias1 = cbias[(size_t)(bh << 9) + w0 + 16 + col];
        }
#pragma unroll
        for (int t2 = 0; t2 < 2; ++t2) {
#pragma unroll
            for (int r = 0; r < 4; ++r) {
                int row = 4 * quad + r;
                float sv = S[t2][r];
                if (seg != 1) {
                    int d = col + 15 - row;
                    int src = quad * 16 + (d & 15);
                    float g0 = __shfl(Gacc[t2][r], src);
                    float g1 = __shfl(Gacc[t2 + 1][r], src);
                    float gv = (d >= 16) ? g1 : g0;
                    sv = (sv + gv) * INV_TAU;
                    if (seg == 2 && (w0 + 16 * t2 + col > l0 + row)) sv = -INF30;
                } else {
                    sv = sv * INV_TAU + ((t2 == 0) ? bias0 : bias1);
                }
                S[t2][r] = sv;
            }
        }
#pragma unroll
        for (int r = 0; r < 4; ++r) {
            float mv = fmaxf(S[0][r], S[1][r]);
#pragma unroll
            for (int m = 8; m > 0; m >>= 1) mv = fmaxf(mv, __shfl_xor(mv, m));
            float mnew = fmaxf(mrun[r], mv);
            float alpha = __expf(mrun[r] - mnew);
            mrun[r] = mnew;
            float p0 = __expf(S[0][r] - mnew);
            float p1 = __expf(S[1][r] - mnew);
            float ps = p0 + p1;
#pragma unroll
            for (int m = 8; m > 0; m >>= 1) ps += __shfl_xor(ps, m);
            lrun[r] = lrun[r] * alpha + ps;
#pragma unroll
            for (int u = 0; u < 8; ++u) O[u][r] *= alpha;
            int row = 4 * quad + r;
            unsigned short h0 = bf16_rne(p0);
            Ph[row * PSTR + col] = h0;
            Pl[row * PSTR + col] = bf16_rne(p0 - bf16_tof(h0));
            unsigned short h1 = bf16_rne(p1);
            Ph[row * PSTR + 16 + col] = h1;
            Pl[row * PSTR + 16 + col] = bf16_rne(p1 - bf16_tof(h1));
        }
        bf16x8 pah = *(const bf16x8*)&Ph[col * PSTR + quad * 8];
        bf16x8 pal = *(const bf16x8*)&Pl[col * PSTR + quad * 8];

        // ---- PV ----
        const ushort_t *vh, *vl;
        size_t vstr;
        int wbase;
        if (seg == 0)      { vh = Vt_hi + ((size_t)bh << 17); vl = Vt_lo + ((size_t)bh << 17); vstr = 1024; wbase = w0; }
        else if (seg == 1) { vh = At_hi + ((size_t)bh << 16); vl = At_lo + ((size_t)bh << 16); vstr = 512;  wbase = w0; }
        else               { vh = Vt_hi + ((size_t)bh << 17); vl = Vt_lo + ((size_t)bh << 17); vstr = 1024; wbase = 512 + w0; }
#pragma unroll
        for (int u = 0; u < 8; ++u) {
            int vcol = 16 * u + col;
            bf16x8 vbh = ldb8(vh + (size_t)vcol * vstr + wbase + quad * 8);
            bf16x8 vbl = ldb8(vl + (size_t)vcol * vstr + wbase + quad * 8);
            O[u] = MFMA16(pah, vbh, O[u]);
            O[u] = MFMA16(pal, vbh, O[u]);
            O[u] = MFMA16(pah, vbl, O[u]);
        }
    }

    // ---- split-K-2 combine per tile (P buffers dead; Oc overlays) ----
    __syncthreads();
    if (kh == 1) {   // waves 2,3 publish partials to slot tt
#pragma unroll
        for (int u = 0; u < 8; ++u)
#pragma unroll
            for (int r = 0; r < 4; ++r)
                Oc[tt][(quad * 4 + r) * 132 + 16 * u + col] = O[u][r];
        if (col == 0) {
#pragma unroll
            for (int r = 0; r < 4; ++r) {
                mc[tt * 16 + quad * 4 + r] = mrun[r];
                lc[tt * 16 + quad * 4 + r] = lrun[r];
            }
        }
    }
    __syncthreads();
    if (kh == 0) {   // waves 0,1 merge + gated write-out
#pragma unroll
        for (int r = 0; r < 4; ++r) {
            int row = quad * 4 + r;
            float m1 = mc[tt * 16 + row], l1 = lc[tt * 16 + row];
            float mm = fmaxf(mrun[r], m1);
            float a0 = __expf(mrun[r] - mm);
            float a1 = __expf(m1 - mm);
            float linv = 1.0f / (lrun[r] * a0 + l1 * a1);
#pragma unroll
            for (int u = 0; u < 8; ++u) {
                size_t gi = ((size_t)b * 512 + l0 + row) * 1024 + (h << 7) + 16 * u + col;
                float val = (O[u][r] * a0 + Oc[tt][row * 132 + 16 * u + col] * a1) * linv;
                wvg[gi] = val * gbuf[gi];
            }
        }
    }
}

extern "C" void kernel_launch(void* const* d_in, const int* in_sizes, int n_in,
                              void* d_out, int out_size, void* d_ws, size_t ws_size,
                              hipStream_t stream) {
    const float* x_in  = (const float*)d_in[0];
    const float* xl_k  = (const float*)d_in[2];
    const float* xl_v  = (const float*)d_in[3];
    const float* agg_u = (const float*)d_in[4];
    const float* agg_l = (const float*)d_in[5];
    const float* W_q   = (const float*)d_in[6];
    const float* W_kvg = (const float*)d_in[7];
    const float* W_res = (const float*)d_in[8];
    const float* x_u   = (const float*)d_in[9];
    const float* x_v   = (const float*)d_in[10];
    const float* xl_r  = (const float*)d_in[11];
    const float* cbk   = (const float*)d_in[12];
    float* out = (float*)d_out;
    char* wb = (char*)d_ws;

    float*  x_t   = (float*)(wb);                       // 16 MB [alias: K_hi; later Awh/Awl]
    float*  qbuf  = (float*)(wb + 16777216ul);          // 16 MB [alias: Vt_lo]
    float*  kbuf  = (float*)(wb + 33554432ul);          // 16 MB [alias: Vt_hi]
    float*  vbuf  = (float*)(wb + 50331648ul);          // 16 MB [alias: At_hi+At_lo]
    float*  gbuf  = (float*)(wb + 67108864ul);          // 16 MB
    float*  wvg   = (float*)(wb + 83886080ul);          // 16 MB [alias: Ah+Al pre-attn]
    float*  cT    = (float*)(wb + 100663296ul);         // 2 MB  [alias: C_hi+C_lo]
    float*  cnm   = (float*)(wb + 102760448ul);         // 16 KB
    ushort_t* Qu_hi = (ushort_t*)(wb + 102776832ul);    // 8 MB  [alias: Wtq pre-split]
    ushort_t* Qu_lo = (ushort_t*)(wb + 111165440ul);    // 8 MB  [alias: Wtvg pre-split]
    ushort_t* Qv_hi = (ushort_t*)(wb + 119554048ul);    // 8 MB  [alias: Wtres post-attn]
    ushort_t* K_lo  = (ushort_t*)(wb + 136331264ul);    // 16 MB
    ushort_t* R_hi  = (ushort_t*)(wb + 153108480ul);    // 2 MB
    float*  cbias   = (float*)(wb + 157302784ul);       // 128 KB

    ushort_t* K_hi  = (ushort_t*)x_t;
    ushort_t* Vt_hi = (ushort_t*)kbuf;
    ushort_t* Vt_lo = (ushort_t*)qbuf;
    ushort_t* At_hi = (ushort_t*)vbuf;
    ushort_t* At_lo = (ushort_t*)(wb + 50331648ul + 8388608ul);
    ushort_t* C_hi  = (ushort_t*)cT;
    ushort_t* C_lo  = (ushort_t*)(wb + 100663296ul + 1048576ul);

    ushort_t* Ah      = (ushort_t*)wvg;
    ushort_t* Al      = (ushort_t*)(wb + 83886080ul + 8388608ul);
    ushort_t* Wtq_hi  = (ushort_t*)Qu_hi;
    ushort_t* Wtq_lo  = (ushort_t*)(wb + 102776832ul + 2097152ul);
    ushort_t* Wtvg_hi = (ushort_t*)Qu_lo;
    ushort_t* Wtvg_lo = (ushort_t*)(wb + 111165440ul + 4194304ul);
    ushort_t* Wtres_hi = (ushort_t*)Qv_hi;
    ushort_t* Wtres_lo = (ushort_t*)(wb + 119554048ul + 2097152ul);
    ushort_t* Awh     = (ushort_t*)x_t;
    ushort_t* Awl     = (ushort_t*)(wb + 8388608ul);

    // 1) input LN
    ln_dm_kernel<<<4096, 256, 0, stream>>>(x_in, x_t);
    // 2) split activations + weights for bf16 GEMMs
    split_plain_kernel<<<16384, 256, 0, stream>>>(x_t, Ah, Al);
    wtsplit_kernel<<<dim3(16, 16), 256, 0, stream>>>(W_q, 1024, 0, Wtq_hi, Wtq_lo);
    wtsplit_kernel<<<dim3(32, 16), 256, 0, stream>>>(W_kvg, 3072, 1024, Wtvg_hi, Wtvg_lo);
    // 3) GEMMs: q (bf16), v+g (bf16), k (fp32 — argmin-critical)
    gemm_bf16_kernel<<<dim3(8, 32), 256, 0, stream>>>(Ah, Al, Wtq_hi, Wtq_lo, 0, qbuf, nullptr);
    gemm_bf16_kernel<<<dim3(16, 32), 256, 0, stream>>>(Ah, Al, Wtvg_hi, Wtvg_lo, 1, vbuf, gbuf);
    gemm_kernel<<<dim3(16, 64), 256, 0, stream>>>(x_t, W_kvg, 3072, 0, kbuf, nullptr, nullptr);
    // 4) LN(q), LN(k); VQ
    ln128_kernel<<<16384, 256, 0, stream>>>(qbuf, kbuf);
    cbt_kernel<<<2048, 256, 0, stream>>>(cbk, cT);
    cnorm_kernel<<<1024, 256, 0, stream>>>(cbk, cnm);
    vq_kernel<<<2048, 256, 0, stream>>>(kbuf, cT, cnm, cbk);
    // 5) attention preps
    split_q_kernel<<<16384, 256, 0, stream>>>(qbuf, x_u, x_v, Qu_hi, Qu_lo, Qv_hi);
    split_koff_kernel<<<16384, 256, 0, stream>>>(xl_k, K_hi, K_lo, 0);
    split_koff_kernel<<<16384, 256, 0, stream>>>(kbuf, K_hi, K_lo, 512);
    split_plain_kernel<<<2048, 256, 0, stream>>>(cbk, C_hi, C_lo);
    cvt_hi_kernel<<<4096, 256, 0, stream>>>(xl_r, R_hi);
    vtsplit_kernel<<<dim3(64, 16), 256, 0, stream>>>(xl_v, vbuf, Vt_hi, Vt_lo, 1024);
    vtsplit_kernel<<<dim3(64, 8), 256, 0, stream>>>(agg_u, agg_u, At_hi, At_lo, 512);
    cbias_kernel<<<128, 256, 0, stream>>>(agg_l, cbias);
    // 6) one-tile-per-wave split-K fused attention, 4 blocks/CU target
    attn7_kernel<<<1024, 256, 0, stream>>>(Qu_hi, Qu_lo, Qv_hi, K_hi, K_lo, C_hi, C_lo,
                                           Vt_hi, Vt_lo, At_hi, At_lo, R_hi,
                                           cbias, gbuf, wvg);
    // 7) output GEMM (bf16)
    split_plain_kernel<<<16384, 256, 0, stream>>>(wvg, Awh, Awl);
    wtsplit_kernel<<<dim3(16, 16), 256, 0, stream>>>(W_res, 1024, 0, Wtres_hi, Wtres_lo);
    gemm_bf16_kernel<<<dim3(8, 32), 256, 0, stream>>>(Awh, Awl, Wtres_hi, Wtres_lo, 2, out, nullptr);
}

// Round 3
// 817.176 us; speedup vs baseline: 1.6179x; 1.2586x over previous
//
#include <hip/hip_runtime.h>

#define INF30 1e30f
#define INV_TAU 0.08838834764831845f

typedef unsigned short ushort_t;
typedef __attribute__((ext_vector_type(8))) short bf16x8;
typedef __attribute__((ext_vector_type(4))) float f32x4;
typedef __attribute__((ext_vector_type(8))) unsigned short us8;

__device__ __forceinline__ float4 ld4(const float* p) { return *(const float4*)p; }

__device__ __forceinline__ unsigned short bf16_rne(float x) {
    unsigned int u = __float_as_uint(x);
    unsigned int r = u + 0x7fffu + ((u >> 16) & 1u);
    return (unsigned short)(r >> 16);
}
__device__ __forceinline__ float bf16_tof(unsigned short h) {
    return __uint_as_float(((unsigned int)h) << 16);
}
__device__ __forceinline__ bf16x8 ldb8(const ushort_t* p) { return *(const bf16x8*)p; }

#define MFMA16(a, b, c) __builtin_amdgcn_mfma_f32_16x16x32_bf16((a), (b), (c), 0, 0, 0)

// ---------------- LayerNorm over DM=1024 ----------------
__global__ __launch_bounds__(256) void ln_dm_kernel(const float* __restrict__ x, float* __restrict__ y) {
    size_t row = blockIdx.x;
    const float4* xr = (const float4*)(x + row * 1024);
    float4 v = xr[threadIdx.x];
    float s  = v.x + v.y + v.z + v.w;
    float ss = v.x*v.x + v.y*v.y + v.z*v.z + v.w*v.w;
#pragma unroll
    for (int off = 32; off > 0; off >>= 1) {
        s  += __shfl_down(s, off);
        ss += __shfl_down(ss, off);
    }
    __shared__ float rs[4], rss[4];
    int wv = threadIdx.x >> 6, ln = threadIdx.x & 63;
    if (ln == 0) { rs[wv] = s; rss[wv] = ss; }
    __syncthreads();
    s  = rs[0] + rs[1] + rs[2] + rs[3];
    ss = rss[0] + rss[1] + rss[2] + rss[3];
    float mu  = s * (1.0f/1024.0f);
    float var = ss * (1.0f/1024.0f) - mu*mu;
    float r = rsqrtf(var + 1e-6f);
    float4 o;
    o.x = (v.x - mu) * r; o.y = (v.y - mu) * r; o.z = (v.z - mu) * r; o.w = (v.w - mu) * r;
    ((float4*)(y + row * 1024))[threadIdx.x] = o;
}

// ---------------- fp32 tiled GEMM (k-columns only: argmin-critical path) ----------------
__global__ __launch_bounds__(256) void gemm_kernel(const float* __restrict__ A, const float* __restrict__ W,
                                                   int N, int mode,
                                                   float* __restrict__ o0, float* __restrict__ o1,
                                                   float* __restrict__ o2) {
    __shared__ float As[16][64];
    __shared__ float Bs[16][64];
    int t = threadIdx.x;
    int col0 = blockIdx.x << 6;
    int row0 = blockIdx.y << 6;
    int tx = t & 15, ty = t >> 4;
    int arow = t >> 2, akq = t & 3;
    int bkr = t >> 4, bcq = t & 15;
    const float* Ap = A + (size_t)(row0 + arow) * 1024 + akq * 4;
    const float* Wp = W + (size_t)bkr * N + col0 + bcq * 4;
    float acc[4][4];
#pragma unroll
    for (int i = 0; i < 4; ++i)
#pragma unroll
        for (int j = 0; j < 4; ++j) acc[i][j] = 0.0f;

    for (int kt = 0; kt < 64; ++kt) {
        float4 a4 = ld4(Ap + kt * 16);
        float4 b4 = ld4(Wp + (size_t)kt * 16 * N);
        __syncthreads();
        As[akq*4+0][arow] = a4.x;
        As[akq*4+1][arow] = a4.y;
        As[akq*4+2][arow] = a4.z;
        As[akq*4+3][arow] = a4.w;
        *(float4*)&Bs[bkr][bcq*4] = b4;
        __syncthreads();
#pragma unroll
        for (int kk = 0; kk < 16; ++kk) {
            float4 av = *(float4*)&As[kk][ty*4];
            float4 bv = *(float4*)&Bs[kk][tx*4];
            acc[0][0] += av.x*bv.x; acc[0][1] += av.x*bv.y; acc[0][2] += av.x*bv.z; acc[0][3] += av.x*bv.w;
            acc[1][0] += av.y*bv.x; acc[1][1] += av.y*bv.y; acc[1][2] += av.y*bv.z; acc[1][3] += av.y*bv.w;
            acc[2][0] += av.z*bv.x; acc[2][1] += av.z*bv.y; acc[2][2] += av.z*bv.z; acc[2][3] += av.z*bv.w;
            acc[3][0] += av.w*bv.x; acc[3][1] += av.w*bv.y; acc[3][2] += av.w*bv.z; acc[3][3] += av.w*bv.w;
        }
    }

#pragma unroll
    for (int i = 0; i < 4; ++i) {
        int rr = row0 + ty*4 + i;
        int b = rr >> 9, l = rr & 511;
#pragma unroll
        for (int j = 0; j < 4; ++j) {
            int cc = col0 + tx*4 + j;
            float vv = acc[i][j];
            if (mode == 0) {
                o0[((size_t)((b<<3) + (cc>>7)) * 512 + l) * 128 + (cc & 127)] = vv;
            } else if (mode == 1) {
                if (cc < 1024) {
                    o0[((size_t)((b<<3) + (cc>>7)) * 512 + l) * 128 + (cc & 127)] = vv;
                } else if (cc < 2048) {
                    int c2 = cc - 1024;
                    o1[((size_t)((b<<3) + (c2>>7)) * 512 + l) * 128 + (c2 & 127)] = vv;
                } else {
                    o2[(size_t)rr * 1024 + (cc - 2048)] = vv / (1.0f + __expf(-vv));
                }
            } else {
                o0[(size_t)rr * 1024 + cc] = vv;
            }
        }
    }
}

// ---------------- weight transpose + bf16 hi/lo split ----------------
__global__ __launch_bounds__(256) void wtsplit_kernel(const float* __restrict__ W, int Ntot, int c0,
                                                      ushort_t* __restrict__ th, ushort_t* __restrict__ tl) {
    __shared__ float T[64][68];
    int n0 = blockIdx.x << 6, k0 = blockIdx.y << 6, t = threadIdx.x;
    for (int i = t; i < 1024; i += 256) {
        int kk = i >> 4, nn4 = (i & 15) << 2;
        *(float4*)&T[kk][nn4] = ld4(W + (size_t)(k0 + kk) * Ntot + c0 + n0 + nn4);
    }
    __syncthreads();
    for (int i = t; i < 512; i += 256) {
        int nn = i >> 3, kc = (i & 7) << 3;
        us8 h8, l8;
#pragma unroll
        for (int j = 0; j < 8; ++j) {
            float x = T[kc + j][nn];
            unsigned short hh = bf16_rne(x);
            h8[j] = hh; l8[j] = bf16_rne(x - bf16_tof(hh));
        }
        size_t off = (size_t)(n0 + nn) * 1024 + k0 + kc;
        *(us8*)(th + off) = h8;
        *(us8*)(tl + off) = l8;
    }
}

// ---------------- bf16 3-term split GEMM ----------------
#define GSTRIDE 40
__global__ __launch_bounds__(256) void gemm_bf16_kernel(
        const ushort_t* __restrict__ Ah, const ushort_t* __restrict__ Al,
        const ushort_t* __restrict__ Bth, const ushort_t* __restrict__ Btl,
        int mode, float* __restrict__ o0, float* __restrict__ o1) {
    __shared__ ushort_t LA[2][128 * GSTRIDE];
    __shared__ ushort_t LB[2][128 * GSTRIDE];
    int t = threadIdx.x;
    int col0 = blockIdx.x << 7, row0 = blockIdx.y << 7;
    int wvid = t >> 6, ln = t & 63;
    int lcol = ln & 15, quad = ln >> 4;
    int qm = wvid >> 1, qn = wvid & 1;

    f32x4 C[4][4];
#pragma unroll
    for (int i = 0; i < 4; ++i)
#pragma unroll
        for (int j = 0; j < 4; ++j) C[i][j] = (f32x4){0.f, 0.f, 0.f, 0.f};

    for (int k0 = 0; k0 < 1024; k0 += 32) {
        us8 ra[2][2], rb[2][2];
#pragma unroll
        for (int v = 0; v < 2; ++v) {
            int cid = t + 256 * v;
            int row = cid >> 2, ch = cid & 3;
            size_t ga = (size_t)(row0 + row) * 1024 + k0 + ch * 8;
            size_t gb = (size_t)(col0 + row) * 1024 + k0 + ch * 8;
            ra[v][0] = *(const us8*)(Ah + ga);
            ra[v][1] = *(const us8*)(Al + ga);
            rb[v][0] = *(const us8*)(Bth + gb);
            rb[v][1] = *(const us8*)(Btl + gb);
        }
        __syncthreads();
#pragma unroll
        for (int v = 0; v < 2; ++v) {
            int cid = t + 256 * v;
            int row = cid >> 2, ch = cid & 3;
            *(us8*)&LA[0][row * GSTRIDE + ch * 8] = ra[v][0];
            *(us8*)&LA[1][row * GSTRIDE + ch * 8] = ra[v][1];
            *(us8*)&LB[0][row * GSTRIDE + ch * 8] = rb[v][0];
            *(us8*)&LB[1][row * GSTRIDE + ch * 8] = rb[v][1];
        }
        __syncthreads();
        bf16x8 afh[4], afl[4], bfh[4], bfl[4];
#pragma unroll
        for (int i = 0; i < 4; ++i) {
            int r = qm * 64 + i * 16 + lcol;
            afh[i] = *(const bf16x8*)&LA[0][r * GSTRIDE + quad * 8];
            afl[i] = *(const bf16x8*)&LA[1][r * GSTRIDE + quad * 8];
            int c = qn * 64 + i * 16 + lcol;
            bfh[i] = *(const bf16x8*)&LB[0][c * GSTRIDE + quad * 8];
            bfl[i] = *(const bf16x8*)&LB[1][c * GSTRIDE + quad * 8];
        }
#pragma unroll
        for (int i = 0; i < 4; ++i)
#pragma unroll
            for (int j = 0; j < 4; ++j) {
                C[i][j] = MFMA16(afh[i], bfh[j], C[i][j]);
                C[i][j] = MFMA16(afl[i], bfh[j], C[i][j]);
                C[i][j] = MFMA16(afh[i], bfl[j], C[i][j]);
            }
    }

#pragma unroll
    for (int i = 0; i < 4; ++i) {
#pragma unroll
        for (int r = 0; r < 4; ++r) {
            int rr = row0 + qm * 64 + 16 * i + quad * 4 + r;
            int b = rr >> 9, l = rr & 511;
#pragma unroll
            for (int j = 0; j < 4; ++j) {
                int cc = col0 + qn * 64 + 16 * j + lcol;
                float vv = C[i][j][r];
                if (mode == 0) {
                    o0[((size_t)((b<<3) + (cc>>7)) * 512 + l) * 128 + (cc & 127)] = vv;
                } else if (mode == 1) {
                    if (cc < 1024) o0[((size_t)((b<<3) + (cc>>7)) * 512 + l) * 128 + (cc & 127)] = vv;
                    else o1[(size_t)rr * 1024 + (cc - 1024)] = vv / (1.0f + __expf(-vv));
                } else {
                    o0[(size_t)rr * 1024 + cc] = vv;
                }
            }
        }
    }
}

// ---------------- LayerNorm over last dim 128 for q and k, in place ----------------
__global__ __launch_bounds__(256) void ln128_kernel(float* __restrict__ qb, float* __restrict__ kb) {
    int wv = threadIdx.x >> 6, ln = threadIdx.x & 63;
    int gw = (blockIdx.x << 2) + wv;
    float* base = (gw < 32768) ? qb : kb;
    int row = gw & 32767;
    float2 x = *(float2*)(base + (size_t)row * 128 + (ln << 1));
    float s  = x.x + x.y;
    float ss = x.x*x.x + x.y*x.y;
#pragma unroll
    for (int m = 32; m > 0; m >>= 1) { s += __shfl_xor(s, m); ss += __shfl_xor(ss, m); }
    float mu  = s * (1.0f/128.0f);
    float var = ss * (1.0f/128.0f) - mu*mu;
    float r = rsqrtf(var + 1e-6f);
    x.x = (x.x - mu) * r; x.y = (x.y - mu) * r;
    *(float2*)(base + (size_t)row * 128 + (ln << 1)) = x;
}

// ---------------- codebook transpose + norms ----------------
__global__ __launch_bounds__(256) void cbt_kernel(const float* __restrict__ cb, float* __restrict__ cT) {
    int idx = blockIdx.x * 256 + threadIdx.x;
    int h = idx >> 16, s = (idx >> 7) & 511, d = idx & 127;
    cT[((size_t)((h << 7) + d)) * 512 + s] = cb[idx];
}

__global__ __launch_bounds__(256) void cnorm_kernel(const float* __restrict__ cb, float* __restrict__ cn) {
    int wv = threadIdx.x >> 6, ln = threadIdx.x & 63;
    int row = (blockIdx.x << 2) + wv;
    float2 x = *(const float2*)(cb + (size_t)row * 128 + (ln << 1));
    float ss = x.x*x.x + x.y*x.y;
#pragma unroll
    for (int m = 32; m > 0; m >>= 1) ss += __shfl_xor(ss, m);
    if (ln == 0) cn[row] = ss;
}

// ---------------- VQ argmin (fp32) ----------------
__global__ __launch_bounds__(256) void vq_kernel(float* __restrict__ kb, const float* __restrict__ cT,
                                                 const float* __restrict__ cn, const float* __restrict__ cb) {
    __shared__ float sK[4][4][128];
    int wv = threadIdx.x >> 6, ln = threadIdx.x & 63;
    int gw = (blockIdx.x << 2) + wv;
    int bh = gw >> 7;
    int l4 = (gw & 127) << 2;
    int h = bh & 7;
    size_t r0 = ((size_t)bh << 9) + l4;
#pragma unroll
    for (int i = 0; i < 4; ++i) {
        float2 kx = *(const float2*)(kb + (r0 + i) * 128 + (ln << 1));
        sK[wv][i][(ln<<1)]   = kx.x;
        sK[wv][i][(ln<<1)+1] = kx.y;
    }
    __syncthreads();
    const float* ct = cT + ((size_t)h << 7) * 512;
    int s0 = ln << 3;
    float dt[4][8];
#pragma unroll
    for (int i = 0; i < 4; ++i)
#pragma unroll
        for (int j = 0; j < 8; ++j) dt[i][j] = 0.0f;

    for (int dc = 0; dc < 4; ++dc) {
        float ch[4][8];
#pragma unroll
        for (int i = 0; i < 4; ++i)
#pragma unroll
            for (int j = 0; j < 8; ++j) ch[i][j] = 0.0f;
#pragma unroll 4
        for (int d = dc * 32; d < dc * 32 + 32; ++d) {
            float4 c0 = ld4(ct + (size_t)d * 512 + s0);
            float4 c1 = ld4(ct + (size_t)d * 512 + s0 + 4);
#pragma unroll
            for (int i = 0; i < 4; ++i) {
                float kd = sK[wv][i][d];
                ch[i][0] += kd * c0.x; ch[i][1] += kd * c0.y; ch[i][2] += kd * c0.z; ch[i][3] += kd * c0.w;
                ch[i][4] += kd * c1.x; ch[i][5] += kd * c1.y; ch[i][6] += kd * c1.z; ch[i][7] += kd * c1.w;
            }
        }
#pragma unroll
        for (int i = 0; i < 4; ++i)
#pragma unroll
            for (int j = 0; j < 8; ++j) dt[i][j] += ch[i][j];
    }
    const float* cnh = cn + (h << 9);
#pragma unroll
    for (int i = 0; i < 4; ++i) {
        float bestv = cnh[s0] - 2.0f * dt[i][0];
        int bestz = s0;
#pragma unroll
        for (int j = 1; j < 8; ++j) {
            float scv = cnh[s0 + j] - 2.0f * dt[i][j];
            if (scv < bestv) { bestv = scv; bestz = s0 + j; }
        }
#pragma unroll
        for (int m = 32; m > 0; m >>= 1) {
            float ov = __shfl_xor(bestv, m);
            int   oz = __shfl_xor(bestz, m);
            if (ov < bestv || (ov == bestv && oz < bestz)) { bestv = ov; bestz = oz; }
        }
        float2 cz = *(const float2*)(cb + ((size_t)(h << 9) + bestz) * 128 + (ln << 1));
        *(float2*)(kb + (r0 + i) * 128 + (ln << 1)) = cz;
    }
}

// ---------------- prep kernels ----------------
__global__ __launch_bounds__(256) void split_q_kernel(const float* __restrict__ q,
        const float* __restrict__ xu, const float* __restrict__ xv,
        ushort_t* __restrict__ quh, ushort_t* __restrict__ qul,
        ushort_t* __restrict__ qvh) {
    int idx = blockIdx.x * 256 + threadIdx.x;
    int d = idx & 127;
    int h = (idx >> 16) & 7;
    float qv = q[idx];
    float a = qv + xu[(h << 7) + d];
    unsigned short ah = bf16_rne(a);
    quh[idx] = ah; qul[idx] = bf16_rne(a - bf16_tof(ah));
    float b = qv + xv[(h << 7) + d];
    qvh[idx] = bf16_rne(b);
}

__global__ __launch_bounds__(256) void split_plain_kernel(const float* __restrict__ src,
        ushort_t* __restrict__ hi, ushort_t* __restrict__ lo) {
    int idx = blockIdx.x * 256 + threadIdx.x;
    float x = src[idx];
    unsigned short h = bf16_rne(x);
    hi[idx] = h; lo[idx] = bf16_rne(x - bf16_tof(h));
}

__global__ __launch_bounds__(256) void cvt_hi_kernel(const float* __restrict__ src,
        ushort_t* __restrict__ hi) {
    int idx = blockIdx.x * 256 + threadIdx.x;
    hi[idx] = bf16_rne(src[idx]);
}

__global__ __launch_bounds__(256) void split_koff_kernel(const float* __restrict__ src,
        ushort_t* __restrict__ hi, ushort_t* __restrict__ lo, int rowoff) {
    int idx = blockIdx.x * 256 + threadIdx.x;
    int bh = idx >> 16, rem = idx & 65535;
    size_t dst = ((size_t)bh << 17) + ((size_t)rowoff << 7) + rem;
    float x = src[idx];
    unsigned short h = bf16_rne(x);
    hi[dst] = h; lo[dst] = bf16_rne(x - bf16_tof(h));
}

__global__ __launch_bounds__(256) void vtsplit_kernel(const float* __restrict__ srcA,
        const float* __restrict__ srcB, ushort_t* __restrict__ hi, ushort_t* __restrict__ lo, int NK) {
    __shared__ float T[64][132];
    int bh = blockIdx.x, kt = blockIdx.y, t = threadIdx.x;
    for (int i = t; i < 2048; i += 256) {
        int r = i >> 5, c4 = (i & 31) << 2;
        int key = (kt << 6) + r;
        const float* s = (key < 512) ? (srcA + ((size_t)bh * 512 + key) * 128 + c4)
                                     : (srcB + ((size_t)bh * 512 + (key - 512)) * 128 + c4);
        *(float4*)&T[r][c4] = ld4(s);
    }
    __syncthreads();
    for (int i = t; i < 1024; i += 256) {
        int vc = i >> 3, kk = (i & 7) << 3;
        us8 h8, l8;
#pragma unroll
        for (int j = 0; j < 8; ++j) {
            float x = T[kk + j][vc];
            unsigned short hh = bf16_rne(x);
            h8[j] = hh; l8[j] = bf16_rne(x - bf16_tof(hh));
        }
        size_t off = ((size_t)bh * 128 + vc) * NK + (kt << 6) + kk;
        *(us8*)(hi + off) = h8;
        *(us8*)(lo + off) = l8;
    }
}

__global__ __launch_bounds__(256) void cbias_kernel(const float* __restrict__ al, float* __restrict__ cb) {
    int idx = blockIdx.x * 256 + threadIdx.x;
    float v = al[idx];
    cb[idx] = (v > 0.0f) ? __logf(fmaxf(v, 1e-30f)) : -INF30;
}

// ---------------- attn8: LDS-staged K/V shared by 4 waves, 4 q-tiles/block ----------------
// 512 blocks x 4 waves; bh = 8*(idx>>3) + (blk&7) pins each bh's 8 blocks to one XCD.
// Block j owns q-tiles {j, 15-j, 16+j, 31-j} (one per wave) -> per-block Tt = 32+nt2(31-j)
// = 45..48, balanced. All 4 waves walk the SAME ti stream; K tile (32x128 hi+lo) is LDS
// double-buffered (stage ti+1 during compute of ti), V tile (128x32 hi+lo) single-buffered
// within the iteration. Staging is reg-staged (global->VGPR issued right after barrier A,
// ds_write late) so HBM/L2 latency hides under G+QK+softmax. XOR swizzles keep all
// ds_read_b128 at 2-way bank aliasing (free): K chunk^=(row&7); V chunk^=((v>>1)&3).
// Qu hi/lo AND Qv are persistent registers (96 VGPR); per-ti global loads drop 56 -> ~20.
// No split-K: each wave owns its tile's full softmax state; direct gated write-out.
#define PSTR 40
__global__ __launch_bounds__(256, 2) void attn8_kernel(
        const ushort_t* __restrict__ Qu_hi, const ushort_t* __restrict__ Qu_lo,
        const ushort_t* __restrict__ Qv_hi,
        const ushort_t* __restrict__ K_hi,  const ushort_t* __restrict__ K_lo,
        const ushort_t* __restrict__ C_hi,  const ushort_t* __restrict__ C_lo,
        const ushort_t* __restrict__ Vt_hi, const ushort_t* __restrict__ Vt_lo,
        const ushort_t* __restrict__ At_hi, const ushort_t* __restrict__ At_lo,
        const ushort_t* __restrict__ R_hi,
        const float* __restrict__ cbias, const float* __restrict__ gbuf,
        float* __restrict__ wvg) {
    __shared__ __align__(16) ushort_t KS[2][2][32 * 128];  // [buf][hi/lo], swizzled
    __shared__ __align__(16) ushort_t VS[2][128 * 32];     // [hi/lo], swizzled
    __shared__ __align__(16) ushort_t Phs[4][16 * PSTR];
    __shared__ __align__(16) ushort_t Pls[4][16 * PSTR];

    int t = threadIdx.x;
    int wvid = t >> 6, ln = t & 63;
    int col = ln & 15, quad = ln >> 4;
    int blk = blockIdx.x;
    int xcd = blk & 7, idx = blk >> 3;
    int bh = ((idx >> 3) << 3) + xcd;
    int j = idx & 7;
    int jt = ((wvid & 1) ? (15 - j) : j) + ((wvid & 2) ? 16 : 0);
    int l0 = jt << 4;
    int h = bh & 7, b = bh >> 3;

    int nt2own = (l0 + 47) >> 5;
    int nt2max = (((31 - j) << 4) + 47) >> 5;
    int Tt = 32 + nt2max;

    // persistent Q fragments (prologue loads only)
    size_t qb = ((size_t)bh * 512 + l0 + col) * 128 + quad * 8;
    bf16x8 quh[4], qul[4], qvf[4];
#pragma unroll
    for (int s = 0; s < 4; ++s) {
        quh[s] = ldb8(Qu_hi + qb + 32 * s);
        qul[s] = ldb8(Qu_lo + qb + 32 * s);
        qvf[s] = ldb8(Qv_hi + qb + 32 * s);
    }

    f32x4 O[8];
#pragma unroll
    for (int u = 0; u < 8; ++u) O[u] = (f32x4){0.f, 0.f, 0.f, 0.f};
    float mrun[4], lrun[4];
#pragma unroll
    for (int r = 0; r < 4; ++r) { mrun[r] = -INF30; lrun[r] = 0.0f; }

    ushort_t* Ph = Phs[wvid];
    ushort_t* Pl = Pls[wvid];

    // ---- prologue: stage K tile for ti=0 (seg0, w0=0) ----
    {
        const ushort_t* nkh = K_hi + ((size_t)bh * 1024) * 128;
        const ushort_t* nkl = K_lo + ((size_t)bh * 1024) * 128;
#pragma unroll
        for (int m = 0; m < 2; ++m) {
            int r = wvid * 8 + m * 4 + (ln >> 4);
            int c = ln & 15;
            us8 vh8 = *(const us8*)(nkh + (size_t)r * 128 + c * 8);
            us8 vl8 = *(const us8*)(nkl + (size_t)r * 128 + c * 8);
            int dst = r * 128 + ((c ^ (r & 7)) << 3);
            *(us8*)&KS[0][0][dst] = vh8;
            *(us8*)&KS[0][1][dst] = vl8;
        }
    }
    int cur = 0;

    for (int ti = 0; ti < Tt; ++ti) {
        int seg, w0;
        if (ti < 16)      { seg = 0; w0 = ti << 5; }
        else if (ti < 32) { seg = 1; w0 = (ti - 16) << 5; }
        else              { seg = 2; w0 = (ti - 32) << 5; }
        bool act = (seg != 2) || ((ti - 32) < nt2own);
        bool hasNext = (ti + 1) < Tt;

        __syncthreads();   // BARRIER A: KS[cur] ready; VS free for rewrite

        // ---- issue next-K global loads early (consumed by ds_write below) ----
        us8 krh[2], krl[2];
        if (hasNext) {
            int tn = ti + 1;
            const ushort_t *nkh, *nkl;
            if (tn < 16) {
                nkh = K_hi + ((size_t)bh * 1024 + (tn << 5)) * 128;
                nkl = K_lo + ((size_t)bh * 1024 + (tn << 5)) * 128;
            } else if (tn < 32) {
                nkh = C_hi + ((size_t)(h << 9) + ((tn - 16) << 5)) * 128;
                nkl = C_lo + ((size_t)(h << 9) + ((tn - 16) << 5)) * 128;
            } else {
                nkh = K_hi + ((size_t)bh * 1024 + 512 + ((tn - 32) << 5)) * 128;
                nkl = K_lo + ((size_t)bh * 1024 + 512 + ((tn - 32) << 5)) * 128;
            }
#pragma unroll
            for (int m = 0; m < 2; ++m) {
                int r = wvid * 8 + m * 4 + (ln >> 4);
                int c = ln & 15;
                krh[m] = *(const us8*)(nkh + (size_t)r * 128 + c * 8);
                krl[m] = *(const us8*)(nkl + (size_t)r * 128 + c * 8);
            }
        }

        // ---- issue V global loads for current ti ----
        const ushort_t *vhp, *vlp; size_t vstr; int wbase;
        if (seg == 0)      { vhp = Vt_hi + ((size_t)bh << 17); vlp = Vt_lo + ((size_t)bh << 17); vstr = 1024; wbase = w0; }
        else if (seg == 1) { vhp = At_hi + ((size_t)bh << 16); vlp = At_lo + ((size_t)bh << 16); vstr = 512;  wbase = w0; }
        else               { vhp = Vt_hi + ((size_t)bh << 17); vlp = Vt_lo + ((size_t)bh << 17); vstr = 1024; wbase = 512 + w0; }
        us8 vrh[2], vrl[2];
#pragma unroll
        for (int m = 0; m < 2; ++m) {
            int dV = wvid * 128 + m * 64 + ln;
            int v = dV >> 2, c = dV & 3;
            vrh[m] = *(const us8*)(vhp + (size_t)v * vstr + wbase + c * 8);
            vrl[m] = *(const us8*)(vlp + (size_t)v * vstr + wbase + c * 8);
        }

        // ---- G phase (rel-pos scores; R from L2-hot global, Qv persistent) ----
        f32x4 Gacc[3];
        f32x4 S[2];
        if (act) {
            if (seg != 1) {
                int jt0 = ((seg == 0) ? w0 : (512 + w0)) + 496 - l0;
#pragma unroll
                for (int u = 0; u < 3; ++u) {
                    int jr = jt0 + 16 * u + col;
                    jr = (jr > 1023) ? 1023 : jr;
                    const ushort_t* rp = R_hi + ((size_t)(h << 10) + jr) * 128 + quad * 8;
                    f32x4 acc = (f32x4){0.f, 0.f, 0.f, 0.f};
                    acc = MFMA16(qvf[0], ldb8(rp), acc);
                    acc = MFMA16(qvf[1], ldb8(rp + 32), acc);
                    acc = MFMA16(qvf[2], ldb8(rp + 64), acc);
                    acc = MFMA16(qvf[3], ldb8(rp + 96), acc);
                    Gacc[u] = acc;
                }
            }

            // ---- QK^T from LDS K[cur] (swizzled ds_read_b128, 2-way = free) ----
            S[0] = (f32x4){0.f, 0.f, 0.f, 0.f};
            S[1] = (f32x4){0.f, 0.f, 0.f, 0.f};
            const ushort_t* KH = KS[cur][0];
            const ushort_t* KL = KS[cur][1];
            int swz = col & 7;
#pragma unroll
            for (int s = 0; s < 4; ++s) {
                int cofs = ((quad + 4 * s) ^ swz) << 3;
                bf16x8 k0h = *(const bf16x8*)&KH[col * 128 + cofs];
                bf16x8 k0l = *(const bf16x8*)&KL[col * 128 + cofs];
                bf16x8 k1h = *(const bf16x8*)&KH[(16 + col) * 128 + cofs];
                bf16x8 k1l = *(const bf16x8*)&KL[(16 + col) * 128 + cofs];
                S[0] = MFMA16(quh[s], k0h, S[0]);
                S[0] = MFMA16(qul[s], k0h, S[0]);
                S[0] = MFMA16(quh[s], k0l, S[0]);
                S[1] = MFMA16(quh[s], k1h, S[1]);
                S[1] = MFMA16(qul[s], k1h, S[1]);
                S[1] = MFMA16(quh[s], k1l, S[1]);
            }
        }

        // ---- late ds_writes: K[next] and V (loads have had G+QK to complete) ----
        if (hasNext) {
#pragma unroll
            for (int m = 0; m < 2; ++m) {
                int r = wvid * 8 + m * 4 + (ln >> 4);
                int c = ln & 15;
                int dst = r * 128 + ((c ^ (r & 7)) << 3);
                *(us8*)&KS[cur ^ 1][0][dst] = krh[m];
                *(us8*)&KS[cur ^ 1][1][dst] = krl[m];
            }
        }
#pragma unroll
        for (int m = 0; m < 2; ++m) {
            int dV = wvid * 128 + m * 64 + ln;
            int v = dV >> 2, c = dV & 3;
            int dst = v * 32 + ((c ^ ((v >> 1) & 3)) << 3);
            *(us8*)&VS[0][dst] = vrh[m];
            *(us8*)&VS[1][dst] = vrl[m];
        }

        // ---- fixup + online softmax + P frags ----
        bf16x8 pah = {}, pal = {};
        if (act) {
            float bias0 = 0.f, bias1 = 0.f;
            if (seg == 1) {
                bias0 = cbias[(size_t)(bh << 9) + w0 + col];
                bias1 = cbias[(size_t)(bh << 9) + w0 + 16 + col];
            }
#pragma unroll
            for (int t2 = 0; t2 < 2; ++t2) {
#pragma unroll
                for (int r = 0; r < 4; ++r) {
                    int row = 4 * quad + r;
                    float sv = S[t2][r];
                    if (seg != 1) {
                        int d = col + 15 - row;
                        int src = quad * 16 + (d & 15);
                        float g0 = __shfl(Gacc[t2][r], src);
                        float g1 = __shfl(Gacc[t2 + 1][r], src);
                        float gv = (d >= 16) ? g1 : g0;
                        sv = (sv + gv) * INV_TAU;
                        if (seg == 2 && (w0 + 16 * t2 + col > l0 + row)) sv = -INF30;
                    } else {
                        sv = sv * INV_TAU + ((t2 == 0) ? bias0 : bias1);
                    }
                    S[t2][r] = sv;
                }
            }
#pragma unroll
            for (int r = 0; r < 4; ++r) {
                float mv = fmaxf(S[0][r], S[1][r]);
#pragma unroll
                for (int m = 8; m > 0; m >>= 1) mv = fmaxf(mv, __shfl_xor(mv, m));
                float mnew = fmaxf(mrun[r], mv);
                float alpha = __expf(mrun[r] - mnew);
                mrun[r] = mnew;
                float p0 = __expf(S[0][r] - mnew);
                float p1 = __expf(S[1][r] - mnew);
                float ps = p0 + p1;
#pragma unroll
                for (int m = 8; m > 0; m >>= 1) ps += __shfl_xor(ps, m);
                lrun[r] = lrun[r] * alpha + ps;
#pragma unroll
                for (int u = 0; u < 8; ++u) O[u][r] *= alpha;
                int row = 4 * quad + r;
                unsigned short h0 = bf16_rne(p0);
                Ph[row * PSTR + col] = h0;
                Pl[row * PSTR + col] = bf16_rne(p0 - bf16_tof(h0));
                unsigned short h1 = bf16_rne(p1);
                Ph[row * PSTR + 16 + col] = h1;
                Pl[row * PSTR + 16 + col] = bf16_rne(p1 - bf16_tof(h1));
            }
            pah = *(const bf16x8*)&Ph[col * PSTR + quad * 8];
            pal = *(const bf16x8*)&Pl[col * PSTR + quad * 8];
        }

        __syncthreads();   // BARRIER B: VS staged by all waves

        // ---- PV from LDS V (swizzled reads, 2-way = free) ----
        if (act) {
            const ushort_t* VH = VS[0];
            const ushort_t* VL = VS[1];
            int vswz = (quad ^ ((col >> 1) & 3)) << 3;
#pragma unroll
            for (int u = 0; u < 8; ++u) {
                int vrow = 16 * u + col;
                bf16x8 vbh = *(const bf16x8*)&VH[vrow * 32 + vswz];
                bf16x8 vbl = *(const bf16x8*)&VL[vrow * 32 + vswz];
                O[u] = MFMA16(pah, vbh, O[u]);
                O[u] = MFMA16(pal, vbh, O[u]);
                O[u] = MFMA16(pah, vbl, O[u]);
            }
        }
        cur ^= 1;
    }

    // ---- direct gated write-out (no split-K combine) ----
#pragma unroll
    for (int r = 0; r < 4; ++r) {
        int row = quad * 4 + r;
        float linv = 1.0f / lrun[r];
#pragma unroll
        for (int u = 0; u < 8; ++u) {
            size_t gi = ((size_t)b * 512 + l0 + row) * 1024 + (h << 7) + 16 * u + col;
            wvg[gi] = O[u][r] * linv * gbuf[gi];
        }
    }
}

extern "C" void kernel_launch(void* const* d_in, const int* in_sizes, int n_in,
                              void* d_out, int out_size, void* d_ws, size_t ws_size,
                              hipStream_t stream) {
    const float* x_in  = (const float*)d_in[0];
    const float* xl_k  = (const float*)d_in[2];
    const float* xl_v  = (const float*)d_in[3];
    const float* agg_u = (const float*)d_in[4];
    const float* agg_l = (const float*)d_in[5];
    const float* W_q   = (const float*)d_in[6];
    const float* W_kvg = (const float*)d_in[7];
    const float* W_res = (const float*)d_in[8];
    const float* x_u   = (const float*)d_in[9];
    const float* x_v   = (const float*)d_in[10];
    const float* xl_r  = (const float*)d_in[11];
    const float* cbk   = (const float*)d_in[12];
    float* out = (float*)d_out;
    char* wb = (char*)d_ws;

    float*  x_t   = (float*)(wb);                       // 16 MB [alias: K_hi; later Awh/Awl]
    float*  qbuf  = (float*)(wb + 16777216ul);          // 16 MB [alias: Vt_lo]
    float*  kbuf  = (float*)(wb + 33554432ul);          // 16 MB [alias: Vt_hi]
    float*  vbuf  = (float*)(wb + 50331648ul);          // 16 MB [alias: At_hi+At_lo]
    float*  gbuf  = (float*)(wb + 67108864ul);          // 16 MB
    float*  wvg   = (float*)(wb + 83886080ul);          // 16 MB [alias: Ah+Al pre-attn]
    float*  cT    = (float*)(wb + 100663296ul);         // 2 MB  [alias: C_hi+C_lo]
    float*  cnm   = (float*)(wb + 102760448ul);         // 16 KB
    ushort_t* Qu_hi = (ushort_t*)(wb + 102776832ul);    // 8 MB  [alias: Wtq pre-split]
    ushort_t* Qu_lo = (ushort_t*)(wb + 111165440ul);    // 8 MB  [alias: Wtvg pre-split]
    ushort_t* Qv_hi = (ushort_t*)(wb + 119554048ul);    // 8 MB  [alias: Wtres post-attn]
    ushort_t* K_lo  = (ushort_t*)(wb + 136331264ul);    // 16 MB
    ushort_t* R_hi  = (ushort_t*)(wb + 153108480ul);    // 2 MB
    float*  cbias   = (float*)(wb + 157302784ul);       // 128 KB

    ushort_t* K_hi  = (ushort_t*)x_t;
    ushort_t* Vt_hi = (ushort_t*)kbuf;
    ushort_t* Vt_lo = (ushort_t*)qbuf;
    ushort_t* At_hi = (ushort_t*)vbuf;
    ushort_t* At_lo = (ushort_t*)(wb + 50331648ul + 8388608ul);
    ushort_t* C_hi  = (ushort_t*)cT;
    ushort_t* C_lo  = (ushort_t*)(wb + 100663296ul + 1048576ul);

    ushort_t* Ah      = (ushort_t*)wvg;
    ushort_t* Al      = (ushort_t*)(wb + 83886080ul + 8388608ul);
    ushort_t* Wtq_hi  = (ushort_t*)Qu_hi;
    ushort_t* Wtq_lo  = (ushort_t*)(wb + 102776832ul + 2097152ul);
    ushort_t* Wtvg_hi = (ushort_t*)Qu_lo;
    ushort_t* Wtvg_lo = (ushort_t*)(wb + 111165440ul + 4194304ul);
    ushort_t* Wtres_hi = (ushort_t*)Qv_hi;
    ushort_t* Wtres_lo = (ushort_t*)(wb + 119554048ul + 2097152ul);
    ushort_t* Awh     = (ushort_t*)x_t;
    ushort_t* Awl     = (ushort_t*)(wb + 8388608ul);

    // 1) input LN
    ln_dm_kernel<<<4096, 256, 0, stream>>>(x_in, x_t);
    // 2) split activations + weights for bf16 GEMMs
    split_plain_kernel<<<16384, 256, 0, stream>>>(x_t, Ah, Al);
    wtsplit_kernel<<<dim3(16, 16), 256, 0, stream>>>(W_q, 1024, 0, Wtq_hi, Wtq_lo);
    wtsplit_kernel<<<dim3(32, 16), 256, 0, stream>>>(W_kvg, 3072, 1024, Wtvg_hi, Wtvg_lo);
    // 3) GEMMs: q (bf16), v+g (bf16), k (fp32 — argmin-critical)
    gemm_bf16_kernel<<<dim3(8, 32), 256, 0, stream>>>(Ah, Al, Wtq_hi, Wtq_lo, 0, qbuf, nullptr);
    gemm_bf16_kernel<<<dim3(16, 32), 256, 0, stream>>>(Ah, Al, Wtvg_hi, Wtvg_lo, 1, vbuf, gbuf);
    gemm_kernel<<<dim3(16, 64), 256, 0, stream>>>(x_t, W_kvg, 3072, 0, kbuf, nullptr, nullptr);
    // 4) LN(q), LN(k); VQ
    ln128_kernel<<<16384, 256, 0, stream>>>(qbuf, kbuf);
    cbt_kernel<<<2048, 256, 0, stream>>>(cbk, cT);
    cnorm_kernel<<<1024, 256, 0, stream>>>(cbk, cnm);
    vq_kernel<<<2048, 256, 0, stream>>>(kbuf, cT, cnm, cbk);
    // 5) attention preps
    split_q_kernel<<<16384, 256, 0, stream>>>(qbuf, x_u, x_v, Qu_hi, Qu_lo, Qv_hi);
    split_koff_kernel<<<16384, 256, 0, stream>>>(xl_k, K_hi, K_lo, 0);
    split_koff_kernel<<<16384, 256, 0, stream>>>(kbuf, K_hi, K_lo, 512);
    split_plain_kernel<<<2048, 256, 0, stream>>>(cbk, C_hi, C_lo);
    cvt_hi_kernel<<<4096, 256, 0, stream>>>(xl_r, R_hi);
    vtsplit_kernel<<<dim3(64, 16), 256, 0, stream>>>(xl_v, vbuf, Vt_hi, Vt_lo, 1024);
    vtsplit_kernel<<<dim3(64, 8), 256, 0, stream>>>(agg_u, agg_u, At_hi, At_lo, 512);
    cbias_kernel<<<128, 256, 0, stream>>>(agg_l, cbias);
    // 6) LDS-staged shared-K/V fused attention (4 q-tiles per block)
    attn8_kernel<<<512, 256, 0, stream>>>(Qu_hi, Qu_lo, Qv_hi, K_hi, K_lo, C_hi, C_lo,
                                          Vt_hi, Vt_lo, At_hi, At_lo, R_hi,
                                          cbias, gbuf, wvg);
    // 7) output GEMM (bf16)
    split_plain_kernel<<<16384, 256, 0, stream>>>(wvg, Awh, Awl);
    wtsplit_kernel<<<dim3(16, 16), 256, 0, stream>>>(W_res, 1024, 0, Wtres_hi, Wtres_lo);
    gemm_bf16_kernel<<<dim3(8, 32), 256, 0, stream>>>(Awh, Awl, Wtres_hi, Wtres_lo, 2, out, nullptr);
}

// Round 4
// 796.896 us; speedup vs baseline: 1.6591x; 1.0254x over previous
//
#include <hip/hip_runtime.h>

#define INF30 1e30f
#define INV_TAU 0.08838834764831845f

typedef unsigned short ushort_t;
typedef __attribute__((ext_vector_type(8))) short bf16x8;
typedef __attribute__((ext_vector_type(4))) float f32x4;
typedef __attribute__((ext_vector_type(8))) unsigned short us8;

__device__ __forceinline__ float4 ld4(const float* p) { return *(const float4*)p; }

__device__ __forceinline__ unsigned short bf16_rne(float x) {
    unsigned int u = __float_as_uint(x);
    unsigned int r = u + 0x7fffu + ((u >> 16) & 1u);
    return (unsigned short)(r >> 16);
}
__device__ __forceinline__ float bf16_tof(unsigned short h) {
    return __uint_as_float(((unsigned int)h) << 16);
}
__device__ __forceinline__ bf16x8 ldb8(const ushort_t* p) { return *(const bf16x8*)p; }

#define MFMA16(a, b, c) __builtin_amdgcn_mfma_f32_16x16x32_bf16((a), (b), (c), 0, 0, 0)

// ---------------- LayerNorm over DM=1024 ----------------
__global__ __launch_bounds__(256) void ln_dm_kernel(const float* __restrict__ x, float* __restrict__ y) {
    size_t row = blockIdx.x;
    const float4* xr = (const float4*)(x + row * 1024);
    float4 v = xr[threadIdx.x];
    float s  = v.x + v.y + v.z + v.w;
    float ss = v.x*v.x + v.y*v.y + v.z*v.z + v.w*v.w;
#pragma unroll
    for (int off = 32; off > 0; off >>= 1) {
        s  += __shfl_down(s, off);
        ss += __shfl_down(ss, off);
    }
    __shared__ float rs[4], rss[4];
    int wv = threadIdx.x >> 6, ln = threadIdx.x & 63;
    if (ln == 0) { rs[wv] = s; rss[wv] = ss; }
    __syncthreads();
    s  = rs[0] + rs[1] + rs[2] + rs[3];
    ss = rss[0] + rss[1] + rss[2] + rss[3];
    float mu  = s * (1.0f/1024.0f);
    float var = ss * (1.0f/1024.0f) - mu*mu;
    float r = rsqrtf(var + 1e-6f);
    float4 o;
    o.x = (v.x - mu) * r; o.y = (v.y - mu) * r; o.z = (v.z - mu) * r; o.w = (v.w - mu) * r;
    ((float4*)(y + row * 1024))[threadIdx.x] = o;
}

// ---------------- fp32 tiled GEMM (k-columns only: argmin-critical path) ----------------
__global__ __launch_bounds__(256) void gemm_kernel(const float* __restrict__ A, const float* __restrict__ W,
                                                   int N, int mode,
                                                   float* __restrict__ o0, float* __restrict__ o1,
                                                   float* __restrict__ o2) {
    __shared__ float As[16][64];
    __shared__ float Bs[16][64];
    int t = threadIdx.x;
    int col0 = blockIdx.x << 6;
    int row0 = blockIdx.y << 6;
    int tx = t & 15, ty = t >> 4;
    int arow = t >> 2, akq = t & 3;
    int bkr = t >> 4, bcq = t & 15;
    const float* Ap = A + (size_t)(row0 + arow) * 1024 + akq * 4;
    const float* Wp = W + (size_t)bkr * N + col0 + bcq * 4;
    float acc[4][4];
#pragma unroll
    for (int i = 0; i < 4; ++i)
#pragma unroll
        for (int j = 0; j < 4; ++j) acc[i][j] = 0.0f;

    for (int kt = 0; kt < 64; ++kt) {
        float4 a4 = ld4(Ap + kt * 16);
        float4 b4 = ld4(Wp + (size_t)kt * 16 * N);
        __syncthreads();
        As[akq*4+0][arow] = a4.x;
        As[akq*4+1][arow] = a4.y;
        As[akq*4+2][arow] = a4.z;
        As[akq*4+3][arow] = a4.w;
        *(float4*)&Bs[bkr][bcq*4] = b4;
        __syncthreads();
#pragma unroll
        for (int kk = 0; kk < 16; ++kk) {
            float4 av = *(float4*)&As[kk][ty*4];
            float4 bv = *(float4*)&Bs[kk][tx*4];
            acc[0][0] += av.x*bv.x; acc[0][1] += av.x*bv.y; acc[0][2] += av.x*bv.z; acc[0][3] += av.x*bv.w;
            acc[1][0] += av.y*bv.x; acc[1][1] += av.y*bv.y; acc[1][2] += av.y*bv.z; acc[1][3] += av.y*bv.w;
            acc[2][0] += av.z*bv.x; acc[2][1] += av.z*bv.y; acc[2][2] += av.z*bv.z; acc[2][3] += av.z*bv.w;
            acc[3][0] += av.w*bv.x; acc[3][1] += av.w*bv.y; acc[3][2] += av.w*bv.z; acc[3][3] += av.w*bv.w;
        }
    }

#pragma unroll
    for (int i = 0; i < 4; ++i) {
        int rr = row0 + ty*4 + i;
        int b = rr >> 9, l = rr & 511;
#pragma unroll
        for (int j = 0; j < 4; ++j) {
            int cc = col0 + tx*4 + j;
            float vv = acc[i][j];
            if (mode == 0) {
                o0[((size_t)((b<<3) + (cc>>7)) * 512 + l) * 128 + (cc & 127)] = vv;
            } else if (mode == 1) {
                if (cc < 1024) {
                    o0[((size_t)((b<<3) + (cc>>7)) * 512 + l) * 128 + (cc & 127)] = vv;
                } else if (cc < 2048) {
                    int c2 = cc - 1024;
                    o1[((size_t)((b<<3) + (c2>>7)) * 512 + l) * 128 + (c2 & 127)] = vv;
                } else {
                    o2[(size_t)rr * 1024 + (cc - 2048)] = vv / (1.0f + __expf(-vv));
                }
            } else {
                o0[(size_t)rr * 1024 + cc] = vv;
            }
        }
    }
}

// ---------------- weight transpose + bf16 hi/lo split ----------------
__global__ __launch_bounds__(256) void wtsplit_kernel(const float* __restrict__ W, int Ntot, int c0,
                                                      ushort_t* __restrict__ th, ushort_t* __restrict__ tl) {
    __shared__ float T[64][68];
    int n0 = blockIdx.x << 6, k0 = blockIdx.y << 6, t = threadIdx.x;
    for (int i = t; i < 1024; i += 256) {
        int kk = i >> 4, nn4 = (i & 15) << 2;
        *(float4*)&T[kk][nn4] = ld4(W + (size_t)(k0 + kk) * Ntot + c0 + n0 + nn4);
    }
    __syncthreads();
    for (int i = t; i < 512; i += 256) {
        int nn = i >> 3, kc = (i & 7) << 3;
        us8 h8, l8;
#pragma unroll
        for (int j = 0; j < 8; ++j) {
            float x = T[kc + j][nn];
            unsigned short hh = bf16_rne(x);
            h8[j] = hh; l8[j] = bf16_rne(x - bf16_tof(hh));
        }
        size_t off = (size_t)(n0 + nn) * 1024 + k0 + kc;
        *(us8*)(th + off) = h8;
        *(us8*)(tl + off) = l8;
    }
}

// ---------------- bf16 3-term split GEMM ----------------
#define GSTRIDE 40
__global__ __launch_bounds__(256) void gemm_bf16_kernel(
        const ushort_t* __restrict__ Ah, const ushort_t* __restrict__ Al,
        const ushort_t* __restrict__ Bth, const ushort_t* __restrict__ Btl,
        int mode, float* __restrict__ o0, float* __restrict__ o1) {
    __shared__ ushort_t LA[2][128 * GSTRIDE];
    __shared__ ushort_t LB[2][128 * GSTRIDE];
    int t = threadIdx.x;
    int col0 = blockIdx.x << 7, row0 = blockIdx.y << 7;
    int wvid = t >> 6, ln = t & 63;
    int lcol = ln & 15, quad = ln >> 4;
    int qm = wvid >> 1, qn = wvid & 1;

    f32x4 C[4][4];
#pragma unroll
    for (int i = 0; i < 4; ++i)
#pragma unroll
        for (int j = 0; j < 4; ++j) C[i][j] = (f32x4){0.f, 0.f, 0.f, 0.f};

    for (int k0 = 0; k0 < 1024; k0 += 32) {
        us8 ra[2][2], rb[2][2];
#pragma unroll
        for (int v = 0; v < 2; ++v) {
            int cid = t + 256 * v;
            int row = cid >> 2, ch = cid & 3;
            size_t ga = (size_t)(row0 + row) * 1024 + k0 + ch * 8;
            size_t gb = (size_t)(col0 + row) * 1024 + k0 + ch * 8;
            ra[v][0] = *(const us8*)(Ah + ga);
            ra[v][1] = *(const us8*)(Al + ga);
            rb[v][0] = *(const us8*)(Bth + gb);
            rb[v][1] = *(const us8*)(Btl + gb);
        }
        __syncthreads();
#pragma unroll
        for (int v = 0; v < 2; ++v) {
            int cid = t + 256 * v;
            int row = cid >> 2, ch = cid & 3;
            *(us8*)&LA[0][row * GSTRIDE + ch * 8] = ra[v][0];
            *(us8*)&LA[1][row * GSTRIDE + ch * 8] = ra[v][1];
            *(us8*)&LB[0][row * GSTRIDE + ch * 8] = rb[v][0];
            *(us8*)&LB[1][row * GSTRIDE + ch * 8] = rb[v][1];
        }
        __syncthreads();
        bf16x8 afh[4], afl[4], bfh[4], bfl[4];
#pragma unroll
        for (int i = 0; i < 4; ++i) {
            int r = qm * 64 + i * 16 + lcol;
            afh[i] = *(const bf16x8*)&LA[0][r * GSTRIDE + quad * 8];
            afl[i] = *(const bf16x8*)&LA[1][r * GSTRIDE + quad * 8];
            int c = qn * 64 + i * 16 + lcol;
            bfh[i] = *(const bf16x8*)&LB[0][c * GSTRIDE + quad * 8];
            bfl[i] = *(const bf16x8*)&LB[1][c * GSTRIDE + quad * 8];
        }
#pragma unroll
        for (int i = 0; i < 4; ++i)
#pragma unroll
            for (int j = 0; j < 4; ++j) {
                C[i][j] = MFMA16(afh[i], bfh[j], C[i][j]);
                C[i][j] = MFMA16(afl[i], bfh[j], C[i][j]);
                C[i][j] = MFMA16(afh[i], bfl[j], C[i][j]);
            }
    }

#pragma unroll
    for (int i = 0; i < 4; ++i) {
#pragma unroll
        for (int r = 0; r < 4; ++r) {
            int rr = row0 + qm * 64 + 16 * i + quad * 4 + r;
            int b = rr >> 9, l = rr & 511;
#pragma unroll
            for (int j = 0; j < 4; ++j) {
                int cc = col0 + qn * 64 + 16 * j + lcol;
                float vv = C[i][j][r];
                if (mode == 0) {
                    o0[((size_t)((b<<3) + (cc>>7)) * 512 + l) * 128 + (cc & 127)] = vv;
                } else if (mode == 1) {
                    if (cc < 1024) o0[((size_t)((b<<3) + (cc>>7)) * 512 + l) * 128 + (cc & 127)] = vv;
                    else o1[(size_t)rr * 1024 + (cc - 1024)] = vv / (1.0f + __expf(-vv));
                } else {
                    o0[(size_t)rr * 1024 + cc] = vv;
                }
            }
        }
    }
}

// ---------------- LayerNorm over last dim 128 for q and k, in place ----------------
__global__ __launch_bounds__(256) void ln128_kernel(float* __restrict__ qb, float* __restrict__ kb) {
    int wv = threadIdx.x >> 6, ln = threadIdx.x & 63;
    int gw = (blockIdx.x << 2) + wv;
    float* base = (gw < 32768) ? qb : kb;
    int row = gw & 32767;
    float2 x = *(float2*)(base + (size_t)row * 128 + (ln << 1));
    float s  = x.x + x.y;
    float ss = x.x*x.x + x.y*x.y;
#pragma unroll
    for (int m = 32; m > 0; m >>= 1) { s += __shfl_xor(s, m); ss += __shfl_xor(ss, m); }
    float mu  = s * (1.0f/128.0f);
    float var = ss * (1.0f/128.0f) - mu*mu;
    float r = rsqrtf(var + 1e-6f);
    x.x = (x.x - mu) * r; x.y = (x.y - mu) * r;
    *(float2*)(base + (size_t)row * 128 + (ln << 1)) = x;
}

// ---------------- codebook transpose + norms ----------------
__global__ __launch_bounds__(256) void cbt_kernel(const float* __restrict__ cb, float* __restrict__ cT) {
    int idx = blockIdx.x * 256 + threadIdx.x;
    int h = idx >> 16, s = (idx >> 7) & 511, d = idx & 127;
    cT[((size_t)((h << 7) + d)) * 512 + s] = cb[idx];
}

__global__ __launch_bounds__(256) void cnorm_kernel(const float* __restrict__ cb, float* __restrict__ cn) {
    int wv = threadIdx.x >> 6, ln = threadIdx.x & 63;
    int row = (blockIdx.x << 2) + wv;
    float2 x = *(const float2*)(cb + (size_t)row * 128 + (ln << 1));
    float ss = x.x*x.x + x.y*x.y;
#pragma unroll
    for (int m = 32; m > 0; m >>= 1) ss += __shfl_xor(ss, m);
    if (ln == 0) cn[row] = ss;
}

// ---------------- VQ argmin (fp32) ----------------
__global__ __launch_bounds__(256) void vq_kernel(float* __restrict__ kb, const float* __restrict__ cT,
                                                 const float* __restrict__ cn, const float* __restrict__ cb) {
    __shared__ float sK[4][4][128];
    int wv = threadIdx.x >> 6, ln = threadIdx.x & 63;
    int gw = (blockIdx.x << 2) + wv;
    int bh = gw >> 7;
    int l4 = (gw & 127) << 2;
    int h = bh & 7;
    size_t r0 = ((size_t)bh << 9) + l4;
#pragma unroll
    for (int i = 0; i < 4; ++i) {
        float2 kx = *(const float2*)(kb + (r0 + i) * 128 + (ln << 1));
        sK[wv][i][(ln<<1)]   = kx.x;
        sK[wv][i][(ln<<1)+1] = kx.y;
    }
    __syncthreads();
    const float* ct = cT + ((size_t)h << 7) * 512;
    int s0 = ln << 3;
    float dt[4][8];
#pragma unroll
    for (int i = 0; i < 4; ++i)
#pragma unroll
        for (int j = 0; j < 8; ++j) dt[i][j] = 0.0f;

    for (int dc = 0; dc < 4; ++dc) {
        float ch[4][8];
#pragma unroll
        for (int i = 0; i < 4; ++i)
#pragma unroll
            for (int j = 0; j < 8; ++j) ch[i][j] = 0.0f;
#pragma unroll 4
        for (int d = dc * 32; d < dc * 32 + 32; ++d) {
            float4 c0 = ld4(ct + (size_t)d * 512 + s0);
            float4 c1 = ld4(ct + (size_t)d * 512 + s0 + 4);
#pragma unroll
            for (int i = 0; i < 4; ++i) {
                float kd = sK[wv][i][d];
                ch[i][0] += kd * c0.x; ch[i][1] += kd * c0.y; ch[i][2] += kd * c0.z; ch[i][3] += kd * c0.w;
                ch[i][4] += kd * c1.x; ch[i][5] += kd * c1.y; ch[i][6] += kd * c1.z; ch[i][7] += kd * c1.w;
            }
        }
#pragma unroll
        for (int i = 0; i < 4; ++i)
#pragma unroll
            for (int j = 0; j < 8; ++j) dt[i][j] += ch[i][j];
    }
    const float* cnh = cn + (h << 9);
#pragma unroll
    for (int i = 0; i < 4; ++i) {
        float bestv = cnh[s0] - 2.0f * dt[i][0];
        int bestz = s0;
#pragma unroll
        for (int j = 1; j < 8; ++j) {
            float scv = cnh[s0 + j] - 2.0f * dt[i][j];
            if (scv < bestv) { bestv = scv; bestz = s0 + j; }
        }
#pragma unroll
        for (int m = 32; m > 0; m >>= 1) {
            float ov = __shfl_xor(bestv, m);
            int   oz = __shfl_xor(bestz, m);
            if (ov < bestv || (ov == bestv && oz < bestz)) { bestv = ov; bestz = oz; }
        }
        float2 cz = *(const float2*)(cb + ((size_t)(h << 9) + bestz) * 128 + (ln << 1));
        *(float2*)(kb + (r0 + i) * 128 + (ln << 1)) = cz;
    }
}

// ---------------- prep kernels ----------------
__global__ __launch_bounds__(256) void split_q_kernel(const float* __restrict__ q,
        const float* __restrict__ xu, const float* __restrict__ xv,
        ushort_t* __restrict__ quh, ushort_t* __restrict__ qul,
        ushort_t* __restrict__ qvh) {
    int idx = blockIdx.x * 256 + threadIdx.x;
    int d = idx & 127;
    int h = (idx >> 16) & 7;
    float qv = q[idx];
    float a = qv + xu[(h << 7) + d];
    unsigned short ah = bf16_rne(a);
    quh[idx] = ah; qul[idx] = bf16_rne(a - bf16_tof(ah));
    float b = qv + xv[(h << 7) + d];
    qvh[idx] = bf16_rne(b);
}

__global__ __launch_bounds__(256) void split_plain_kernel(const float* __restrict__ src,
        ushort_t* __restrict__ hi, ushort_t* __restrict__ lo) {
    int idx = blockIdx.x * 256 + threadIdx.x;
    float x = src[idx];
    unsigned short h = bf16_rne(x);
    hi[idx] = h; lo[idx] = bf16_rne(x - bf16_tof(h));
}

__global__ __launch_bounds__(256) void cvt_hi_kernel(const float* __restrict__ src,
        ushort_t* __restrict__ hi) {
    int idx = blockIdx.x * 256 + threadIdx.x;
    hi[idx] = bf16_rne(src[idx]);
}

__global__ __launch_bounds__(256) void split_koff_kernel(const float* __restrict__ src,
        ushort_t* __restrict__ hi, ushort_t* __restrict__ lo, int rowoff) {
    int idx = blockIdx.x * 256 + threadIdx.x;
    int bh = idx >> 16, rem = idx & 65535;
    size_t dst = ((size_t)bh << 17) + ((size_t)rowoff << 7) + rem;
    float x = src[idx];
    unsigned short h = bf16_rne(x);
    hi[dst] = h; lo[dst] = bf16_rne(x - bf16_tof(h));
}

__global__ __launch_bounds__(256) void vtsplit_kernel(const float* __restrict__ srcA,
        const float* __restrict__ srcB, ushort_t* __restrict__ hi, ushort_t* __restrict__ lo, int NK) {
    __shared__ float T[64][132];
    int bh = blockIdx.x, kt = blockIdx.y, t = threadIdx.x;
    for (int i = t; i < 2048; i += 256) {
        int r = i >> 5, c4 = (i & 31) << 2;
        int key = (kt << 6) + r;
        const float* s = (key < 512) ? (srcA + ((size_t)bh * 512 + key) * 128 + c4)
                                     : (srcB + ((size_t)bh * 512 + (key - 512)) * 128 + c4);
        *(float4*)&T[r][c4] = ld4(s);
    }
    __syncthreads();
    for (int i = t; i < 1024; i += 256) {
        int vc = i >> 3, kk = (i & 7) << 3;
        us8 h8, l8;
#pragma unroll
        for (int j = 0; j < 8; ++j) {
            float x = T[kk + j][vc];
            unsigned short hh = bf16_rne(x);
            h8[j] = hh; l8[j] = bf16_rne(x - bf16_tof(hh));
        }
        size_t off = ((size_t)bh * 128 + vc) * NK + (kt << 6) + kk;
        *(us8*)(hi + off) = h8;
        *(us8*)(lo + off) = l8;
    }
}

__global__ __launch_bounds__(256) void cbias_kernel(const float* __restrict__ al, float* __restrict__ cb) {
    int idx = blockIdx.x * 256 + threadIdx.x;
    float v = al[idx];
    cb[idx] = (v > 0.0f) ? __logf(fmaxf(v, 1e-30f)) : -INF30;
}

// ---------------- attn9: single-barrier, full K+V double-buffer, R-prefetch, defer-max ----
// attn8 structure (512 blocks x 4 waves, LDS-staged K/V shared by 4 q-tiles) with:
//  * V double-buffered too (VS[2][2]) -> ONE __syncthreads per ti (was 2): all staging
//    writes for ti+1 target buf^1 after PV; barrier protects the 1-iteration-apart reuse.
//  * R fragments prefetched into registers for ti+1 right after the G phase consumes them
//    (~2000 cyc hiding vs post-barrier issue) -> G MFMA chain never waits on L2.
//  * T13 defer-max: skip O-rescale unless __any(mv - mrun > 8); P bounded by e^8 (safe
//    in bf16 hi/lo + f32 accum).
//  * T5 setprio(1) around QK and PV MFMA clusters.
// LDS = 32K (KS) + 32K (VS) + 10.25K (P) = 75.8 KB -> 2 blocks/CU (unchanged occupancy;
// the win is stall removal, not TLP).
#define PSTR 40
__global__ __launch_bounds__(256, 2) void attn9_kernel(
        const ushort_t* __restrict__ Qu_hi, const ushort_t* __restrict__ Qu_lo,
        const ushort_t* __restrict__ Qv_hi,
        const ushort_t* __restrict__ K_hi,  const ushort_t* __restrict__ K_lo,
        const ushort_t* __restrict__ C_hi,  const ushort_t* __restrict__ C_lo,
        const ushort_t* __restrict__ Vt_hi, const ushort_t* __restrict__ Vt_lo,
        const ushort_t* __restrict__ At_hi, const ushort_t* __restrict__ At_lo,
        const ushort_t* __restrict__ R_hi,
        const float* __restrict__ cbias, const float* __restrict__ gbuf,
        float* __restrict__ wvg) {
    __shared__ __align__(16) ushort_t KS[2][2][32 * 128];  // [buf][hi/lo], swizzled
    __shared__ __align__(16) ushort_t VS[2][2][128 * 32];  // [buf][hi/lo], swizzled
    __shared__ __align__(16) ushort_t Phs[4][16 * PSTR];
    __shared__ __align__(16) ushort_t Pls[4][16 * PSTR];

    int t = threadIdx.x;
    int wvid = t >> 6, ln = t & 63;
    int col = ln & 15, quad = ln >> 4;
    int blk = blockIdx.x;
    int xcd = blk & 7, idx = blk >> 3;
    int bh = ((idx >> 3) << 3) + xcd;
    int j = idx & 7;
    int jt = ((wvid & 1) ? (15 - j) : j) + ((wvid & 2) ? 16 : 0);
    int l0 = jt << 4;
    int h = bh & 7, b = bh >> 3;

    int nt2own = (l0 + 47) >> 5;
    int nt2max = (((31 - j) << 4) + 47) >> 5;
    int Tt = 32 + nt2max;

    // persistent Q fragments
    size_t qb = ((size_t)bh * 512 + l0 + col) * 128 + quad * 8;
    bf16x8 quh[4], qul[4], qvf[4];
#pragma unroll
    for (int s = 0; s < 4; ++s) {
        quh[s] = ldb8(Qu_hi + qb + 32 * s);
        qul[s] = ldb8(Qu_lo + qb + 32 * s);
        qvf[s] = ldb8(Qv_hi + qb + 32 * s);
    }

    f32x4 O[8];
#pragma unroll
    for (int u = 0; u < 8; ++u) O[u] = (f32x4){0.f, 0.f, 0.f, 0.f};
    float mrun[4], lrun[4];
#pragma unroll
    for (int r = 0; r < 4; ++r) { mrun[r] = -INF30; lrun[r] = 0.0f; }

    ushort_t* Ph = Phs[wvid];
    ushort_t* Pl = Pls[wvid];

    // ---- prologue: stage K[0] and V[0] into buf 0; prefetch R for ti=0 ----
    {
        const ushort_t* nkh = K_hi + ((size_t)bh * 1024) * 128;
        const ushort_t* nkl = K_lo + ((size_t)bh * 1024) * 128;
#pragma unroll
        for (int m = 0; m < 2; ++m) {
            int r = wvid * 8 + m * 4 + (ln >> 4);
            int c = ln & 15;
            us8 vh8 = *(const us8*)(nkh + (size_t)r * 128 + c * 8);
            us8 vl8 = *(const us8*)(nkl + (size_t)r * 128 + c * 8);
            int dst = r * 128 + ((c ^ (r & 7)) << 3);
            *(us8*)&KS[0][0][dst] = vh8;
            *(us8*)&KS[0][1][dst] = vl8;
        }
        const ushort_t* vhp = Vt_hi + ((size_t)bh << 17);
        const ushort_t* vlp = Vt_lo + ((size_t)bh << 17);
#pragma unroll
        for (int m = 0; m < 2; ++m) {
            int dV = wvid * 128 + m * 64 + ln;
            int v = dV >> 2, c = dV & 3;
            us8 vh8 = *(const us8*)(vhp + (size_t)v * 1024 + c * 8);
            us8 vl8 = *(const us8*)(vlp + (size_t)v * 1024 + c * 8);
            int dst = v * 32 + ((c ^ ((v >> 1) & 3)) << 3);
            *(us8*)&VS[0][0][dst] = vh8;
            *(us8*)&VS[0][1][dst] = vl8;
        }
    }
    bf16x8 rg[3][4];   // prefetched R fragments for the NEXT G phase
    {
        int jt0 = 496 - l0;    // ti=0: seg0, w0=0
#pragma unroll
        for (int u = 0; u < 3; ++u) {
            int jr = jt0 + 16 * u + col;
            jr = (jr > 1023) ? 1023 : jr;
            const ushort_t* rp = R_hi + ((size_t)(h << 10) + jr) * 128 + quad * 8;
#pragma unroll
            for (int s = 0; s < 4; ++s) rg[u][s] = ldb8(rp + 32 * s);
        }
    }
    __syncthreads();
    int cur = 0;

    for (int ti = 0; ti < Tt; ++ti) {
        int seg, w0;
        if (ti < 16)      { seg = 0; w0 = ti << 5; }
        else if (ti < 32) { seg = 1; w0 = (ti - 16) << 5; }
        else              { seg = 2; w0 = (ti - 32) << 5; }
        bool act = (seg != 2) || ((ti - 32) < nt2own);

        int tn = ti + 1;
        bool hasNext = tn < Tt;
        int seg_n = 0, w0_n = 0;
        if (tn < 16)      { seg_n = 0; w0_n = tn << 5; }
        else if (tn < 32) { seg_n = 1; w0_n = (tn - 16) << 5; }
        else              { seg_n = 2; w0_n = (tn - 32) << 5; }
        bool act_n = hasNext && ((seg_n != 2) || ((tn - 32) < nt2own));

        // ---- issue next-iteration K and V global loads (consumed by late ds_writes) ----
        us8 krh[2], krl[2], vrh[2], vrl[2];
        if (hasNext) {
            const ushort_t *nkh, *nkl;
            if (seg_n == 0)      { nkh = K_hi + ((size_t)bh * 1024 + w0_n) * 128;
                                   nkl = K_lo + ((size_t)bh * 1024 + w0_n) * 128; }
            else if (seg_n == 1) { nkh = C_hi + ((size_t)(h << 9) + w0_n) * 128;
                                   nkl = C_lo + ((size_t)(h << 9) + w0_n) * 128; }
            else                 { nkh = K_hi + ((size_t)bh * 1024 + 512 + w0_n) * 128;
                                   nkl = K_lo + ((size_t)bh * 1024 + 512 + w0_n) * 128; }
#pragma unroll
            for (int m = 0; m < 2; ++m) {
                int r = wvid * 8 + m * 4 + (ln >> 4);
                int c = ln & 15;
                krh[m] = *(const us8*)(nkh + (size_t)r * 128 + c * 8);
                krl[m] = *(const us8*)(nkl + (size_t)r * 128 + c * 8);
            }
            const ushort_t *vhp, *vlp; size_t vstr; int wbase;
            if (seg_n == 0)      { vhp = Vt_hi + ((size_t)bh << 17); vlp = Vt_lo + ((size_t)bh << 17); vstr = 1024; wbase = w0_n; }
            else if (seg_n == 1) { vhp = At_hi + ((size_t)bh << 16); vlp = At_lo + ((size_t)bh << 16); vstr = 512;  wbase = w0_n; }
            else                 { vhp = Vt_hi + ((size_t)bh << 17); vlp = Vt_lo + ((size_t)bh << 17); vstr = 1024; wbase = 512 + w0_n; }
#pragma unroll
            for (int m = 0; m < 2; ++m) {
                int dV = wvid * 128 + m * 64 + ln;
                int v = dV >> 2, c = dV & 3;
                vrh[m] = *(const us8*)(vhp + (size_t)v * vstr + wbase + c * 8);
                vrl[m] = *(const us8*)(vlp + (size_t)v * vstr + wbase + c * 8);
            }
        }

        // ---- G phase from PREFETCHED R registers ----
        f32x4 Gacc[3];
        f32x4 S[2];
        if (act && seg != 1) {
#pragma unroll
            for (int u = 0; u < 3; ++u) {
                f32x4 acc = (f32x4){0.f, 0.f, 0.f, 0.f};
                acc = MFMA16(qvf[0], rg[u][0], acc);
                acc = MFMA16(qvf[1], rg[u][1], acc);
                acc = MFMA16(qvf[2], rg[u][2], acc);
                acc = MFMA16(qvf[3], rg[u][3], acc);
                Gacc[u] = acc;
            }
        }

        // ---- R prefetch for ti+1 (reload rg; whole rest of iteration to hide) ----
        if (act_n && seg_n != 1) {
            int jt0n = ((seg_n == 0) ? w0_n : (512 + w0_n)) + 496 - l0;
#pragma unroll
            for (int u = 0; u < 3; ++u) {
                int jr = jt0n + 16 * u + col;
                jr = (jr > 1023) ? 1023 : jr;
                const ushort_t* rp = R_hi + ((size_t)(h << 10) + jr) * 128 + quad * 8;
#pragma unroll
                for (int s = 0; s < 4; ++s) rg[u][s] = ldb8(rp + 32 * s);
            }
        }

        // ---- QK^T from LDS K[cur] ----
        if (act) {
            S[0] = (f32x4){0.f, 0.f, 0.f, 0.f};
            S[1] = (f32x4){0.f, 0.f, 0.f, 0.f};
            const ushort_t* KH = KS[cur][0];
            const ushort_t* KL = KS[cur][1];
            int swz = col & 7;
            __builtin_amdgcn_s_setprio(1);
#pragma unroll
            for (int s = 0; s < 4; ++s) {
                int cofs = ((quad + 4 * s) ^ swz) << 3;
                bf16x8 k0h = *(const bf16x8*)&KH[col * 128 + cofs];
                bf16x8 k0l = *(const bf16x8*)&KL[col * 128 + cofs];
                bf16x8 k1h = *(const bf16x8*)&KH[(16 + col) * 128 + cofs];
                bf16x8 k1l = *(const bf16x8*)&KL[(16 + col) * 128 + cofs];
                S[0] = MFMA16(quh[s], k0h, S[0]);
                S[0] = MFMA16(qul[s], k0h, S[0]);
                S[0] = MFMA16(quh[s], k0l, S[0]);
                S[1] = MFMA16(quh[s], k1h, S[1]);
                S[1] = MFMA16(qul[s], k1h, S[1]);
                S[1] = MFMA16(quh[s], k1l, S[1]);
            }
            __builtin_amdgcn_s_setprio(0);
        }

        // ---- fixup + online softmax (defer-max) + P frags ----
        bf16x8 pah = {}, pal = {};
        if (act) {
            float bias0 = 0.f, bias1 = 0.f;
            if (seg == 1) {
                bias0 = cbias[(size_t)(bh << 9) + w0 + col];
                bias1 = cbias[(size_t)(bh << 9) + w0 + 16 + col];
            }
#pragma unroll
            for (int t2 = 0; t2 < 2; ++t2) {
#pragma unroll
                for (int r = 0; r < 4; ++r) {
                    int row = 4 * quad + r;
                    float sv = S[t2][r];
                    if (seg != 1) {
                        int d = col + 15 - row;
                        int src = quad * 16 + (d & 15);
                        float g0 = __shfl(Gacc[t2][r], src);
                        float g1 = __shfl(Gacc[t2 + 1][r], src);
                        float gv = (d >= 16) ? g1 : g0;
                        sv = (sv + gv) * INV_TAU;
                        if (seg == 2 && (w0 + 16 * t2 + col > l0 + row)) sv = -INF30;
                    } else {
                        sv = sv * INV_TAU + ((t2 == 0) ? bias0 : bias1);
                    }
                    S[t2][r] = sv;
                }
            }
            float mv4[4];
            float need = -INF30;
#pragma unroll
            for (int r = 0; r < 4; ++r) {
                float mv = fmaxf(S[0][r], S[1][r]);
#pragma unroll
                for (int m = 8; m > 0; m >>= 1) mv = fmaxf(mv, __shfl_xor(mv, m));
                mv4[r] = mv;
                need = fmaxf(need, mv - mrun[r]);
            }
            if (__any(need > 8.0f)) {   // T13: rescale only when max grew enough
#pragma unroll
                for (int r = 0; r < 4; ++r) {
                    float mnew = fmaxf(mrun[r], mv4[r]);
                    float alpha = __expf(mrun[r] - mnew);
                    mrun[r] = mnew;
                    lrun[r] *= alpha;
#pragma unroll
                    for (int u = 0; u < 8; ++u) O[u][r] *= alpha;
                }
            }
#pragma unroll
            for (int r = 0; r < 4; ++r) {
                float p0 = __expf(S[0][r] - mrun[r]);
                float p1 = __expf(S[1][r] - mrun[r]);
                float ps = p0 + p1;
#pragma unroll
                for (int m = 8; m > 0; m >>= 1) ps += __shfl_xor(ps, m);
                lrun[r] += ps;
                int row = 4 * quad + r;
                unsigned short h0 = bf16_rne(p0);
                Ph[row * PSTR + col] = h0;
                Pl[row * PSTR + col] = bf16_rne(p0 - bf16_tof(h0));
                unsigned short h1 = bf16_rne(p1);
                Ph[row * PSTR + 16 + col] = h1;
                Pl[row * PSTR + 16 + col] = bf16_rne(p1 - bf16_tof(h1));
            }
            pah = *(const bf16x8*)&Ph[col * PSTR + quad * 8];
            pal = *(const bf16x8*)&Pl[col * PSTR + quad * 8];
        }

        // ---- PV from LDS V[cur] ----
        if (act) {
            const ushort_t* VH = VS[cur][0];
            const ushort_t* VL = VS[cur][1];
            int vswz = (quad ^ ((col >> 1) & 3)) << 3;
            __builtin_amdgcn_s_setprio(1);
#pragma unroll
            for (int u = 0; u < 8; ++u) {
                int vrow = 16 * u + col;
                bf16x8 vbh = *(const bf16x8*)&VH[vrow * 32 + vswz];
                bf16x8 vbl = *(const bf16x8*)&VL[vrow * 32 + vswz];
                O[u] = MFMA16(pah, vbh, O[u]);
                O[u] = MFMA16(pal, vbh, O[u]);
                O[u] = MFMA16(pah, vbl, O[u]);
            }
            __builtin_amdgcn_s_setprio(0);
        }

        // ---- late ds_writes of next K/V into buf^1 ----
        if (hasNext) {
#pragma unroll
            for (int m = 0; m < 2; ++m) {
                int r = wvid * 8 + m * 4 + (ln >> 4);
                int c = ln & 15;
                int dst = r * 128 + ((c ^ (r & 7)) << 3);
                *(us8*)&KS[cur ^ 1][0][dst] = krh[m];
                *(us8*)&KS[cur ^ 1][1][dst] = krl[m];
            }
#pragma unroll
            for (int m = 0; m < 2; ++m) {
                int dV = wvid * 128 + m * 64 + ln;
                int v = dV >> 2, c = dV & 3;
                int dst = v * 32 + ((c ^ ((v >> 1) & 3)) << 3);
                *(us8*)&VS[cur ^ 1][0][dst] = vrh[m];
                *(us8*)&VS[cur ^ 1][1][dst] = vrl[m];
            }
        }

        __syncthreads();   // single barrier per ti
        cur ^= 1;
    }

    // ---- direct gated write-out ----
#pragma unroll
    for (int r = 0; r < 4; ++r) {
        int row = quad * 4 + r;
        float linv = 1.0f / lrun[r];
#pragma unroll
        for (int u = 0; u < 8; ++u) {
            size_t gi = ((size_t)b * 512 + l0 + row) * 1024 + (h << 7) + 16 * u + col;
            wvg[gi] = O[u][r] * linv * gbuf[gi];
        }
    }
}

extern "C" void kernel_launch(void* const* d_in, const int* in_sizes, int n_in,
                              void* d_out, int out_size, void* d_ws, size_t ws_size,
                              hipStream_t stream) {
    const float* x_in  = (const float*)d_in[0];
    const float* xl_k  = (const float*)d_in[2];
    const float* xl_v  = (const float*)d_in[3];
    const float* agg_u = (const float*)d_in[4];
    const float* agg_l = (const float*)d_in[5];
    const float* W_q   = (const float*)d_in[6];
    const float* W_kvg = (const float*)d_in[7];
    const float* W_res = (const float*)d_in[8];
    const float* x_u   = (const float*)d_in[9];
    const float* x_v   = (const float*)d_in[10];
    const float* xl_r  = (const float*)d_in[11];
    const float* cbk   = (const float*)d_in[12];
    float* out = (float*)d_out;
    char* wb = (char*)d_ws;

    float*  x_t   = (float*)(wb);                       // 16 MB [alias: K_hi; later Awh/Awl]
    float*  qbuf  = (float*)(wb + 16777216ul);          // 16 MB [alias: Vt_lo]
    float*  kbuf  = (float*)(wb + 33554432ul);          // 16 MB [alias: Vt_hi]
    float*  vbuf  = (float*)(wb + 50331648ul);          // 16 MB [alias: At_hi+At_lo]
    float*  gbuf  = (float*)(wb + 67108864ul);          // 16 MB
    float*  wvg   = (float*)(wb + 83886080ul);          // 16 MB [alias: Ah+Al pre-attn]
    float*  cT    = (float*)(wb + 100663296ul);         // 2 MB  [alias: C_hi+C_lo]
    float*  cnm   = (float*)(wb + 102760448ul);         // 16 KB
    ushort_t* Qu_hi = (ushort_t*)(wb + 102776832ul);    // 8 MB  [alias: Wtq pre-split]
    ushort_t* Qu_lo = (ushort_t*)(wb + 111165440ul);    // 8 MB  [alias: Wtvg pre-split]
    ushort_t* Qv_hi = (ushort_t*)(wb + 119554048ul);    // 8 MB  [alias: Wtres post-attn]
    ushort_t* K_lo  = (ushort_t*)(wb + 136331264ul);    // 16 MB
    ushort_t* R_hi  = (ushort_t*)(wb + 153108480ul);    // 2 MB
    float*  cbias   = (float*)(wb + 157302784ul);       // 128 KB

    ushort_t* K_hi  = (ushort_t*)x_t;
    ushort_t* Vt_hi = (ushort_t*)kbuf;
    ushort_t* Vt_lo = (ushort_t*)qbuf;
    ushort_t* At_hi = (ushort_t*)vbuf;
    ushort_t* At_lo = (ushort_t*)(wb + 50331648ul + 8388608ul);
    ushort_t* C_hi  = (ushort_t*)cT;
    ushort_t* C_lo  = (ushort_t*)(wb + 100663296ul + 1048576ul);

    ushort_t* Ah      = (ushort_t*)wvg;
    ushort_t* Al      = (ushort_t*)(wb + 83886080ul + 8388608ul);
    ushort_t* Wtq_hi  = (ushort_t*)Qu_hi;
    ushort_t* Wtq_lo  = (ushort_t*)(wb + 102776832ul + 2097152ul);
    ushort_t* Wtvg_hi = (ushort_t*)Qu_lo;
    ushort_t* Wtvg_lo = (ushort_t*)(wb + 111165440ul + 4194304ul);
    ushort_t* Wtres_hi = (ushort_t*)Qv_hi;
    ushort_t* Wtres_lo = (ushort_t*)(wb + 119554048ul + 2097152ul);
    ushort_t* Awh     = (ushort_t*)x_t;
    ushort_t* Awl     = (ushort_t*)(wb + 8388608ul);

    // 1) input LN
    ln_dm_kernel<<<4096, 256, 0, stream>>>(x_in, x_t);
    // 2) split activations + weights for bf16 GEMMs
    split_plain_kernel<<<16384, 256, 0, stream>>>(x_t, Ah, Al);
    wtsplit_kernel<<<dim3(16, 16), 256, 0, stream>>>(W_q, 1024, 0, Wtq_hi, Wtq_lo);
    wtsplit_kernel<<<dim3(32, 16), 256, 0, stream>>>(W_kvg, 3072, 1024, Wtvg_hi, Wtvg_lo);
    // 3) GEMMs: q (bf16), v+g (bf16), k (fp32 — argmin-critical)
    gemm_bf16_kernel<<<dim3(8, 32), 256, 0, stream>>>(Ah, Al, Wtq_hi, Wtq_lo, 0, qbuf, nullptr);
    gemm_bf16_kernel<<<dim3(16, 32), 256, 0, stream>>>(Ah, Al, Wtvg_hi, Wtvg_lo, 1, vbuf, gbuf);
    gemm_kernel<<<dim3(16, 64), 256, 0, stream>>>(x_t, W_kvg, 3072, 0, kbuf, nullptr, nullptr);
    // 4) LN(q), LN(k); VQ
    ln128_kernel<<<16384, 256, 0, stream>>>(qbuf, kbuf);
    cbt_kernel<<<2048, 256, 0, stream>>>(cbk, cT);
    cnorm_kernel<<<1024, 256, 0, stream>>>(cbk, cnm);
    vq_kernel<<<2048, 256, 0, stream>>>(kbuf, cT, cnm, cbk);
    // 5) attention preps
    split_q_kernel<<<16384, 256, 0, stream>>>(qbuf, x_u, x_v, Qu_hi, Qu_lo, Qv_hi);
    split_koff_kernel<<<16384, 256, 0, stream>>>(xl_k, K_hi, K_lo, 0);
    split_koff_kernel<<<16384, 256, 0, stream>>>(kbuf, K_hi, K_lo, 512);
    split_plain_kernel<<<2048, 256, 0, stream>>>(cbk, C_hi, C_lo);
    cvt_hi_kernel<<<4096, 256, 0, stream>>>(xl_r, R_hi);
    vtsplit_kernel<<<dim3(64, 16), 256, 0, stream>>>(xl_v, vbuf, Vt_hi, Vt_lo, 1024);
    vtsplit_kernel<<<dim3(64, 8), 256, 0, stream>>>(agg_u, agg_u, At_hi, At_lo, 512);
    cbias_kernel<<<128, 256, 0, stream>>>(agg_l, cbias);
    // 6) single-barrier double-buffered fused attention
    attn9_kernel<<<512, 256, 0, stream>>>(Qu_hi, Qu_lo, Qv_hi, K_hi, K_lo, C_hi, C_lo,
                                          Vt_hi, Vt_lo, At_hi, At_lo, R_hi,
                                          cbias, gbuf, wvg);
    // 7) output GEMM (bf16)
    split_plain_kernel<<<16384, 256, 0, stream>>>(wvg, Awh, Awl);
    wtsplit_kernel<<<dim3(16, 16), 256, 0, stream>>>(W_res, 1024, 0, Wtres_hi, Wtres_lo);
    gemm_bf16_kernel<<<dim3(8, 32), 256, 0, stream>>>(Awh, Awl, Wtres_hi, Wtres_lo, 2, out, nullptr);
}

// Round 5
// 779.614 us; speedup vs baseline: 1.6958x; 1.0222x over previous
//
#include <hip/hip_runtime.h>

#define INF30 1e30f
#define INV_TAU 0.08838834764831845f

typedef unsigned short ushort_t;
typedef __attribute__((ext_vector_type(8))) short bf16x8;
typedef __attribute__((ext_vector_type(4))) float f32x4;
typedef __attribute__((ext_vector_type(8))) unsigned short us8;

__device__ __forceinline__ float4 ld4(const float* p) { return *(const float4*)p; }

__device__ __forceinline__ unsigned short bf16_rne(float x) {
    unsigned int u = __float_as_uint(x);
    unsigned int r = u + 0x7fffu + ((u >> 16) & 1u);
    return (unsigned short)(r >> 16);
}
__device__ __forceinline__ float bf16_tof(unsigned short h) {
    return __uint_as_float(((unsigned int)h) << 16);
}
__device__ __forceinline__ bf16x8 ldb8(const ushort_t* p) { return *(const bf16x8*)p; }

#define MFMA16(a, b, c) __builtin_amdgcn_mfma_f32_16x16x32_bf16((a), (b), (c), 0, 0, 0)

// ---------------- LayerNorm over DM=1024 ----------------
__global__ __launch_bounds__(256) void ln_dm_kernel(const float* __restrict__ x, float* __restrict__ y) {
    size_t row = blockIdx.x;
    const float4* xr = (const float4*)(x + row * 1024);
    float4 v = xr[threadIdx.x];
    float s  = v.x + v.y + v.z + v.w;
    float ss = v.x*v.x + v.y*v.y + v.z*v.z + v.w*v.w;
#pragma unroll
    for (int off = 32; off > 0; off >>= 1) {
        s  += __shfl_down(s, off);
        ss += __shfl_down(ss, off);
    }
    __shared__ float rs[4], rss[4];
    int wv = threadIdx.x >> 6, ln = threadIdx.x & 63;
    if (ln == 0) { rs[wv] = s; rss[wv] = ss; }
    __syncthreads();
    s  = rs[0] + rs[1] + rs[2] + rs[3];
    ss = rss[0] + rss[1] + rss[2] + rss[3];
    float mu  = s * (1.0f/1024.0f);
    float var = ss * (1.0f/1024.0f) - mu*mu;
    float r = rsqrtf(var + 1e-6f);
    float4 o;
    o.x = (v.x - mu) * r; o.y = (v.y - mu) * r; o.z = (v.z - mu) * r; o.w = (v.w - mu) * r;
    ((float4*)(y + row * 1024))[threadIdx.x] = o;
}

// ---------------- fp32 tiled GEMM, 128x128 tile, 8x8/thread (k-columns: argmin path) ----
// Column/row groups split as {g*4, 64+g*4} so LDS reads are broadcast (A) or 2-way (B) = free.
__global__ __launch_bounds__(256) void gemm_kernel(const float* __restrict__ A, const float* __restrict__ W,
                                                   int N, int mode,
                                                   float* __restrict__ o0, float* __restrict__ o1,
                                                   float* __restrict__ o2) {
    __shared__ float As[16][128];
    __shared__ float Bs[16][128];
    int t = threadIdx.x;
    int col0 = blockIdx.x << 7;
    int row0 = blockIdx.y << 7;
    int tx = t & 15, ty = t >> 4;
    int arow = t >> 1, akq = (t & 1) * 8;
    int bkr = t >> 4, bcq = (t & 15) * 4;
    const float* Ap = A + (size_t)(row0 + arow) * 1024 + akq;
    const float* Wp = W + (size_t)bkr * N + col0 + bcq;
    float acc[8][8];
#pragma unroll
    for (int i = 0; i < 8; ++i)
#pragma unroll
        for (int j = 0; j < 8; ++j) acc[i][j] = 0.0f;

    float4 a0 = ld4(Ap), a1 = ld4(Ap + 4);
    float4 b0 = ld4(Wp), b1 = ld4(Wp + 64);

    for (int kt = 0; kt < 64; ++kt) {
        __syncthreads();
        As[akq+0][arow] = a0.x; As[akq+1][arow] = a0.y;
        As[akq+2][arow] = a0.z; As[akq+3][arow] = a0.w;
        As[akq+4][arow] = a1.x; As[akq+5][arow] = a1.y;
        As[akq+6][arow] = a1.z; As[akq+7][arow] = a1.w;
        *(float4*)&Bs[bkr][bcq]      = b0;
        *(float4*)&Bs[bkr][64 + bcq] = b1;
        __syncthreads();
        if (kt < 63) {
            a0 = ld4(Ap + (kt + 1) * 16);
            a1 = ld4(Ap + (kt + 1) * 16 + 4);
            b0 = ld4(Wp + (size_t)(kt + 1) * 16 * N);
            b1 = ld4(Wp + (size_t)(kt + 1) * 16 * N + 64);
        }
#pragma unroll
        for (int kk = 0; kk < 16; ++kk) {
            float4 av0 = *(float4*)&As[kk][ty * 4];
            float4 av1 = *(float4*)&As[kk][64 + ty * 4];
            float4 bv0 = *(float4*)&Bs[kk][tx * 4];
            float4 bv1 = *(float4*)&Bs[kk][64 + tx * 4];
            float a8[8] = {av0.x, av0.y, av0.z, av0.w, av1.x, av1.y, av1.z, av1.w};
            float b8[8] = {bv0.x, bv0.y, bv0.z, bv0.w, bv1.x, bv1.y, bv1.z, bv1.w};
#pragma unroll
            for (int i = 0; i < 8; ++i)
#pragma unroll
                for (int j = 0; j < 8; ++j) acc[i][j] += a8[i] * b8[j];
        }
    }

#pragma unroll
    for (int i = 0; i < 8; ++i) {
        int rr = row0 + ((i < 4) ? (ty * 4 + i) : (64 + ty * 4 + i - 4));
        int b = rr >> 9, l = rr & 511;
#pragma unroll
        for (int j = 0; j < 8; ++j) {
            int cc = col0 + ((j < 4) ? (tx * 4 + j) : (64 + tx * 4 + j - 4));
            float vv = acc[i][j];
            if (mode == 0) {
                o0[((size_t)((b<<3) + (cc>>7)) * 512 + l) * 128 + (cc & 127)] = vv;
            } else if (mode == 1) {
                if (cc < 1024) {
                    o0[((size_t)((b<<3) + (cc>>7)) * 512 + l) * 128 + (cc & 127)] = vv;
                } else if (cc < 2048) {
                    int c2 = cc - 1024;
                    o1[((size_t)((b<<3) + (c2>>7)) * 512 + l) * 128 + (c2 & 127)] = vv;
                } else {
                    o2[(size_t)rr * 1024 + (cc - 2048)] = vv / (1.0f + __expf(-vv));
                }
            } else {
                o0[(size_t)rr * 1024 + cc] = vv;
            }
        }
    }
}

// ---------------- weight transpose + bf16 hi/lo split ----------------
__global__ __launch_bounds__(256) void wtsplit_kernel(const float* __restrict__ W, int Ntot, int c0,
                                                      ushort_t* __restrict__ th, ushort_t* __restrict__ tl) {
    __shared__ float T[64][68];
    int n0 = blockIdx.x << 6, k0 = blockIdx.y << 6, t = threadIdx.x;
    for (int i = t; i < 1024; i += 256) {
        int kk = i >> 4, nn4 = (i & 15) << 2;
        *(float4*)&T[kk][nn4] = ld4(W + (size_t)(k0 + kk) * Ntot + c0 + n0 + nn4);
    }
    __syncthreads();
    for (int i = t; i < 512; i += 256) {
        int nn = i >> 3, kc = (i & 7) << 3;
        us8 h8, l8;
#pragma unroll
        for (int j = 0; j < 8; ++j) {
            float x = T[kc + j][nn];
            unsigned short hh = bf16_rne(x);
            h8[j] = hh; l8[j] = bf16_rne(x - bf16_tof(hh));
        }
        size_t off = (size_t)(n0 + nn) * 1024 + k0 + kc;
        *(us8*)(th + off) = h8;
        *(us8*)(tl + off) = l8;
    }
}

// ---------------- bf16 3-term split GEMM ----------------
#define GSTRIDE 40
__global__ __launch_bounds__(256) void gemm_bf16_kernel(
        const ushort_t* __restrict__ Ah, const ushort_t* __restrict__ Al,
        const ushort_t* __restrict__ Bth, const ushort_t* __restrict__ Btl,
        int mode, float* __restrict__ o0, float* __restrict__ o1) {
    __shared__ ushort_t LA[2][128 * GSTRIDE];
    __shared__ ushort_t LB[2][128 * GSTRIDE];
    int t = threadIdx.x;
    int col0 = blockIdx.x << 7, row0 = blockIdx.y << 7;
    int wvid = t >> 6, ln = t & 63;
    int lcol = ln & 15, quad = ln >> 4;
    int qm = wvid >> 1, qn = wvid & 1;

    f32x4 C[4][4];
#pragma unroll
    for (int i = 0; i < 4; ++i)
#pragma unroll
        for (int j = 0; j < 4; ++j) C[i][j] = (f32x4){0.f, 0.f, 0.f, 0.f};

    for (int k0 = 0; k0 < 1024; k0 += 32) {
        us8 ra[2][2], rb[2][2];
#pragma unroll
        for (int v = 0; v < 2; ++v) {
            int cid = t + 256 * v;
            int row = cid >> 2, ch = cid & 3;
            size_t ga = (size_t)(row0 + row) * 1024 + k0 + ch * 8;
            size_t gb = (size_t)(col0 + row) * 1024 + k0 + ch * 8;
            ra[v][0] = *(const us8*)(Ah + ga);
            ra[v][1] = *(const us8*)(Al + ga);
            rb[v][0] = *(const us8*)(Bth + gb);
            rb[v][1] = *(const us8*)(Btl + gb);
        }
        __syncthreads();
#pragma unroll
        for (int v = 0; v < 2; ++v) {
            int cid = t + 256 * v;
            int row = cid >> 2, ch = cid & 3;
            *(us8*)&LA[0][row * GSTRIDE + ch * 8] = ra[v][0];
            *(us8*)&LA[1][row * GSTRIDE + ch * 8] = ra[v][1];
            *(us8*)&LB[0][row * GSTRIDE + ch * 8] = rb[v][0];
            *(us8*)&LB[1][row * GSTRIDE + ch * 8] = rb[v][1];
        }
        __syncthreads();
        bf16x8 afh[4], afl[4], bfh[4], bfl[4];
#pragma unroll
        for (int i = 0; i < 4; ++i) {
            int r = qm * 64 + i * 16 + lcol;
            afh[i] = *(const bf16x8*)&LA[0][r * GSTRIDE + quad * 8];
            afl[i] = *(const bf16x8*)&LA[1][r * GSTRIDE + quad * 8];
            int c = qn * 64 + i * 16 + lcol;
            bfh[i] = *(const bf16x8*)&LB[0][c * GSTRIDE + quad * 8];
            bfl[i] = *(const bf16x8*)&LB[1][c * GSTRIDE + quad * 8];
        }
#pragma unroll
        for (int i = 0; i < 4; ++i)
#pragma unroll
            for (int j = 0; j < 4; ++j) {
                C[i][j] = MFMA16(afh[i], bfh[j], C[i][j]);
                C[i][j] = MFMA16(afl[i], bfh[j], C[i][j]);
                C[i][j] = MFMA16(afh[i], bfl[j], C[i][j]);
            }
    }

#pragma unroll
    for (int i = 0; i < 4; ++i) {
#pragma unroll
        for (int r = 0; r < 4; ++r) {
            int rr = row0 + qm * 64 + 16 * i + quad * 4 + r;
            int b = rr >> 9, l = rr & 511;
#pragma unroll
            for (int j = 0; j < 4; ++j) {
                int cc = col0 + qn * 64 + 16 * j + lcol;
                float vv = C[i][j][r];
                if (mode == 0) {
                    o0[((size_t)((b<<3) + (cc>>7)) * 512 + l) * 128 + (cc & 127)] = vv;
                } else if (mode == 1) {
                    if (cc < 1024) o0[((size_t)((b<<3) + (cc>>7)) * 512 + l) * 128 + (cc & 127)] = vv;
                    else o1[(size_t)rr * 1024 + (cc - 1024)] = vv / (1.0f + __expf(-vv));
                } else {
                    o0[(size_t)rr * 1024 + cc] = vv;
                }
            }
        }
    }
}

// ---------------- LayerNorm over last dim 128 for q and k, in place ----------------
__global__ __launch_bounds__(256) void ln128_kernel(float* __restrict__ qb, float* __restrict__ kb) {
    int wv = threadIdx.x >> 6, ln = threadIdx.x & 63;
    int gw = (blockIdx.x << 2) + wv;
    float* base = (gw < 32768) ? qb : kb;
    int row = gw & 32767;
    float2 x = *(float2*)(base + (size_t)row * 128 + (ln << 1));
    float s  = x.x + x.y;
    float ss = x.x*x.x + x.y*x.y;
#pragma unroll
    for (int m = 32; m > 0; m >>= 1) { s += __shfl_xor(s, m); ss += __shfl_xor(ss, m); }
    float mu  = s * (1.0f/128.0f);
    float var = ss * (1.0f/128.0f) - mu*mu;
    float r = rsqrtf(var + 1e-6f);
    x.x = (x.x - mu) * r; x.y = (x.y - mu) * r;
    *(float2*)(base + (size_t)row * 128 + (ln << 1)) = x;
}

// ---------------- codebook transpose + norms ----------------
__global__ __launch_bounds__(256) void cbt_kernel(const float* __restrict__ cb, float* __restrict__ cT) {
    int idx = blockIdx.x * 256 + threadIdx.x;
    int h = idx >> 16, s = (idx >> 7) & 511, d = idx & 127;
    cT[((size_t)((h << 7) + d)) * 512 + s] = cb[idx];
}

__global__ __launch_bounds__(256) void cnorm_kernel(const float* __restrict__ cb, float* __restrict__ cn) {
    int wv = threadIdx.x >> 6, ln = threadIdx.x & 63;
    int row = (blockIdx.x << 2) + wv;
    float2 x = *(const float2*)(cb + (size_t)row * 128 + (ln << 1));
    float ss = x.x*x.x + x.y*x.y;
#pragma unroll
    for (int m = 32; m > 0; m >>= 1) ss += __shfl_xor(ss, m);
    if (ln == 0) cn[row] = ss;
}

// ---------------- VQ argmin (fp32) ----------------
__global__ __launch_bounds__(256) void vq_kernel(float* __restrict__ kb, const float* __restrict__ cT,
                                                 const float* __restrict__ cn, const float* __restrict__ cb) {
    __shared__ float sK[4][4][128];
    int wv = threadIdx.x >> 6, ln = threadIdx.x & 63;
    int gw = (blockIdx.x << 2) + wv;
    int bh = gw >> 7;
    int l4 = (gw & 127) << 2;
    int h = bh & 7;
    size_t r0 = ((size_t)bh << 9) + l4;
#pragma unroll
    for (int i = 0; i < 4; ++i) {
        float2 kx = *(const float2*)(kb + (r0 + i) * 128 + (ln << 1));
        sK[wv][i][(ln<<1)]   = kx.x;
        sK[wv][i][(ln<<1)+1] = kx.y;
    }
    __syncthreads();
    const float* ct = cT + ((size_t)h << 7) * 512;
    int s0 = ln << 3;
    float dt[4][8];
#pragma unroll
    for (int i = 0; i < 4; ++i)
#pragma unroll
        for (int j = 0; j < 8; ++j) dt[i][j] = 0.0f;

    for (int dc = 0; dc < 4; ++dc) {
        float ch[4][8];
#pragma unroll
        for (int i = 0; i < 4; ++i)
#pragma unroll
            for (int j = 0; j < 8; ++j) ch[i][j] = 0.0f;
#pragma unroll 4
        for (int d = dc * 32; d < dc * 32 + 32; ++d) {
            float4 c0 = ld4(ct + (size_t)d * 512 + s0);
            float4 c1 = ld4(ct + (size_t)d * 512 + s0 + 4);
#pragma unroll
            for (int i = 0; i < 4; ++i) {
                float kd = sK[wv][i][d];
                ch[i][0] += kd * c0.x; ch[i][1] += kd * c0.y; ch[i][2] += kd * c0.z; ch[i][3] += kd * c0.w;
                ch[i][4] += kd * c1.x; ch[i][5] += kd * c1.y; ch[i][6] += kd * c1.z; ch[i][7] += kd * c1.w;
            }
        }
#pragma unroll
        for (int i = 0; i < 4; ++i)
#pragma unroll
            for (int j = 0; j < 8; ++j) dt[i][j] += ch[i][j];
    }
    const float* cnh = cn + (h << 9);
#pragma unroll
    for (int i = 0; i < 4; ++i) {
        float bestv = cnh[s0] - 2.0f * dt[i][0];
        int bestz = s0;
#pragma unroll
        for (int j = 1; j < 8; ++j) {
            float scv = cnh[s0 + j] - 2.0f * dt[i][j];
            if (scv < bestv) { bestv = scv; bestz = s0 + j; }
        }
#pragma unroll
        for (int m = 32; m > 0; m >>= 1) {
            float ov = __shfl_xor(bestv, m);
            int   oz = __shfl_xor(bestz, m);
            if (ov < bestv || (ov == bestv && oz < bestz)) { bestv = ov; bestz = oz; }
        }
        float2 cz = *(const float2*)(cb + ((size_t)(h << 9) + bestz) * 128 + (ln << 1));
        *(float2*)(kb + (r0 + i) * 128 + (ln << 1)) = cz;
    }
}

// ---------------- prep kernels ----------------
__global__ __launch_bounds__(256) void split_q_kernel(const float* __restrict__ q,
        const float* __restrict__ xu, const float* __restrict__ xv,
        ushort_t* __restrict__ quh, ushort_t* __restrict__ qul,
        ushort_t* __restrict__ qvh) {
    int idx = blockIdx.x * 256 + threadIdx.x;
    int d = idx & 127;
    int h = (idx >> 16) & 7;
    float qv = q[idx];
    float a = qv + xu[(h << 7) + d];
    unsigned short ah = bf16_rne(a);
    quh[idx] = ah; qul[idx] = bf16_rne(a - bf16_tof(ah));
    float b = qv + xv[(h << 7) + d];
    qvh[idx] = bf16_rne(b);
}

__global__ __launch_bounds__(256) void split_plain_kernel(const float* __restrict__ src,
        ushort_t* __restrict__ hi, ushort_t* __restrict__ lo) {
    int idx = blockIdx.x * 256 + threadIdx.x;
    float x = src[idx];
    unsigned short h = bf16_rne(x);
    hi[idx] = h; lo[idx] = bf16_rne(x - bf16_tof(h));
}

__global__ __launch_bounds__(256) void cvt_hi_kernel(const float* __restrict__ src,
        ushort_t* __restrict__ hi) {
    int idx = blockIdx.x * 256 + threadIdx.x;
    hi[idx] = bf16_rne(src[idx]);
}

__global__ __launch_bounds__(256) void split_koff_kernel(const float* __restrict__ src,
        ushort_t* __restrict__ hi, ushort_t* __restrict__ lo, int rowoff) {
    int idx = blockIdx.x * 256 + threadIdx.x;
    int bh = idx >> 16, rem = idx & 65535;
    size_t dst = ((size_t)bh << 17) + ((size_t)rowoff << 7) + rem;
    float x = src[idx];
    unsigned short h = bf16_rne(x);
    hi[dst] = h; lo[dst] = bf16_rne(x - bf16_tof(h));
}

__global__ __launch_bounds__(256) void vtsplit_kernel(const float* __restrict__ srcA,
        const float* __restrict__ srcB, ushort_t* __restrict__ hi, ushort_t* __restrict__ lo, int NK) {
    __shared__ float T[64][132];
    int bh = blockIdx.x, kt = blockIdx.y, t = threadIdx.x;
    for (int i = t; i < 2048; i += 256) {
        int r = i >> 5, c4 = (i & 31) << 2;
        int key = (kt << 6) + r;
        const float* s = (key < 512) ? (srcA + ((size_t)bh * 512 + key) * 128 + c4)
                                     : (srcB + ((size_t)bh * 512 + (key - 512)) * 128 + c4);
        *(float4*)&T[r][c4] = ld4(s);
    }
    __syncthreads();
    for (int i = t; i < 1024; i += 256) {
        int vc = i >> 3, kk = (i & 7) << 3;
        us8 h8, l8;
#pragma unroll
        for (int j = 0; j < 8; ++j) {
            float x = T[kk + j][vc];
            unsigned short hh = bf16_rne(x);
            h8[j] = hh; l8[j] = bf16_rne(x - bf16_tof(hh));
        }
        size_t off = ((size_t)bh * 128 + vc) * NK + (kt << 6) + kk;
        *(us8*)(hi + off) = h8;
        *(us8*)(lo + off) = l8;
    }
}

__global__ __launch_bounds__(256) void cbias_kernel(const float* __restrict__ al, float* __restrict__ cb) {
    int idx = blockIdx.x * 256 + threadIdx.x;
    float v = al[idx];
    cb[idx] = (v > 0.0f) ? __logf(fmaxf(v, 1e-30f)) : -INF30;
}

// ---------------- attn10: shuffle-free softmax (l via ones-MFMA, lazy max) ----------------
// attn9 structure + two changes that remove the 64 dependent __shfl_xor per ti:
//  * l-sum via MFMA: Oe = mfma(pah,ones) + mfma(pal,ones) -> each row's sum(p) lands in the
//    accumulator layout (B all-ones => every out col = row-sum). Consistent with exact P
//    used in PV. Replaces 16-shfl sum tree with 2 MFMAs.
//  * lazy max (T13): max tree + O/Oe rescale only when __any(max(S)-mrun > 8) (first ti +
//    rare). P bounded by e^8; f32 accum safe.
#define PSTR 40
__global__ __launch_bounds__(256, 2) void attn10_kernel(
        const ushort_t* __restrict__ Qu_hi, const ushort_t* __restrict__ Qu_lo,
        const ushort_t* __restrict__ Qv_hi,
        const ushort_t* __restrict__ K_hi,  const ushort_t* __restrict__ K_lo,
        const ushort_t* __restrict__ C_hi,  const ushort_t* __restrict__ C_lo,
        const ushort_t* __restrict__ Vt_hi, const ushort_t* __restrict__ Vt_lo,
        const ushort_t* __restrict__ At_hi, const ushort_t* __restrict__ At_lo,
        const ushort_t* __restrict__ R_hi,
        const float* __restrict__ cbias, const float* __restrict__ gbuf,
        float* __restrict__ wvg) {
    __shared__ __align__(16) ushort_t KS[2][2][32 * 128];  // [buf][hi/lo], swizzled
    __shared__ __align__(16) ushort_t VS[2][2][128 * 32];  // [buf][hi/lo], swizzled
    __shared__ __align__(16) ushort_t Phs[4][16 * PSTR];
    __shared__ __align__(16) ushort_t Pls[4][16 * PSTR];

    int t = threadIdx.x;
    int wvid = t >> 6, ln = t & 63;
    int col = ln & 15, quad = ln >> 4;
    int blk = blockIdx.x;
    int xcd = blk & 7, idx = blk >> 3;
    int bh = ((idx >> 3) << 3) + xcd;
    int j = idx & 7;
    int jt = ((wvid & 1) ? (15 - j) : j) + ((wvid & 2) ? 16 : 0);
    int l0 = jt << 4;
    int h = bh & 7, b = bh >> 3;

    int nt2own = (l0 + 47) >> 5;
    int nt2max = (((31 - j) << 4) + 47) >> 5;
    int Tt = 32 + nt2max;

    // persistent Q fragments
    size_t qb = ((size_t)bh * 512 + l0 + col) * 128 + quad * 8;
    bf16x8 quh[4], qul[4], qvf[4];
#pragma unroll
    for (int s = 0; s < 4; ++s) {
        quh[s] = ldb8(Qu_hi + qb + 32 * s);
        qul[s] = ldb8(Qu_lo + qb + 32 * s);
        qvf[s] = ldb8(Qv_hi + qb + 32 * s);
    }
    bf16x8 onesv;
#pragma unroll
    for (int i = 0; i < 8; ++i) onesv[i] = (short)0x3F80;

    f32x4 O[8];
#pragma unroll
    for (int u = 0; u < 8; ++u) O[u] = (f32x4){0.f, 0.f, 0.f, 0.f};
    f32x4 Oe = (f32x4){0.f, 0.f, 0.f, 0.f};   // row-sum(p) accumulator (l)
    float mrun[4];
#pragma unroll
    for (int r = 0; r < 4; ++r) mrun[r] = -INF30;

    ushort_t* Ph = Phs[wvid];
    ushort_t* Pl = Pls[wvid];

    // ---- prologue: stage K[0]/V[0]; prefetch R for ti=0 ----
    {
        const ushort_t* nkh = K_hi + ((size_t)bh * 1024) * 128;
        const ushort_t* nkl = K_lo + ((size_t)bh * 1024) * 128;
#pragma unroll
        for (int m = 0; m < 2; ++m) {
            int r = wvid * 8 + m * 4 + (ln >> 4);
            int c = ln & 15;
            us8 vh8 = *(const us8*)(nkh + (size_t)r * 128 + c * 8);
            us8 vl8 = *(const us8*)(nkl + (size_t)r * 128 + c * 8);
            int dst = r * 128 + ((c ^ (r & 7)) << 3);
            *(us8*)&KS[0][0][dst] = vh8;
            *(us8*)&KS[0][1][dst] = vl8;
        }
        const ushort_t* vhp = Vt_hi + ((size_t)bh << 17);
        const ushort_t* vlp = Vt_lo + ((size_t)bh << 17);
#pragma unroll
        for (int m = 0; m < 2; ++m) {
            int dV = wvid * 128 + m * 64 + ln;
            int v = dV >> 2, c = dV & 3;
            us8 vh8 = *(const us8*)(vhp + (size_t)v * 1024 + c * 8);
            us8 vl8 = *(const us8*)(vlp + (size_t)v * 1024 + c * 8);
            int dst = v * 32 + ((c ^ ((v >> 1) & 3)) << 3);
            *(us8*)&VS[0][0][dst] = vh8;
            *(us8*)&VS[0][1][dst] = vl8;
        }
    }
    bf16x8 rg[3][4];
    {
        int jt0 = 496 - l0;
#pragma unroll
        for (int u = 0; u < 3; ++u) {
            int jr = jt0 + 16 * u + col;
            jr = (jr > 1023) ? 1023 : jr;
            const ushort_t* rp = R_hi + ((size_t)(h << 10) + jr) * 128 + quad * 8;
#pragma unroll
            for (int s = 0; s < 4; ++s) rg[u][s] = ldb8(rp + 32 * s);
        }
    }
    __syncthreads();
    int cur = 0;

    for (int ti = 0; ti < Tt; ++ti) {
        int seg, w0;
        if (ti < 16)      { seg = 0; w0 = ti << 5; }
        else if (ti < 32) { seg = 1; w0 = (ti - 16) << 5; }
        else              { seg = 2; w0 = (ti - 32) << 5; }
        bool act = (seg != 2) || ((ti - 32) < nt2own);

        int tn = ti + 1;
        bool hasNext = tn < Tt;
        int seg_n = 0, w0_n = 0;
        if (tn < 16)      { seg_n = 0; w0_n = tn << 5; }
        else if (tn < 32) { seg_n = 1; w0_n = (tn - 16) << 5; }
        else              { seg_n = 2; w0_n = (tn - 32) << 5; }
        bool act_n = hasNext && ((seg_n != 2) || ((tn - 32) < nt2own));

        // ---- issue next-iteration K and V global loads ----
        us8 krh[2], krl[2], vrh[2], vrl[2];
        if (hasNext) {
            const ushort_t *nkh, *nkl;
            if (seg_n == 0)      { nkh = K_hi + ((size_t)bh * 1024 + w0_n) * 128;
                                   nkl = K_lo + ((size_t)bh * 1024 + w0_n) * 128; }
            else if (seg_n == 1) { nkh = C_hi + ((size_t)(h << 9) + w0_n) * 128;
                                   nkl = C_lo + ((size_t)(h << 9) + w0_n) * 128; }
            else                 { nkh = K_hi + ((size_t)bh * 1024 + 512 + w0_n) * 128;
                                   nkl = K_lo + ((size_t)bh * 1024 + 512 + w0_n) * 128; }
#pragma unroll
            for (int m = 0; m < 2; ++m) {
                int r = wvid * 8 + m * 4 + (ln >> 4);
                int c = ln & 15;
                krh[m] = *(const us8*)(nkh + (size_t)r * 128 + c * 8);
                krl[m] = *(const us8*)(nkl + (size_t)r * 128 + c * 8);
            }
            const ushort_t *vhp, *vlp; size_t vstr; int wbase;
            if (seg_n == 0)      { vhp = Vt_hi + ((size_t)bh << 17); vlp = Vt_lo + ((size_t)bh << 17); vstr = 1024; wbase = w0_n; }
            else if (seg_n == 1) { vhp = At_hi + ((size_t)bh << 16); vlp = At_lo + ((size_t)bh << 16); vstr = 512;  wbase = w0_n; }
            else                 { vhp = Vt_hi + ((size_t)bh << 17); vlp = Vt_lo + ((size_t)bh << 17); vstr = 1024; wbase = 512 + w0_n; }
#pragma unroll
            for (int m = 0; m < 2; ++m) {
                int dV = wvid * 128 + m * 64 + ln;
                int v = dV >> 2, c = dV & 3;
                vrh[m] = *(const us8*)(vhp + (size_t)v * vstr + wbase + c * 8);
                vrl[m] = *(const us8*)(vlp + (size_t)v * vstr + wbase + c * 8);
            }
        }

        // ---- G phase from prefetched R registers ----
        f32x4 Gacc[3];
        f32x4 S[2];
        if (act && seg != 1) {
#pragma unroll
            for (int u = 0; u < 3; ++u) {
                f32x4 acc = (f32x4){0.f, 0.f, 0.f, 0.f};
                acc = MFMA16(qvf[0], rg[u][0], acc);
                acc = MFMA16(qvf[1], rg[u][1], acc);
                acc = MFMA16(qvf[2], rg[u][2], acc);
                acc = MFMA16(qvf[3], rg[u][3], acc);
                Gacc[u] = acc;
            }
        }

        // ---- R prefetch for ti+1 ----
        if (act_n && seg_n != 1) {
            int jt0n = ((seg_n == 0) ? w0_n : (512 + w0_n)) + 496 - l0;
#pragma unroll
            for (int u = 0; u < 3; ++u) {
                int jr = jt0n + 16 * u + col;
                jr = (jr > 1023) ? 1023 : jr;
                const ushort_t* rp = R_hi + ((size_t)(h << 10) + jr) * 128 + quad * 8;
#pragma unroll
                for (int s = 0; s < 4; ++s) rg[u][s] = ldb8(rp + 32 * s);
            }
        }

        // ---- QK^T from LDS K[cur] ----
        if (act) {
            S[0] = (f32x4){0.f, 0.f, 0.f, 0.f};
            S[1] = (f32x4){0.f, 0.f, 0.f, 0.f};
            const ushort_t* KH = KS[cur][0];
            const ushort_t* KL = KS[cur][1];
            int swz = col & 7;
            __builtin_amdgcn_s_setprio(1);
#pragma unroll
            for (int s = 0; s < 4; ++s) {
                int cofs = ((quad + 4 * s) ^ swz) << 3;
                bf16x8 k0h = *(const bf16x8*)&KH[col * 128 + cofs];
                bf16x8 k0l = *(const bf16x8*)&KL[col * 128 + cofs];
                bf16x8 k1h = *(const bf16x8*)&KH[(16 + col) * 128 + cofs];
                bf16x8 k1l = *(const bf16x8*)&KL[(16 + col) * 128 + cofs];
                S[0] = MFMA16(quh[s], k0h, S[0]);
                S[0] = MFMA16(qul[s], k0h, S[0]);
                S[0] = MFMA16(quh[s], k0l, S[0]);
                S[1] = MFMA16(quh[s], k1h, S[1]);
                S[1] = MFMA16(qul[s], k1h, S[1]);
                S[1] = MFMA16(quh[s], k1l, S[1]);
            }
            __builtin_amdgcn_s_setprio(0);
        }

        // ---- fixup + shuffle-free online softmax + P frags ----
        bf16x8 pah = {}, pal = {};
        if (act) {
            float bias0 = 0.f, bias1 = 0.f;
            if (seg == 1) {
                bias0 = cbias[(size_t)(bh << 9) + w0 + col];
                bias1 = cbias[(size_t)(bh << 9) + w0 + 16 + col];
            }
#pragma unroll
            for (int t2 = 0; t2 < 2; ++t2) {
#pragma unroll
                for (int r = 0; r < 4; ++r) {
                    int row = 4 * quad + r;
                    float sv = S[t2][r];
                    if (seg != 1) {
                        int d = col + 15 - row;
                        int src = quad * 16 + (d & 15);
                        float g0 = __shfl(Gacc[t2][r], src);
                        float g1 = __shfl(Gacc[t2 + 1][r], src);
                        float gv = (d >= 16) ? g1 : g0;
                        sv = (sv + gv) * INV_TAU;
                        if (seg == 2 && (w0 + 16 * t2 + col > l0 + row)) sv = -INF30;
                    } else {
                        sv = sv * INV_TAU + ((t2 == 0) ? bias0 : bias1);
                    }
                    S[t2][r] = sv;
                }
            }
            // lazy max: local check only; tree+rescale on rare trigger
            float mx[4];
            float need = -INF30;
#pragma unroll
            for (int r = 0; r < 4; ++r) {
                mx[r] = fmaxf(S[0][r], S[1][r]);
                need = fmaxf(need, mx[r] - mrun[r]);
            }
            if (__any(need > 8.0f)) {
#pragma unroll
                for (int r = 0; r < 4; ++r) {
                    float mv = mx[r];
#pragma unroll
                    for (int m = 8; m > 0; m >>= 1) mv = fmaxf(mv, __shfl_xor(mv, m));
                    float mnew = fmaxf(mrun[r], mv);
                    float alpha = __expf(mrun[r] - mnew);
                    mrun[r] = mnew;
                    Oe[r] *= alpha;
#pragma unroll
                    for (int u = 0; u < 8; ++u) O[u][r] *= alpha;
                }
            }
#pragma unroll
            for (int r = 0; r < 4; ++r) {
                float p0 = __expf(S[0][r] - mrun[r]);
                float p1 = __expf(S[1][r] - mrun[r]);
                int row = 4 * quad + r;
                unsigned short h0 = bf16_rne(p0);
                Ph[row * PSTR + col] = h0;
                Pl[row * PSTR + col] = bf16_rne(p0 - bf16_tof(h0));
                unsigned short h1 = bf16_rne(p1);
                Ph[row * PSTR + 16 + col] = h1;
                Pl[row * PSTR + 16 + col] = bf16_rne(p1 - bf16_tof(h1));
            }
            pah = *(const bf16x8*)&Ph[col * PSTR + quad * 8];
            pal = *(const bf16x8*)&Pl[col * PSTR + quad * 8];
        }

        // ---- PV from LDS V[cur] (+ l accumulation via ones-column MFMA) ----
        if (act) {
            const ushort_t* VH = VS[cur][0];
            const ushort_t* VL = VS[cur][1];
            int vswz = (quad ^ ((col >> 1) & 3)) << 3;
            __builtin_amdgcn_s_setprio(1);
#pragma unroll
            for (int u = 0; u < 8; ++u) {
                int vrow = 16 * u + col;
                bf16x8 vbh = *(const bf16x8*)&VH[vrow * 32 + vswz];
                bf16x8 vbl = *(const bf16x8*)&VL[vrow * 32 + vswz];
                O[u] = MFMA16(pah, vbh, O[u]);
                O[u] = MFMA16(pal, vbh, O[u]);
                O[u] = MFMA16(pah, vbl, O[u]);
            }
            Oe = MFMA16(pah, onesv, Oe);
            Oe = MFMA16(pal, onesv, Oe);
            __builtin_amdgcn_s_setprio(0);
        }

        // ---- late ds_writes of next K/V into buf^1 ----
        if (hasNext) {
#pragma unroll
            for (int m = 0; m < 2; ++m) {
                int r = wvid * 8 + m * 4 + (ln >> 4);
                int c = ln & 15;
                int dst = r * 128 + ((c ^ (r & 7)) << 3);
                *(us8*)&KS[cur ^ 1][0][dst] = krh[m];
                *(us8*)&KS[cur ^ 1][1][dst] = krl[m];
            }
#pragma unroll
            for (int m = 0; m < 2; ++m) {
                int dV = wvid * 128 + m * 64 + ln;
                int v = dV >> 2, c = dV & 3;
                int dst = v * 32 + ((c ^ ((v >> 1) & 3)) << 3);
                *(us8*)&VS[cur ^ 1][0][dst] = vrh[m];
                *(us8*)&VS[cur ^ 1][1][dst] = vrl[m];
            }
        }

        __syncthreads();   // single barrier per ti
        cur ^= 1;
    }

    // ---- direct gated write-out (l = Oe) ----
#pragma unroll
    for (int r = 0; r < 4; ++r) {
        int row = quad * 4 + r;
        float linv = 1.0f / Oe[r];
#pragma unroll
        for (int u = 0; u < 8; ++u) {
            size_t gi = ((size_t)b * 512 + l0 + row) * 1024 + (h << 7) + 16 * u + col;
            wvg[gi] = O[u][r] * linv * gbuf[gi];
        }
    }
}

extern "C" void kernel_launch(void* const* d_in, const int* in_sizes, int n_in,
                              void* d_out, int out_size, void* d_ws, size_t ws_size,
                              hipStream_t stream) {
    const float* x_in  = (const float*)d_in[0];
    const float* xl_k  = (const float*)d_in[2];
    const float* xl_v  = (const float*)d_in[3];
    const float* agg_u = (const float*)d_in[4];
    const float* agg_l = (const float*)d_in[5];
    const float* W_q   = (const float*)d_in[6];
    const float* W_kvg = (const float*)d_in[7];
    const float* W_res = (const float*)d_in[8];
    const float* x_u   = (const float*)d_in[9];
    const float* x_v   = (const float*)d_in[10];
    const float* xl_r  = (const float*)d_in[11];
    const float* cbk   = (const float*)d_in[12];
    float* out = (float*)d_out;
    char* wb = (char*)d_ws;

    float*  x_t   = (float*)(wb);                       // 16 MB [alias: K_hi; later Awh/Awl]
    float*  qbuf  = (float*)(wb + 16777216ul);          // 16 MB [alias: Vt_lo]
    float*  kbuf  = (float*)(wb + 33554432ul);          // 16 MB [alias: Vt_hi]
    float*  vbuf  = (float*)(wb + 50331648ul);          // 16 MB [alias: At_hi+At_lo]
    float*  gbuf  = (float*)(wb + 67108864ul);          // 16 MB
    float*  wvg   = (float*)(wb + 83886080ul);          // 16 MB [alias: Ah+Al pre-attn]
    float*  cT    = (float*)(wb + 100663296ul);         // 2 MB  [alias: C_hi+C_lo]
    float*  cnm   = (float*)(wb + 102760448ul);         // 16 KB
    ushort_t* Qu_hi = (ushort_t*)(wb + 102776832ul);    // 8 MB  [alias: Wtq pre-split]
    ushort_t* Qu_lo = (ushort_t*)(wb + 111165440ul);    // 8 MB  [alias: Wtvg pre-split]
    ushort_t* Qv_hi = (ushort_t*)(wb + 119554048ul);    // 8 MB  [alias: Wtres post-attn]
    ushort_t* K_lo  = (ushort_t*)(wb + 136331264ul);    // 16 MB
    ushort_t* R_hi  = (ushort_t*)(wb + 153108480ul);    // 2 MB
    float*  cbias   = (float*)(wb + 157302784ul);       // 128 KB

    ushort_t* K_hi  = (ushort_t*)x_t;
    ushort_t* Vt_hi = (ushort_t*)kbuf;
    ushort_t* Vt_lo = (ushort_t*)qbuf;
    ushort_t* At_hi = (ushort_t*)vbuf;
    ushort_t* At_lo = (ushort_t*)(wb + 50331648ul + 8388608ul);
    ushort_t* C_hi  = (ushort_t*)cT;
    ushort_t* C_lo  = (ushort_t*)(wb + 100663296ul + 1048576ul);

    ushort_t* Ah      = (ushort_t*)wvg;
    ushort_t* Al      = (ushort_t*)(wb + 83886080ul + 8388608ul);
    ushort_t* Wtq_hi  = (ushort_t*)Qu_hi;
    ushort_t* Wtq_lo  = (ushort_t*)(wb + 102776832ul + 2097152ul);
    ushort_t* Wtvg_hi = (ushort_t*)Qu_lo;
    ushort_t* Wtvg_lo = (ushort_t*)(wb + 111165440ul + 4194304ul);
    ushort_t* Wtres_hi = (ushort_t*)Qv_hi;
    ushort_t* Wtres_lo = (ushort_t*)(wb + 119554048ul + 2097152ul);
    ushort_t* Awh     = (ushort_t*)x_t;
    ushort_t* Awl     = (ushort_t*)(wb + 8388608ul);

    // 1) input LN
    ln_dm_kernel<<<4096, 256, 0, stream>>>(x_in, x_t);
    // 2) split activations + weights for bf16 GEMMs
    split_plain_kernel<<<16384, 256, 0, stream>>>(x_t, Ah, Al);
    wtsplit_kernel<<<dim3(16, 16), 256, 0, stream>>>(W_q, 1024, 0, Wtq_hi, Wtq_lo);
    wtsplit_kernel<<<dim3(32, 16), 256, 0, stream>>>(W_kvg, 3072, 1024, Wtvg_hi, Wtvg_lo);
    // 3) GEMMs: q (bf16), v+g (bf16), k (fp32 reg-blocked — argmin-critical)
    gemm_bf16_kernel<<<dim3(8, 32), 256, 0, stream>>>(Ah, Al, Wtq_hi, Wtq_lo, 0, qbuf, nullptr);
    gemm_bf16_kernel<<<dim3(16, 32), 256, 0, stream>>>(Ah, Al, Wtvg_hi, Wtvg_lo, 1, vbuf, gbuf);
    gemm_kernel<<<dim3(8, 32), 256, 0, stream>>>(x_t, W_kvg, 3072, 0, kbuf, nullptr, nullptr);
    // 4) LN(q), LN(k); VQ
    ln128_kernel<<<16384, 256, 0, stream>>>(qbuf, kbuf);
    cbt_kernel<<<2048, 256, 0, stream>>>(cbk, cT);
    cnorm_kernel<<<1024, 256, 0, stream>>>(cbk, cnm);
    vq_kernel<<<2048, 256, 0, stream>>>(kbuf, cT, cnm, cbk);
    // 5) attention preps
    split_q_kernel<<<16384, 256, 0, stream>>>(qbuf, x_u, x_v, Qu_hi, Qu_lo, Qv_hi);
    split_koff_kernel<<<16384, 256, 0, stream>>>(xl_k, K_hi, K_lo, 0);
    split_koff_kernel<<<16384, 256, 0, stream>>>(kbuf, K_hi, K_lo, 512);
    split_plain_kernel<<<2048, 256, 0, stream>>>(cbk, C_hi, C_lo);
    cvt_hi_kernel<<<4096, 256, 0, stream>>>(xl_r, R_hi);
    vtsplit_kernel<<<dim3(64, 16), 256, 0, stream>>>(xl_v, vbuf, Vt_hi, Vt_lo, 1024);
    vtsplit_kernel<<<dim3(64, 8), 256, 0, stream>>>(agg_u, agg_u, At_hi, At_lo, 512);
    cbias_kernel<<<128, 256, 0, stream>>>(agg_l, cbias);
    // 6) shuffle-free-softmax fused attention
    attn10_kernel<<<512, 256, 0, stream>>>(Qu_hi, Qu_lo, Qv_hi, K_hi, K_lo, C_hi, C_lo,
                                           Vt_hi, Vt_lo, At_hi, At_lo, R_hi,
                                           cbias, gbuf, wvg);
    // 7) output GEMM (bf16)
    split_plain_kernel<<<16384, 256, 0, stream>>>(wvg, Awh, Awl);
    wtsplit_kernel<<<dim3(16, 16), 256, 0, stream>>>(W_res, 1024, 0, Wtres_hi, Wtres_lo);
    gemm_bf16_kernel<<<dim3(8, 32), 256, 0, stream>>>(Awh, Awl, Wtres_hi, Wtres_lo, 2, out, nullptr);
}

// Round 8
// 747.655 us; speedup vs baseline: 1.7683x; 1.0427x over previous
//
#include <hip/hip_runtime.h>

#define INF30 1e30f
#define INV_TAU 0.08838834764831845f

typedef unsigned short ushort_t;
typedef __attribute__((ext_vector_type(8))) short bf16x8;
typedef __attribute__((ext_vector_type(4))) float f32x4;
typedef __attribute__((ext_vector_type(8))) unsigned short us8;
typedef __attribute__((ext_vector_type(4))) unsigned short us4;
typedef __attribute__((ext_vector_type(2))) unsigned short us2;

__device__ __forceinline__ float4 ld4(const float* p) { return *(const float4*)p; }

__device__ __forceinline__ unsigned short bf16_rne(float x) {
    unsigned int u = __float_as_uint(x);
    unsigned int r = u + 0x7fffu + ((u >> 16) & 1u);
    return (unsigned short)(r >> 16);
}
__device__ __forceinline__ float bf16_tof(unsigned short h) {
    return __uint_as_float(((unsigned int)h) << 16);
}
__device__ __forceinline__ bf16x8 ldb8(const ushort_t* p) { return *(const bf16x8*)p; }

#define MFMA16(a, b, c) __builtin_amdgcn_mfma_f32_16x16x32_bf16((a), (b), (c), 0, 0, 0)

// ======== LayerNorm over DM=1024 with fused bf16 hi/lo emission ========
__global__ __launch_bounds__(256) void ln_dm_kernel(const float* __restrict__ x, float* __restrict__ y,
                                                    ushort_t* __restrict__ Ah, ushort_t* __restrict__ Al) {
    size_t row = blockIdx.x;
    const float4* xr = (const float4*)(x + row * 1024);
    float4 v = xr[threadIdx.x];
    float s  = v.x + v.y + v.z + v.w;
    float ss = v.x*v.x + v.y*v.y + v.z*v.z + v.w*v.w;
#pragma unroll
    for (int off = 32; off > 0; off >>= 1) {
        s  += __shfl_down(s, off);
        ss += __shfl_down(ss, off);
    }
    __shared__ float rs[4], rss[4];
    int wv = threadIdx.x >> 6, ln = threadIdx.x & 63;
    if (ln == 0) { rs[wv] = s; rss[wv] = ss; }
    __syncthreads();
    s  = rs[0] + rs[1] + rs[2] + rs[3];
    ss = rss[0] + rss[1] + rss[2] + rss[3];
    float mu  = s * (1.0f/1024.0f);
    float var = ss * (1.0f/1024.0f) - mu*mu;
    float r = rsqrtf(var + 1e-6f);
    float4 o;
    o.x = (v.x - mu) * r; o.y = (v.y - mu) * r; o.z = (v.z - mu) * r; o.w = (v.w - mu) * r;
    ((float4*)(y + row * 1024))[threadIdx.x] = o;
    float ov[4] = {o.x, o.y, o.z, o.w};
    us4 h4, l4v;
#pragma unroll
    for (int j = 0; j < 4; ++j) {
        unsigned short hh = bf16_rne(ov[j]);
        h4[j] = hh; l4v[j] = bf16_rne(ov[j] - bf16_tof(hh));
    }
    size_t off = row * 1024 + threadIdx.x * 4;
    *(us4*)(Ah + off) = h4;
    *(us4*)(Al + off) = l4v;
}

// ======== fp32 GEMM, 128x128 tile, 8x8 per thread (k projection, argmin path) ========
__global__ __launch_bounds__(256) void gemm_kernel(const float* __restrict__ A, const float* __restrict__ W,
                                                   int N, int mode,
                                                   float* __restrict__ o0, float* __restrict__ o1,
                                                   float* __restrict__ o2) {
    __shared__ float As[16][128];
    __shared__ float Bs[16][128];
    int t = threadIdx.x;
    int col0 = blockIdx.x << 7;
    int row0 = blockIdx.y << 7;
    int tx = t & 15, ty = t >> 4;
    int arow = t >> 1, akq = (t & 1) * 8;
    int bkr = t >> 4, bcq = (t & 15) * 4;
    const float* Ap = A + (size_t)(row0 + arow) * 1024 + akq;
    const float* Wp = W + (size_t)bkr * N + col0 + bcq;
    float acc[8][8];
#pragma unroll
    for (int i = 0; i < 8; ++i)
#pragma unroll
        for (int j = 0; j < 8; ++j) acc[i][j] = 0.0f;

    float4 a0 = ld4(Ap), a1 = ld4(Ap + 4);
    float4 b0 = ld4(Wp), b1 = ld4(Wp + 64);

    for (int kt = 0; kt < 64; ++kt) {
        __syncthreads();
        As[akq+0][arow] = a0.x; As[akq+1][arow] = a0.y;
        As[akq+2][arow] = a0.z; As[akq+3][arow] = a0.w;
        As[akq+4][arow] = a1.x; As[akq+5][arow] = a1.y;
        As[akq+6][arow] = a1.z; As[akq+7][arow] = a1.w;
        *(float4*)&Bs[bkr][bcq]      = b0;
        *(float4*)&Bs[bkr][64 + bcq] = b1;
        __syncthreads();
        if (kt < 63) {
            a0 = ld4(Ap + (kt + 1) * 16);
            a1 = ld4(Ap + (kt + 1) * 16 + 4);
            b0 = ld4(Wp + (size_t)(kt + 1) * 16 * N);
            b1 = ld4(Wp + (size_t)(kt + 1) * 16 * N + 64);
        }
#pragma unroll
        for (int kk = 0; kk < 16; ++kk) {
            float4 av0 = *(float4*)&As[kk][ty * 4];
            float4 av1 = *(float4*)&As[kk][64 + ty * 4];
            float4 bv0 = *(float4*)&Bs[kk][tx * 4];
            float4 bv1 = *(float4*)&Bs[kk][64 + tx * 4];
            float a8[8] = {av0.x, av0.y, av0.z, av0.w, av1.x, av1.y, av1.z, av1.w};
            float b8[8] = {bv0.x, bv0.y, bv0.z, bv0.w, bv1.x, bv1.y, bv1.z, bv1.w};
#pragma unroll
            for (int i = 0; i < 8; ++i)
#pragma unroll
                for (int j = 0; j < 8; ++j) acc[i][j] += a8[i] * b8[j];
        }
    }

#pragma unroll
    for (int i = 0; i < 8; ++i) {
        int rr = row0 + ((i < 4) ? (ty * 4 + i) : (64 + ty * 4 + i - 4));
        int b = rr >> 9, l = rr & 511;
#pragma unroll
        for (int j = 0; j < 8; ++j) {
            int cc = col0 + ((j < 4) ? (tx * 4 + j) : (64 + tx * 4 + j - 4));
            float vv = acc[i][j];
            if (mode == 0) {
                o0[((size_t)((b<<3) + (cc>>7)) * 512 + l) * 128 + (cc & 127)] = vv;
            } else if (mode == 1) {
                if (cc < 1024) {
                    o0[((size_t)((b<<3) + (cc>>7)) * 512 + l) * 128 + (cc & 127)] = vv;
                } else if (cc < 2048) {
                    int c2 = cc - 1024;
                    o1[((size_t)((b<<3) + (c2>>7)) * 512 + l) * 128 + (c2 & 127)] = vv;
                } else {
                    o2[(size_t)rr * 1024 + (cc - 2048)] = vv / (1.0f + __expf(-vv));
                }
            } else {
                o0[(size_t)rr * 1024 + cc] = vv;
            }
        }
    }
}

// ======== weight transpose + bf16 hi/lo split ========
__global__ __launch_bounds__(256) void wtsplit_kernel(const float* __restrict__ W, int Ntot, int c0,
                                                      ushort_t* __restrict__ th, ushort_t* __restrict__ tl) {
    __shared__ float T[64][68];
    int n0 = blockIdx.x << 6, k0 = blockIdx.y << 6, t = threadIdx.x;
    for (int i = t; i < 1024; i += 256) {
        int kk = i >> 4, nn4 = (i & 15) << 2;
        *(float4*)&T[kk][nn4] = ld4(W + (size_t)(k0 + kk) * Ntot + c0 + n0 + nn4);
    }
    __syncthreads();
    for (int i = t; i < 512; i += 256) {
        int nn = i >> 3, kc = (i & 7) << 3;
        us8 h8, l8;
#pragma unroll
        for (int j = 0; j < 8; ++j) {
            float x = T[kc + j][nn];
            unsigned short hh = bf16_rne(x);
            h8[j] = hh; l8[j] = bf16_rne(x - bf16_tof(hh));
        }
        size_t off = (size_t)(n0 + nn) * 1024 + k0 + kc;
        *(us8*)(th + off) = h8;
        *(us8*)(tl + off) = l8;
    }
}

// ======== bf16 3-term split GEMM ========
#define GSTRIDE 40
__global__ __launch_bounds__(256) void gemm_bf16_kernel(
        const ushort_t* __restrict__ Ah, const ushort_t* __restrict__ Al,
        const ushort_t* __restrict__ Bth, const ushort_t* __restrict__ Btl,
        int mode, float* __restrict__ o0, float* __restrict__ o1) {
    __shared__ ushort_t LA[2][128 * GSTRIDE];
    __shared__ ushort_t LB[2][128 * GSTRIDE];
    int t = threadIdx.x;
    int col0 = blockIdx.x << 7, row0 = blockIdx.y << 7;
    int wvid = t >> 6, ln = t & 63;
    int lcol = ln & 15, quad = ln >> 4;
    int qm = wvid >> 1, qn = wvid & 1;

    f32x4 C[4][4];
#pragma unroll
    for (int i = 0; i < 4; ++i)
#pragma unroll
        for (int j = 0; j < 4; ++j) C[i][j] = (f32x4){0.f, 0.f, 0.f, 0.f};

    for (int k0 = 0; k0 < 1024; k0 += 32) {
        us8 ra[2][2], rb[2][2];
#pragma unroll
        for (int v = 0; v < 2; ++v) {
            int cid = t + 256 * v;
            int row = cid >> 2, ch = cid & 3;
            size_t ga = (size_t)(row0 + row) * 1024 + k0 + ch * 8;
            size_t gb = (size_t)(col0 + row) * 1024 + k0 + ch * 8;
            ra[v][0] = *(const us8*)(Ah + ga);
            ra[v][1] = *(const us8*)(Al + ga);
            rb[v][0] = *(const us8*)(Bth + gb);
            rb[v][1] = *(const us8*)(Btl + gb);
        }
        __syncthreads();
#pragma unroll
        for (int v = 0; v < 2; ++v) {
            int cid = t + 256 * v;
            int row = cid >> 2, ch = cid & 3;
            *(us8*)&LA[0][row * GSTRIDE + ch * 8] = ra[v][0];
            *(us8*)&LA[1][row * GSTRIDE + ch * 8] = ra[v][1];
            *(us8*)&LB[0][row * GSTRIDE + ch * 8] = rb[v][0];
            *(us8*)&LB[1][row * GSTRIDE + ch * 8] = rb[v][1];
        }
        __syncthreads();
        bf16x8 afh[4], afl[4], bfh[4], bfl[4];
#pragma unroll
        for (int i = 0; i < 4; ++i) {
            int r = qm * 64 + i * 16 + lcol;
            afh[i] = *(const bf16x8*)&LA[0][r * GSTRIDE + quad * 8];
            afl[i] = *(const bf16x8*)&LA[1][r * GSTRIDE + quad * 8];
            int c = qn * 64 + i * 16 + lcol;
            bfh[i] = *(const bf16x8*)&LB[0][c * GSTRIDE + quad * 8];
            bfl[i] = *(const bf16x8*)&LB[1][c * GSTRIDE + quad * 8];
        }
#pragma unroll
        for (int i = 0; i < 4; ++i)
#pragma unroll
            for (int j = 0; j < 4; ++j) {
                C[i][j] = MFMA16(afh[i], bfh[j], C[i][j]);
                C[i][j] = MFMA16(afl[i], bfh[j], C[i][j]);
                C[i][j] = MFMA16(afh[i], bfl[j], C[i][j]);
            }
    }

#pragma unroll
    for (int i = 0; i < 4; ++i) {
#pragma unroll
        for (int r = 0; r < 4; ++r) {
            int rr = row0 + qm * 64 + 16 * i + quad * 4 + r;
            int b = rr >> 9, l = rr & 511;
#pragma unroll
            for (int j = 0; j < 4; ++j) {
                int cc = col0 + qn * 64 + 16 * j + lcol;
                float vv = C[i][j][r];
                if (mode == 0) {
                    o0[((size_t)((b<<3) + (cc>>7)) * 512 + l) * 128 + (cc & 127)] = vv;
                } else if (mode == 1) {
                    if (cc < 1024) o0[((size_t)((b<<3) + (cc>>7)) * 512 + l) * 128 + (cc & 127)] = vv;
                    else o1[(size_t)rr * 1024 + (cc - 1024)] = vv / (1.0f + __expf(-vv));
                } else {
                    o0[(size_t)rr * 1024 + cc] = vv;
                }
            }
        }
    }
}

// ======== codebook transpose + norms, single pass ========
__global__ __launch_bounds__(256) void cbtn_kernel(const float* __restrict__ cb, float* __restrict__ cT,
                                                   float* __restrict__ cn) {
    int wv = threadIdx.x >> 6, ln = threadIdx.x & 63;
    int row = (blockIdx.x << 2) + wv;
    float2 x = *(const float2*)(cb + (size_t)row * 128 + (ln << 1));
    float ss = x.x*x.x + x.y*x.y;
#pragma unroll
    for (int m = 32; m > 0; m >>= 1) ss += __shfl_xor(ss, m);
    if (ln == 0) cn[row] = ss;
    int h = row >> 9, s = row & 511, d = ln << 1;
    cT[((size_t)((h << 7) + d)) * 512 + s] = x.x;
    cT[((size_t)((h << 7) + d + 1)) * 512 + s] = x.y;
}

// ======== VQ argmin, fused LN(k) in-register, direct K hi/lo emission rows 512+ ========
__global__ __launch_bounds__(256) void vq_kernel(const float* __restrict__ kb, const float* __restrict__ cT,
                                                 const float* __restrict__ cn, const float* __restrict__ cb,
                                                 ushort_t* __restrict__ Khi, ushort_t* __restrict__ Klo) {
    __shared__ float sK[4][4][128];
    int wv = threadIdx.x >> 6, ln = threadIdx.x & 63;
    int gw = (blockIdx.x << 2) + wv;
    int bh = gw >> 7;
    int l4 = (gw & 127) << 2;
    int h = bh & 7;
    size_t r0 = ((size_t)bh << 9) + l4;
    float2 kreg[4];
#pragma unroll
    for (int i = 0; i < 4; ++i)
        kreg[i] = *(const float2*)(kb + (r0 + i) * 128 + (ln << 1));
#pragma unroll
    for (int i = 0; i < 4; ++i) {
        float s  = kreg[i].x + kreg[i].y;
        float ss = kreg[i].x*kreg[i].x + kreg[i].y*kreg[i].y;
#pragma unroll
        for (int m = 32; m > 0; m >>= 1) { s += __shfl_xor(s, m); ss += __shfl_xor(ss, m); }
        float mu  = s * (1.0f/128.0f);
        float var = ss * (1.0f/128.0f) - mu*mu;
        float rr = rsqrtf(var + 1e-6f);
        kreg[i].x = (kreg[i].x - mu) * rr;
        kreg[i].y = (kreg[i].y - mu) * rr;
        sK[wv][i][(ln<<1)]   = kreg[i].x;
        sK[wv][i][(ln<<1)+1] = kreg[i].y;
    }
    __syncthreads();
    const float* ct = cT + ((size_t)h << 7) * 512;
    int s0 = ln << 3;
    float dt[4][8];
#pragma unroll
    for (int i = 0; i < 4; ++i)
#pragma unroll
        for (int j = 0; j < 8; ++j) dt[i][j] = 0.0f;

    for (int dc = 0; dc < 4; ++dc) {
        float ch[4][8];
#pragma unroll
        for (int i = 0; i < 4; ++i)
#pragma unroll
            for (int j = 0; j < 8; ++j) ch[i][j] = 0.0f;
#pragma unroll 4
        for (int d = dc * 32; d < dc * 32 + 32; ++d) {
            float4 c0 = ld4(ct + (size_t)d * 512 + s0);
            float4 c1 = ld4(ct + (size_t)d * 512 + s0 + 4);
#pragma unroll
            for (int i = 0; i < 4; ++i) {
                float kd = sK[wv][i][d];
                ch[i][0] += kd * c0.x; ch[i][1] += kd * c0.y; ch[i][2] += kd * c0.z; ch[i][3] += kd * c0.w;
                ch[i][4] += kd * c1.x; ch[i][5] += kd * c1.y; ch[i][6] += kd * c1.z; ch[i][7] += kd * c1.w;
            }
        }
#pragma unroll
        for (int i = 0; i < 4; ++i)
#pragma unroll
            for (int j = 0; j < 8; ++j) dt[i][j] += ch[i][j];
    }
    const float* cnh = cn + (h << 9);
#pragma unroll
    for (int i = 0; i < 4; ++i) {
        float bestv = cnh[s0] - 2.0f * dt[i][0];
        int bestz = s0;
#pragma unroll
        for (int j = 1; j < 8; ++j) {
            float scv = cnh[s0 + j] - 2.0f * dt[i][j];
            if (scv < bestv) { bestv = scv; bestz = s0 + j; }
        }
#pragma unroll
        for (int m = 32; m > 0; m >>= 1) {
            float ov = __shfl_xor(bestv, m);
            int   oz = __shfl_xor(bestz, m);
            if (ov < bestv || (ov == bestv && oz < bestz)) { bestv = ov; bestz = oz; }
        }
        float2 cz = *(const float2*)(cb + ((size_t)(h << 9) + bestz) * 128 + (ln << 1));
        size_t dst = (size_t)bh * 131072 + (size_t)(512 + l4 + i) * 128 + (ln << 1);
        us2 hh, ll;
        unsigned short h0 = bf16_rne(cz.x);
        hh[0] = h0; ll[0] = bf16_rne(cz.x - bf16_tof(h0));
        unsigned short h1 = bf16_rne(cz.y);
        hh[1] = h1; ll[1] = bf16_rne(cz.y - bf16_tof(h1));
        *(us2*)(Khi + dst) = hh;
        *(us2*)(Klo + dst) = ll;
    }
}

// ======== fused LN(128) + q offsets + hi/lo emission ========
__global__ __launch_bounds__(256) void ln_split_q_kernel(const float* __restrict__ qb,
        const float* __restrict__ xu, const float* __restrict__ xv,
        ushort_t* __restrict__ quh, ushort_t* __restrict__ qul,
        ushort_t* __restrict__ qvh) {
    int wv = threadIdx.x >> 6, ln = threadIdx.x & 63;
    int row = (blockIdx.x << 2) + wv;
    float2 x = *(const float2*)(qb + (size_t)row * 128 + (ln << 1));
    float s  = x.x + x.y;
    float ss = x.x*x.x + x.y*x.y;
#pragma unroll
    for (int m = 32; m > 0; m >>= 1) { s += __shfl_xor(s, m); ss += __shfl_xor(ss, m); }
    float mu  = s * (1.0f/128.0f);
    float var = ss * (1.0f/128.0f) - mu*mu;
    float r = rsqrtf(var + 1e-6f);
    x.x = (x.x - mu) * r; x.y = (x.y - mu) * r;
    int h = (row >> 9) & 7, d = ln << 1;
    float a0 = x.x + xu[(h << 7) + d];
    float a1 = x.y + xu[(h << 7) + d + 1];
    float b0 = x.x + xv[(h << 7) + d];
    float b1 = x.y + xv[(h << 7) + d + 1];
    size_t off = (size_t)row * 128 + d;
    us2 h2, l2, v2;
    unsigned short ah0 = bf16_rne(a0);
    h2[0] = ah0; l2[0] = bf16_rne(a0 - bf16_tof(ah0));
    unsigned short ah1 = bf16_rne(a1);
    h2[1] = ah1; l2[1] = bf16_rne(a1 - bf16_tof(ah1));
    v2[0] = bf16_rne(b0); v2[1] = bf16_rne(b1);
    *(us2*)(quh + off) = h2;
    *(us2*)(qul + off) = l2;
    *(us2*)(qvh + off) = v2;
}

// ======== remaining prep kernels ========
__global__ __launch_bounds__(256) void split_plain_kernel(const float* __restrict__ src,
        ushort_t* __restrict__ hi, ushort_t* __restrict__ lo) {
    int idx = blockIdx.x * 256 + threadIdx.x;
    float x = src[idx];
    unsigned short h = bf16_rne(x);
    hi[idx] = h; lo[idx] = bf16_rne(x - bf16_tof(h));
}

__global__ __launch_bounds__(256) void cvt_hi_kernel(const float* __restrict__ src,
        ushort_t* __restrict__ hi) {
    int idx = blockIdx.x * 256 + threadIdx.x;
    hi[idx] = bf16_rne(src[idx]);
}

__global__ __launch_bounds__(256) void split_koff_kernel(const float* __restrict__ src,
        ushort_t* __restrict__ hi, ushort_t* __restrict__ lo, int rowoff) {
    int idx = blockIdx.x * 256 + threadIdx.x;
    int bh = idx >> 16, rem = idx & 65535;
    size_t dst = ((size_t)bh << 17) + ((size_t)rowoff << 7) + rem;
    float x = src[idx];
    unsigned short h = bf16_rne(x);
    hi[dst] = h; lo[dst] = bf16_rne(x - bf16_tof(h));
}

__global__ __launch_bounds__(256) void vtsplit_kernel(const float* __restrict__ srcA,
        const float* __restrict__ srcB, ushort_t* __restrict__ hi, ushort_t* __restrict__ lo, int NK) {
    __shared__ float T[64][132];
    int bh = blockIdx.x, kt = blockIdx.y, t = threadIdx.x;
    for (int i = t; i < 2048; i += 256) {
        int r = i >> 5, c4 = (i & 31) << 2;
        int key = (kt << 6) + r;
        const float* s = (key < 512) ? (srcA + ((size_t)bh * 512 + key) * 128 + c4)
                                     : (srcB + ((size_t)bh * 512 + (key - 512)) * 128 + c4);
        *(float4*)&T[r][c4] = ld4(s);
    }
    __syncthreads();
    for (int i = t; i < 1024; i += 256) {
        int vc = i >> 3, kk = (i & 7) << 3;
        us8 h8, l8;
#pragma unroll
        for (int j = 0; j < 8; ++j) {
            float x = T[kk + j][vc];
            unsigned short hh = bf16_rne(x);
            h8[j] = hh; l8[j] = bf16_rne(x - bf16_tof(hh));
        }
        size_t off = ((size_t)bh * 128 + vc) * NK + (kt << 6) + kk;
        *(us8*)(hi + off) = h8;
        *(us8*)(lo + off) = l8;
    }
}

__global__ __launch_bounds__(256) void cbias_kernel(const float* __restrict__ al, float* __restrict__ cb) {
    int idx = blockIdx.x * 256 + threadIdx.x;
    float v = al[idx];
    cb[idx] = (v > 0.0f) ? __logf(fmaxf(v, 1e-30f)) : -INF30;
}

// ======== attn10: shuffle-free online softmax; epilogue emits Awh/Awl ========
#define PSTR 40
__global__ __launch_bounds__(256, 2) void attn10_kernel(
        const ushort_t* __restrict__ Qu_hi, const ushort_t* __restrict__ Qu_lo,
        const ushort_t* __restrict__ Qv_hi,
        const ushort_t* __restrict__ K_hi,  const ushort_t* __restrict__ K_lo,
        const ushort_t* __restrict__ C_hi,  const ushort_t* __restrict__ C_lo,
        const ushort_t* __restrict__ Vt_hi, const ushort_t* __restrict__ Vt_lo,
        const ushort_t* __restrict__ At_hi, const ushort_t* __restrict__ At_lo,
        const ushort_t* __restrict__ R_hi,
        const float* __restrict__ cbias, const float* __restrict__ gbuf,
        ushort_t* __restrict__ Awh, ushort_t* __restrict__ Awl) {
    __shared__ __align__(16) ushort_t KS[2][2][32 * 128];
    __shared__ __align__(16) ushort_t VS[2][2][128 * 32];
    __shared__ __align__(16) ushort_t Phs[4][16 * PSTR];
    __shared__ __align__(16) ushort_t Pls[4][16 * PSTR];

    int t = threadIdx.x;
    int wvid = t >> 6, ln = t & 63;
    int col = ln & 15, quad = ln >> 4;
    int blk = blockIdx.x;
    int xcd = blk & 7, idx = blk >> 3;
    int bh = ((idx >> 3) << 3) + xcd;
    int j = idx & 7;
    int jt = ((wvid & 1) ? (15 - j) : j) + ((wvid & 2) ? 16 : 0);
    int l0 = jt << 4;
    int h = bh & 7, b = bh >> 3;

    int nt2own = (l0 + 47) >> 5;
    int nt2max = (((31 - j) << 4) + 47) >> 5;
    int Tt = 32 + nt2max;

    size_t qb = ((size_t)bh * 512 + l0 + col) * 128 + quad * 8;
    bf16x8 quh[4], qul[4], qvf[4];
#pragma unroll
    for (int s = 0; s < 4; ++s) {
        quh[s] = ldb8(Qu_hi + qb + 32 * s);
        qul[s] = ldb8(Qu_lo + qb + 32 * s);
        qvf[s] = ldb8(Qv_hi + qb + 32 * s);
    }
    bf16x8 onesv;
#pragma unroll
    for (int i = 0; i < 8; ++i) onesv[i] = (short)0x3F80;

    f32x4 O[8];
#pragma unroll
    for (int u = 0; u < 8; ++u) O[u] = (f32x4){0.f, 0.f, 0.f, 0.f};
    f32x4 Oe = (f32x4){0.f, 0.f, 0.f, 0.f};
    float mrun[4];
#pragma unroll
    for (int r = 0; r < 4; ++r) mrun[r] = -INF30;

    ushort_t* Ph = Phs[wvid];
    ushort_t* Pl = Pls[wvid];

    {
        const ushort_t* nkh = K_hi + ((size_t)bh * 1024) * 128;
        const ushort_t* nkl = K_lo + ((size_t)bh * 1024) * 128;
#pragma unroll
        for (int m = 0; m < 2; ++m) {
            int r = wvid * 8 + m * 4 + (ln >> 4);
            int c = ln & 15;
            us8 vh8 = *(const us8*)(nkh + (size_t)r * 128 + c * 8);
            us8 vl8 = *(const us8*)(nkl + (size_t)r * 128 + c * 8);
            int dst = r * 128 + ((c ^ (r & 7)) << 3);
            *(us8*)&KS[0][0][dst] = vh8;
            *(us8*)&KS[0][1][dst] = vl8;
        }
        const ushort_t* vhp = Vt_hi + ((size_t)bh << 17);
        const ushort_t* vlp = Vt_lo + ((size_t)bh << 17);
#pragma unroll
        for (int m = 0; m < 2; ++m) {
            int dV = wvid * 128 + m * 64 + ln;
            int v = dV >> 2, c = dV & 3;
            us8 vh8 = *(const us8*)(vhp + (size_t)v * 1024 + c * 8);
            us8 vl8 = *(const us8*)(vlp + (size_t)v * 1024 + c * 8);
            int dst = v * 32 + ((c ^ ((v >> 1) & 3)) << 3);
            *(us8*)&VS[0][0][dst] = vh8;
            *(us8*)&VS[0][1][dst] = vl8;
        }
    }
    bf16x8 rg[3][4];
    {
        int jt0 = 496 - l0;
#pragma unroll
        for (int u = 0; u < 3; ++u) {
            int jr = jt0 + 16 * u + col;
            jr = (jr > 1023) ? 1023 : jr;
            const ushort_t* rp = R_hi + ((size_t)(h << 10) + jr) * 128 + quad * 8;
#pragma unroll
            for (int s = 0; s < 4; ++s) rg[u][s] = ldb8(rp + 32 * s);
        }
    }
    __syncthreads();
    int cur = 0;

    for (int ti = 0; ti < Tt; ++ti) {
        int seg, w0;
        if (ti < 16)      { seg = 0; w0 = ti << 5; }
        else if (ti < 32) { seg = 1; w0 = (ti - 16) << 5; }
        else              { seg = 2; w0 = (ti - 32) << 5; }
        bool act = (seg != 2) || ((ti - 32) < nt2own);

        int tn = ti + 1;
        bool hasNext = tn < Tt;
        int seg_n = 0, w0_n = 0;
        if (tn < 16)      { seg_n = 0; w0_n = tn << 5; }
        else if (tn < 32) { seg_n = 1; w0_n = (tn - 16) << 5; }
        else              { seg_n = 2; w0_n = (tn - 32) << 5; }
        bool act_n = hasNext && ((seg_n != 2) || ((tn - 32) < nt2own));

        us8 krh[2], krl[2], vrh[2], vrl[2];
        if (hasNext) {
            const ushort_t *nkh, *nkl;
            if (seg_n == 0)      { nkh = K_hi + ((size_t)bh * 1024 + w0_n) * 128;
                                   nkl = K_lo + ((size_t)bh * 1024 + w0_n) * 128; }
            else if (seg_n == 1) { nkh = C_hi + ((size_t)(h << 9) + w0_n) * 128;
                                   nkl = C_lo + ((size_t)(h << 9) + w0_n) * 128; }
            else                 { nkh = K_hi + ((size_t)bh * 1024 + 512 + w0_n) * 128;
                                   nkl = K_lo + ((size_t)bh * 1024 + 512 + w0_n) * 128; }
#pragma unroll
            for (int m = 0; m < 2; ++m) {
                int r = wvid * 8 + m * 4 + (ln >> 4);
                int c = ln & 15;
                krh[m] = *(const us8*)(nkh + (size_t)r * 128 + c * 8);
                krl[m] = *(const us8*)(nkl + (size_t)r * 128 + c * 8);
            }
            const ushort_t *vhp, *vlp; size_t vstr; int wbase;
            if (seg_n == 0)      { vhp = Vt_hi + ((size_t)bh << 17); vlp = Vt_lo + ((size_t)bh << 17); vstr = 1024; wbase = w0_n; }
            else if (seg_n == 1) { vhp = At_hi + ((size_t)bh << 16); vlp = At_lo + ((size_t)bh << 16); vstr = 512;  wbase = w0_n; }
            else                 { vhp = Vt_hi + ((size_t)bh << 17); vlp = Vt_lo + ((size_t)bh << 17); vstr = 1024; wbase = 512 + w0_n; }
#pragma unroll
            for (int m = 0; m < 2; ++m) {
                int dV = wvid * 128 + m * 64 + ln;
                int v = dV >> 2, c = dV & 3;
                vrh[m] = *(const us8*)(vhp + (size_t)v * vstr + wbase + c * 8);
                vrl[m] = *(const us8*)(vlp + (size_t)v * vstr + wbase + c * 8);
            }
        }

        f32x4 Gacc[3];
        f32x4 S[2];
        if (act && seg != 1) {
#pragma unroll
            for (int u = 0; u < 3; ++u) {
                f32x4 acc = (f32x4){0.f, 0.f, 0.f, 0.f};
                acc = MFMA16(qvf[0], rg[u][0], acc);
                acc = MFMA16(qvf[1], rg[u][1], acc);
                acc = MFMA16(qvf[2], rg[u][2], acc);
                acc = MFMA16(qvf[3], rg[u][3], acc);
                Gacc[u] = acc;
            }
        }

        if (act_n && seg_n != 1) {
            int jt0n = ((seg_n == 0) ? w0_n : (512 + w0_n)) + 496 - l0;
#pragma unroll
            for (int u = 0; u < 3; ++u) {
                int jr = jt0n + 16 * u + col;
                jr = (jr > 1023) ? 1023 : jr;
                const ushort_t* rp = R_hi + ((size_t)(h << 10) + jr) * 128 + quad * 8;
#pragma unroll
                for (int s = 0; s < 4; ++s) rg[u][s] = ldb8(rp + 32 * s);
            }
        }

        if (act) {
            S[0] = (f32x4){0.f, 0.f, 0.f, 0.f};
            S[1] = (f32x4){0.f, 0.f, 0.f, 0.f};
            const ushort_t* KH = KS[cur][0];
            const ushort_t* KL = KS[cur][1];
            int swz = col & 7;
            __builtin_amdgcn_s_setprio(1);
#pragma unroll
            for (int s = 0; s < 4; ++s) {
                int cofs = ((quad + 4 * s) ^ swz) << 3;
                bf16x8 k0h = *(const bf16x8*)&KH[col * 128 + cofs];
                bf16x8 k0l = *(const bf16x8*)&KL[col * 128 + cofs];
                bf16x8 k1h = *(const bf16x8*)&KH[(16 + col) * 128 + cofs];
                bf16x8 k1l = *(const bf16x8*)&KL[(16 + col) * 128 + cofs];
                S[0] = MFMA16(quh[s], k0h, S[0]);
                S[0] = MFMA16(qul[s], k0h, S[0]);
                S[0] = MFMA16(quh[s], k0l, S[0]);
                S[1] = MFMA16(quh[s], k1h, S[1]);
                S[1] = MFMA16(qul[s], k1h, S[1]);
                S[1] = MFMA16(quh[s], k1l, S[1]);
            }
            __builtin_amdgcn_s_setprio(0);
        }

        bf16x8 pah = {}, pal = {};
        if (act) {
            float bias0 = 0.f, bias1 = 0.f;
            if (seg == 1) {
                bias0 = cbias[(size_t)(bh << 9) + w0 + col];
                bias1 = cbias[(size_t)(bh << 9) + w0 + 16 + col];
            }
#pragma unroll
            for (int t2 = 0; t2 < 2; ++t2) {
#pragma unroll
                for (int r = 0; r < 4; ++r) {
                    int row = 4 * quad + r;
                    float sv = S[t2][r];
                    if (seg != 1) {
                        int d = col + 15 - row;
                        int src = quad * 16 + (d & 15);
                        float g0 = __shfl(Gacc[t2][r], src);
                        float g1 = __shfl(Gacc[t2 + 1][r], src);
                        float gv = (d >= 16) ? g1 : g0;
                        sv = (sv + gv) * INV_TAU;
                        if (seg == 2 && (w0 + 16 * t2 + col > l0 + row)) sv = -INF30;
                    } else {
                        sv = sv * INV_TAU + ((t2 == 0) ? bias0 : bias1);
                    }
                    S[t2][r] = sv;
                }
            }
            float mx[4];
            float need = -INF30;
#pragma unroll
            for (int r = 0; r < 4; ++r) {
                mx[r] = fmaxf(S[0][r], S[1][r]);
                need = fmaxf(need, mx[r] - mrun[r]);
            }
            if (__any(need > 8.0f)) {
#pragma unroll
                for (int r = 0; r < 4; ++r) {
                    float mv = mx[r];
#pragma unroll
                    for (int m = 8; m > 0; m >>= 1) mv = fmaxf(mv, __shfl_xor(mv, m));
                    float mnew = fmaxf(mrun[r], mv);
                    float alpha = __expf(mrun[r] - mnew);
                    mrun[r] = mnew;
                    Oe[r] *= alpha;
#pragma unroll
                    for (int u = 0; u < 8; ++u) O[u][r] *= alpha;
                }
            }
#pragma unroll
            for (int r = 0; r < 4; ++r) {
                float p0 = __expf(S[0][r] - mrun[r]);
                float p1 = __expf(S[1][r] - mrun[r]);
                int row = 4 * quad + r;
                unsigned short h0 = bf16_rne(p0);
                Ph[row * PSTR + col] = h0;
                Pl[row * PSTR + col] = bf16_rne(p0 - bf16_tof(h0));
                unsigned short h1 = bf16_rne(p1);
                Ph[row * PSTR + 16 + col] = h1;
                Pl[row * PSTR + 16 + col] = bf16_rne(p1 - bf16_tof(h1));
            }
            pah = *(const bf16x8*)&Ph[col * PSTR + quad * 8];
            pal = *(const bf16x8*)&Pl[col * PSTR + quad * 8];
        }

        if (act) {
            const ushort_t* VH = VS[cur][0];
            const ushort_t* VL = VS[cur][1];
            int vswz = (quad ^ ((col >> 1) & 3)) << 3;
            __builtin_amdgcn_s_setprio(1);
#pragma unroll
            for (int u = 0; u < 8; ++u) {
                int vrow = 16 * u + col;
                bf16x8 vbh = *(const bf16x8*)&VH[vrow * 32 + vswz];
                bf16x8 vbl = *(const bf16x8*)&VL[vrow * 32 + vswz];
                O[u] = MFMA16(pah, vbh, O[u]);
                O[u] = MFMA16(pal, vbh, O[u]);
                O[u] = MFMA16(pah, vbl, O[u]);
            }
            Oe = MFMA16(pah, onesv, Oe);
            Oe = MFMA16(pal, onesv, Oe);
            __builtin_amdgcn_s_setprio(0);
        }

        if (hasNext) {
#pragma unroll
            for (int m = 0; m < 2; ++m) {
                int r = wvid * 8 + m * 4 + (ln >> 4);
                int c = ln & 15;
                int dst = r * 128 + ((c ^ (r & 7)) << 3);
                *(us8*)&KS[cur ^ 1][0][dst] = krh[m];
                *(us8*)&KS[cur ^ 1][1][dst] = krl[m];
            }
#pragma unroll
            for (int m = 0; m < 2; ++m) {
                int dV = wvid * 128 + m * 64 + ln;
                int v = dV >> 2, c = dV & 3;
                int dst = v * 32 + ((c ^ ((v >> 1) & 3)) << 3);
                *(us8*)&VS[cur ^ 1][0][dst] = vrh[m];
                *(us8*)&VS[cur ^ 1][1][dst] = vrl[m];
            }
        }

        __syncthreads();
        cur ^= 1;
    }

#pragma unroll
    for (int r = 0; r < 4; ++r) {
        int row = quad * 4 + r;
        float linv = 1.0f / Oe[r];
#pragma unroll
        for (int u = 0; u < 8; ++u) {
            size_t gi = ((size_t)b * 512 + l0 + row) * 1024 + (h << 7) + 16 * u + col;
            float val = O[u][r] * linv * gbuf[gi];
            unsigned short hv = bf16_rne(val);
            Awh[gi] = hv;
            Awl[gi] = bf16_rne(val - bf16_tof(hv));
        }
    }
}

extern "C" void kernel_launch(void* const* d_in, const int* in_sizes, int n_in,
                              void* d_out, int out_size, void* d_ws, size_t ws_size,
                              hipStream_t stream) {
    const float* x_in  = (const float*)d_in[0];
    const float* xl_k  = (const float*)d_in[2];
    const float* xl_v  = (const float*)d_in[3];
    const float* agg_u = (const float*)d_in[4];
    const float* agg_l = (const float*)d_in[5];
    const float* W_q   = (const float*)d_in[6];
    const float* W_kvg = (const float*)d_in[7];
    const float* W_res = (const float*)d_in[8];
    const float* x_u   = (const float*)d_in[9];
    const float* x_v   = (const float*)d_in[10];
    const float* xl_r  = (const float*)d_in[11];
    const float* cbk   = (const float*)d_in[12];
    float* out = (float*)d_out;
    char* wb = (char*)d_ws;

    float*  x_t   = (float*)(wb);                       // 16 MB [alias: K_hi]
    float*  qbuf  = (float*)(wb + 16777216ul);          // 16 MB [alias: Vt_lo]
    float*  kbuf  = (float*)(wb + 33554432ul);          // 16 MB [alias: Vt_hi]
    float*  vbuf  = (float*)(wb + 50331648ul);          // 16 MB [alias: At_hi+At_lo]
    float*  gbuf  = (float*)(wb + 67108864ul);          // 16 MB
    float*  wvg   = (float*)(wb + 83886080ul);          // 16 MB [Ah+Al pre-attn; Awh+Awl post]
    float*  cT    = (float*)(wb + 100663296ul);         // 2 MB  [alias: C_hi+C_lo]
    float*  cnm   = (float*)(wb + 102760448ul);         // 16 KB
    ushort_t* Qu_hi = (ushort_t*)(wb + 102776832ul);    // 8 MB  [alias: Wtq pre-split]
    ushort_t* Qu_lo = (ushort_t*)(wb + 111165440ul);    // 8 MB  [alias: Wtvg pre-split]
    ushort_t* Qv_hi = (ushort_t*)(wb + 119554048ul);    // 8 MB  [alias: Wtres post-attn]
    ushort_t* K_lo  = (ushort_t*)(wb + 136331264ul);    // 16 MB
    ushort_t* R_hi  = (ushort_t*)(wb + 153108480ul);    // 2 MB
    float*  cbias   = (float*)(wb + 157302784ul);       // 128 KB

    ushort_t* K_hi  = (ushort_t*)x_t;
    ushort_t* Vt_hi = (ushort_t*)kbuf;
    ushort_t* Vt_lo = (ushort_t*)qbuf;
    ushort_t* At_hi = (ushort_t*)vbuf;
    ushort_t* At_lo = (ushort_t*)(wb + 50331648ul + 8388608ul);
    ushort_t* C_hi  = (ushort_t*)cT;
    ushort_t* C_lo  = (ushort_t*)(wb + 100663296ul + 1048576ul);

    ushort_t* Ah      = (ushort_t*)wvg;
    ushort_t* Al      = (ushort_t*)(wb + 83886080ul + 8388608ul);
    ushort_t* Awh     = (ushort_t*)wvg;
    ushort_t* Awl     = (ushort_t*)(wb + 83886080ul + 8388608ul);
    ushort_t* Wtq_hi  = (ushort_t*)Qu_hi;
    ushort_t* Wtq_lo  = (ushort_t*)(wb + 102776832ul + 2097152ul);
    ushort_t* Wtvg_hi = (ushort_t*)Qu_lo;
    ushort_t* Wtvg_lo = (ushort_t*)(wb + 111165440ul + 4194304ul);
    ushort_t* Wtres_hi = (ushort_t*)Qv_hi;
    ushort_t* Wtres_lo = (ushort_t*)(wb + 119554048ul + 2097152ul);

    // 1) input LN with fused bf16 split
    ln_dm_kernel<<<4096, 256, 0, stream>>>(x_in, x_t, Ah, Al);
    // 2) weight splits
    wtsplit_kernel<<<dim3(16, 16), 256, 0, stream>>>(W_q, 1024, 0, Wtq_hi, Wtq_lo);
    wtsplit_kernel<<<dim3(32, 16), 256, 0, stream>>>(W_kvg, 3072, 1024, Wtvg_hi, Wtvg_lo);
    // 3) projections
    gemm_bf16_kernel<<<dim3(8, 32), 256, 0, stream>>>(Ah, Al, Wtq_hi, Wtq_lo, 0, qbuf, nullptr);
    gemm_bf16_kernel<<<dim3(16, 32), 256, 0, stream>>>(Ah, Al, Wtvg_hi, Wtvg_lo, 1, vbuf, gbuf);
    gemm_kernel<<<dim3(8, 32), 256, 0, stream>>>(x_t, W_kvg, 3072, 0, kbuf, nullptr, nullptr);
    // 4) codebook prep + VQ (LN(k) fused, K split emitted in place)
    cbtn_kernel<<<1024, 256, 0, stream>>>(cbk, cT, cnm);
    vq_kernel<<<2048, 256, 0, stream>>>(kbuf, cT, cnm, cbk, K_hi, K_lo);
    // 5) attention preps
    ln_split_q_kernel<<<8192, 256, 0, stream>>>(qbuf, x_u, x_v, Qu_hi, Qu_lo, Qv_hi);
    split_koff_kernel<<<16384, 256, 0, stream>>>(xl_k, K_hi, K_lo, 0);
    split_plain_kernel<<<2048, 256, 0, stream>>>(cbk, C_hi, C_lo);
    cvt_hi_kernel<<<4096, 256, 0, stream>>>(xl_r, R_hi);
    vtsplit_kernel<<<dim3(64, 16), 256, 0, stream>>>(xl_v, vbuf, Vt_hi, Vt_lo, 1024);
    vtsplit_kernel<<<dim3(64, 8), 256, 0, stream>>>(agg_u, agg_u, At_hi, At_lo, 512);
    cbias_kernel<<<128, 256, 0, stream>>>(agg_l, cbias);
    // 6) fused attention (epilogue emits Awh/Awl for the output GEMM)
    attn10_kernel<<<512, 256, 0, stream>>>(Qu_hi, Qu_lo, Qv_hi, K_hi, K_lo, C_hi, C_lo,
                                           Vt_hi, Vt_lo, At_hi, At_lo, R_hi,
                                           cbias, gbuf, Awh, Awl);
    // 7) output projection
    wtsplit_kernel<<<dim3(16, 16), 256, 0, stream>>>(W_res, 1024, 0, Wtres_hi, Wtres_lo);
    gemm_bf16_kernel<<<dim3(8, 32), 256, 0, stream>>>(Awh, Awl, Wtres_hi, Wtres_lo, 2, out, nullptr);
}

// Round 9
// 713.490 us; speedup vs baseline: 1.8530x; 1.0479x over previous
//
#include <hip/hip_runtime.h>

#define INF30 1e30f
#define INV_TAU 0.08838834764831845f

typedef unsigned short ushort_t;
typedef __attribute__((ext_vector_type(8))) short bf16x8;
typedef __attribute__((ext_vector_type(4))) float f32x4;
typedef __attribute__((ext_vector_type(8))) unsigned short us8;
typedef __attribute__((ext_vector_type(4))) unsigned short us4;
typedef __attribute__((ext_vector_type(2))) unsigned short us2;

__device__ __forceinline__ float4 ld4(const float* p) { return *(const float4*)p; }

__device__ __forceinline__ unsigned short bf16_rne(float x) {
    unsigned int u = __float_as_uint(x);
    unsigned int r = u + 0x7fffu + ((u >> 16) & 1u);
    return (unsigned short)(r >> 16);
}
__device__ __forceinline__ float bf16_tof(unsigned short h) {
    return __uint_as_float(((unsigned int)h) << 16);
}
__device__ __forceinline__ bf16x8 ldb8(const ushort_t* p) { return *(const bf16x8*)p; }

#define MFMA16(a, b, c) __builtin_amdgcn_mfma_f32_16x16x32_bf16((a), (b), (c), 0, 0, 0)

// ======== LayerNorm over DM=1024 with fused bf16 hi/lo emission ========
__global__ __launch_bounds__(256) void ln_dm_kernel(const float* __restrict__ x, float* __restrict__ y,
                                                    ushort_t* __restrict__ Ah, ushort_t* __restrict__ Al) {
    size_t row = blockIdx.x;
    const float4* xr = (const float4*)(x + row * 1024);
    float4 v = xr[threadIdx.x];
    float s  = v.x + v.y + v.z + v.w;
    float ss = v.x*v.x + v.y*v.y + v.z*v.z + v.w*v.w;
#pragma unroll
    for (int off = 32; off > 0; off >>= 1) {
        s  += __shfl_down(s, off);
        ss += __shfl_down(ss, off);
    }
    __shared__ float rs[4], rss[4];
    int wv = threadIdx.x >> 6, ln = threadIdx.x & 63;
    if (ln == 0) { rs[wv] = s; rss[wv] = ss; }
    __syncthreads();
    s  = rs[0] + rs[1] + rs[2] + rs[3];
    ss = rss[0] + rss[1] + rss[2] + rss[3];
    float mu  = s * (1.0f/1024.0f);
    float var = ss * (1.0f/1024.0f) - mu*mu;
    float r = rsqrtf(var + 1e-6f);
    float4 o;
    o.x = (v.x - mu) * r; o.y = (v.y - mu) * r; o.z = (v.z - mu) * r; o.w = (v.w - mu) * r;
    ((float4*)(y + row * 1024))[threadIdx.x] = o;
    float ov[4] = {o.x, o.y, o.z, o.w};
    us4 h4, l4v;
#pragma unroll
    for (int j = 0; j < 4; ++j) {
        unsigned short hh = bf16_rne(ov[j]);
        h4[j] = hh; l4v[j] = bf16_rne(ov[j] - bf16_tof(hh));
    }
    size_t off = row * 1024 + threadIdx.x * 4;
    *(us4*)(Ah + off) = h4;
    *(us4*)(Al + off) = l4v;
}

// ======== fp32 GEMM, 128x64 tile, 8x4 per thread (k projection, argmin path) ========
// Tile shrunk from 128x128 (256 blocks = 1/CU = 1 wave/SIMD, barrier stalls exposed) to
// 128x64 -> 512 blocks = 2/CU. Same kt/kk/FMA order per output element -> bit-identical.
__global__ __launch_bounds__(256) void gemm_kernel(const float* __restrict__ A, const float* __restrict__ W,
                                                   int N, int mode,
                                                   float* __restrict__ o0, float* __restrict__ o1,
                                                   float* __restrict__ o2) {
    __shared__ float As[16][128];
    __shared__ float Bs[16][64];
    int t = threadIdx.x;
    int col0 = blockIdx.x << 6;
    int row0 = blockIdx.y << 7;
    int tx = t & 15, ty = t >> 4;
    int arow = t >> 1, akq = (t & 1) * 8;
    int bkr = t >> 4, bcq = (t & 15) * 4;
    const float* Ap = A + (size_t)(row0 + arow) * 1024 + akq;
    const float* Wp = W + (size_t)bkr * N + col0 + bcq;
    float acc[8][4];
#pragma unroll
    for (int i = 0; i < 8; ++i)
#pragma unroll
        for (int j = 0; j < 4; ++j) acc[i][j] = 0.0f;

    float4 a0 = ld4(Ap), a1 = ld4(Ap + 4);
    float4 b0 = ld4(Wp);

    for (int kt = 0; kt < 64; ++kt) {
        __syncthreads();
        As[akq+0][arow] = a0.x; As[akq+1][arow] = a0.y;
        As[akq+2][arow] = a0.z; As[akq+3][arow] = a0.w;
        As[akq+4][arow] = a1.x; As[akq+5][arow] = a1.y;
        As[akq+6][arow] = a1.z; As[akq+7][arow] = a1.w;
        *(float4*)&Bs[bkr][bcq] = b0;
        __syncthreads();
        if (kt < 63) {
            a0 = ld4(Ap + (kt + 1) * 16);
            a1 = ld4(Ap + (kt + 1) * 16 + 4);
            b0 = ld4(Wp + (size_t)(kt + 1) * 16 * N);
        }
#pragma unroll
        for (int kk = 0; kk < 16; ++kk) {
            float4 av0 = *(float4*)&As[kk][ty * 4];
            float4 av1 = *(float4*)&As[kk][64 + ty * 4];
            float4 bv0 = *(float4*)&Bs[kk][tx * 4];
            float a8[8] = {av0.x, av0.y, av0.z, av0.w, av1.x, av1.y, av1.z, av1.w};
            float b4[4] = {bv0.x, bv0.y, bv0.z, bv0.w};
#pragma unroll
            for (int i = 0; i < 8; ++i)
#pragma unroll
                for (int j = 0; j < 4; ++j) acc[i][j] += a8[i] * b4[j];
        }
    }

#pragma unroll
    for (int i = 0; i < 8; ++i) {
        int rr = row0 + ((i < 4) ? (ty * 4 + i) : (64 + ty * 4 + i - 4));
        int b = rr >> 9, l = rr & 511;
#pragma unroll
        for (int j = 0; j < 4; ++j) {
            int cc = col0 + tx * 4 + j;
            float vv = acc[i][j];
            if (mode == 0) {
                o0[((size_t)((b<<3) + (cc>>7)) * 512 + l) * 128 + (cc & 127)] = vv;
            } else if (mode == 1) {
                if (cc < 1024) o0[((size_t)((b<<3) + (cc>>7)) * 512 + l) * 128 + (cc & 127)] = vv;
                else o1[(size_t)rr * 1024 + (cc - 1024)] = vv / (1.0f + __expf(-vv));
            } else {
                o0[(size_t)rr * 1024 + cc] = vv;
            }
        }
    }
}

// ======== weight transpose + bf16 hi/lo split (single) ========
__global__ __launch_bounds__(256) void wtsplit_kernel(const float* __restrict__ W, int Ntot, int c0,
                                                      ushort_t* __restrict__ th, ushort_t* __restrict__ tl) {
    __shared__ float T[64][68];
    int n0 = blockIdx.x << 6, k0 = blockIdx.y << 6, t = threadIdx.x;
    for (int i = t; i < 1024; i += 256) {
        int kk = i >> 4, nn4 = (i & 15) << 2;
        *(float4*)&T[kk][nn4] = ld4(W + (size_t)(k0 + kk) * Ntot + c0 + n0 + nn4);
    }
    __syncthreads();
    for (int i = t; i < 512; i += 256) {
        int nn = i >> 3, kc = (i & 7) << 3;
        us8 h8, l8;
#pragma unroll
        for (int j = 0; j < 8; ++j) {
            float x = T[kc + j][nn];
            unsigned short hh = bf16_rne(x);
            h8[j] = hh; l8[j] = bf16_rne(x - bf16_tof(hh));
        }
        size_t off = (size_t)(n0 + nn) * 1024 + k0 + kc;
        *(us8*)(th + off) = h8;
        *(us8*)(tl + off) = l8;
    }
}

// ======== dual weight split: W_q (bx<16) and W_kvg (bx>=16) in one launch ========
__global__ __launch_bounds__(256) void wtsplit_dual_kernel(const float* __restrict__ Wq, const float* __restrict__ Wkvg,
                                                           ushort_t* __restrict__ qh, ushort_t* __restrict__ ql,
                                                           ushort_t* __restrict__ vh, ushort_t* __restrict__ vl) {
    __shared__ float T[64][68];
    int bx = blockIdx.x, t = threadIdx.x;
    const float* W; int Ntot, c0, n0; ushort_t *th, *tl;
    if (bx < 16) { W = Wq;   Ntot = 1024; c0 = 0;    n0 = bx << 6;        th = qh; tl = ql; }
    else         { W = Wkvg; Ntot = 3072; c0 = 1024; n0 = (bx - 16) << 6; th = vh; tl = vl; }
    int k0 = blockIdx.y << 6;
    for (int i = t; i < 1024; i += 256) {
        int kk = i >> 4, nn4 = (i & 15) << 2;
        *(float4*)&T[kk][nn4] = ld4(W + (size_t)(k0 + kk) * Ntot + c0 + n0 + nn4);
    }
    __syncthreads();
    for (int i = t; i < 512; i += 256) {
        int nn = i >> 3, kc = (i & 7) << 3;
        us8 h8, l8;
#pragma unroll
        for (int j = 0; j < 8; ++j) {
            float x = T[kc + j][nn];
            unsigned short hh = bf16_rne(x);
            h8[j] = hh; l8[j] = bf16_rne(x - bf16_tof(hh));
        }
        size_t off = (size_t)(n0 + nn) * 1024 + k0 + kc;
        *(us8*)(th + off) = h8;
        *(us8*)(tl + off) = l8;
    }
}

// ======== bf16 3-term split GEMM, 128x64 tile (was 128x128) ========
// Grid doubles -> 2-4 blocks/CU (LDS 30 KB). 4 waves = 2x2 over 64x32 quadrants.
// K-chunk order and 3-term MFMA order per output unchanged -> bit-identical.
#define GSTRIDE 40
__global__ __launch_bounds__(256) void gemm_bf16_kernel(
        const ushort_t* __restrict__ Ah, const ushort_t* __restrict__ Al,
        const ushort_t* __restrict__ Bth, const ushort_t* __restrict__ Btl,
        int mode, float* __restrict__ o0, float* __restrict__ o1) {
    __shared__ ushort_t LA[2][128 * GSTRIDE];
    __shared__ ushort_t LB[2][64 * GSTRIDE];
    int t = threadIdx.x;
    int col0 = blockIdx.x << 6, row0 = blockIdx.y << 7;
    int wvid = t >> 6, ln = t & 63;
    int lcol = ln & 15, quad = ln >> 4;
    int qm = wvid >> 1, qn = wvid & 1;

    f32x4 C[4][2];
#pragma unroll
    for (int i = 0; i < 4; ++i)
#pragma unroll
        for (int j = 0; j < 2; ++j) C[i][j] = (f32x4){0.f, 0.f, 0.f, 0.f};

    for (int k0 = 0; k0 < 1024; k0 += 32) {
        us8 ra[2][2], rb[2];
#pragma unroll
        for (int v = 0; v < 2; ++v) {
            int cid = t + 256 * v;
            int row = cid >> 2, ch = cid & 3;
            size_t ga = (size_t)(row0 + row) * 1024 + k0 + ch * 8;
            ra[v][0] = *(const us8*)(Ah + ga);
            ra[v][1] = *(const us8*)(Al + ga);
        }
        {
            int row = t >> 2, ch = t & 3;
            size_t gb = (size_t)(col0 + row) * 1024 + k0 + ch * 8;
            rb[0] = *(const us8*)(Bth + gb);
            rb[1] = *(const us8*)(Btl + gb);
        }
        __syncthreads();
#pragma unroll
        for (int v = 0; v < 2; ++v) {
            int cid = t + 256 * v;
            int row = cid >> 2, ch = cid & 3;
            *(us8*)&LA[0][row * GSTRIDE + ch * 8] = ra[v][0];
            *(us8*)&LA[1][row * GSTRIDE + ch * 8] = ra[v][1];
        }
        {
            int row = t >> 2, ch = t & 3;
            *(us8*)&LB[0][row * GSTRIDE + ch * 8] = rb[0];
            *(us8*)&LB[1][row * GSTRIDE + ch * 8] = rb[1];
        }
        __syncthreads();
        bf16x8 afh[4], afl[4], bfh[2], bfl[2];
#pragma unroll
        for (int i = 0; i < 4; ++i) {
            int r = qm * 64 + i * 16 + lcol;
            afh[i] = *(const bf16x8*)&LA[0][r * GSTRIDE + quad * 8];
            afl[i] = *(const bf16x8*)&LA[1][r * GSTRIDE + quad * 8];
        }
#pragma unroll
        for (int j = 0; j < 2; ++j) {
            int c = qn * 32 + j * 16 + lcol;
            bfh[j] = *(const bf16x8*)&LB[0][c * GSTRIDE + quad * 8];
            bfl[j] = *(const bf16x8*)&LB[1][c * GSTRIDE + quad * 8];
        }
#pragma unroll
        for (int i = 0; i < 4; ++i)
#pragma unroll
            for (int j = 0; j < 2; ++j) {
                C[i][j] = MFMA16(afh[i], bfh[j], C[i][j]);
                C[i][j] = MFMA16(afl[i], bfh[j], C[i][j]);
                C[i][j] = MFMA16(afh[i], bfl[j], C[i][j]);
            }
    }

#pragma unroll
    for (int i = 0; i < 4; ++i) {
#pragma unroll
        for (int r = 0; r < 4; ++r) {
            int rr = row0 + qm * 64 + 16 * i + quad * 4 + r;
            int b = rr >> 9, l = rr & 511;
#pragma unroll
            for (int j = 0; j < 2; ++j) {
                int cc = col0 + qn * 32 + 16 * j + lcol;
                float vv = C[i][j][r];
                if (mode == 0) {
                    o0[((size_t)((b<<3) + (cc>>7)) * 512 + l) * 128 + (cc & 127)] = vv;
                } else if (mode == 1) {
                    if (cc < 1024) o0[((size_t)((b<<3) + (cc>>7)) * 512 + l) * 128 + (cc & 127)] = vv;
                    else o1[(size_t)rr * 1024 + (cc - 1024)] = vv / (1.0f + __expf(-vv));
                } else {
                    o0[(size_t)rr * 1024 + cc] = vv;
                }
            }
        }
    }
}

// ======== codebook transpose + norms, single pass ========
__global__ __launch_bounds__(256) void cbtn_kernel(const float* __restrict__ cb, float* __restrict__ cT,
                                                   float* __restrict__ cn) {
    int wv = threadIdx.x >> 6, ln = threadIdx.x & 63;
    int row = (blockIdx.x << 2) + wv;
    float2 x = *(const float2*)(cb + (size_t)row * 128 + (ln << 1));
    float ss = x.x*x.x + x.y*x.y;
#pragma unroll
    for (int m = 32; m > 0; m >>= 1) ss += __shfl_xor(ss, m);
    if (ln == 0) cn[row] = ss;
    int h = row >> 9, s = row & 511, d = ln << 1;
    cT[((size_t)((h << 7) + d)) * 512 + s] = x.x;
    cT[((size_t)((h << 7) + d + 1)) * 512 + s] = x.y;
}

// ======== VQ argmin, fused LN(k) in-register, direct K hi/lo emission rows 512+ ========
__global__ __launch_bounds__(256) void vq_kernel(const float* __restrict__ kb, const float* __restrict__ cT,
                                                 const float* __restrict__ cn, const float* __restrict__ cb,
                                                 ushort_t* __restrict__ Khi, ushort_t* __restrict__ Klo) {
    __shared__ float sK[4][4][128];
    int wv = threadIdx.x >> 6, ln = threadIdx.x & 63;
    int gw = (blockIdx.x << 2) + wv;
    int bh = gw >> 7;
    int l4 = (gw & 127) << 2;
    int h = bh & 7;
    size_t r0 = ((size_t)bh << 9) + l4;
    float2 kreg[4];
#pragma unroll
    for (int i = 0; i < 4; ++i)
        kreg[i] = *(const float2*)(kb + (r0 + i) * 128 + (ln << 1));
#pragma unroll
    for (int i = 0; i < 4; ++i) {
        float s  = kreg[i].x + kreg[i].y;
        float ss = kreg[i].x*kreg[i].x + kreg[i].y*kreg[i].y;
#pragma unroll
        for (int m = 32; m > 0; m >>= 1) { s += __shfl_xor(s, m); ss += __shfl_xor(ss, m); }
        float mu  = s * (1.0f/128.0f);
        float var = ss * (1.0f/128.0f) - mu*mu;
        float rr = rsqrtf(var + 1e-6f);
        kreg[i].x = (kreg[i].x - mu) * rr;
        kreg[i].y = (kreg[i].y - mu) * rr;
        sK[wv][i][(ln<<1)]   = kreg[i].x;
        sK[wv][i][(ln<<1)+1] = kreg[i].y;
    }
    __syncthreads();
    const float* ct = cT + ((size_t)h << 7) * 512;
    int s0 = ln << 3;
    float dt[4][8];
#pragma unroll
    for (int i = 0; i < 4; ++i)
#pragma unroll
        for (int j = 0; j < 8; ++j) dt[i][j] = 0.0f;

    for (int dc = 0; dc < 4; ++dc) {
        float ch[4][8];
#pragma unroll
        for (int i = 0; i < 4; ++i)
#pragma unroll
            for (int j = 0; j < 8; ++j) ch[i][j] = 0.0f;
#pragma unroll 4
        for (int d = dc * 32; d < dc * 32 + 32; ++d) {
            float4 c0 = ld4(ct + (size_t)d * 512 + s0);
            float4 c1 = ld4(ct + (size_t)d * 512 + s0 + 4);
#pragma unroll
            for (int i = 0; i < 4; ++i) {
                float kd = sK[wv][i][d];
                ch[i][0] += kd * c0.x; ch[i][1] += kd * c0.y; ch[i][2] += kd * c0.z; ch[i][3] += kd * c0.w;
                ch[i][4] += kd * c1.x; ch[i][5] += kd * c1.y; ch[i][6] += kd * c1.z; ch[i][7] += kd * c1.w;
            }
        }
#pragma unroll
        for (int i = 0; i < 4; ++i)
#pragma unroll
            for (int j = 0; j < 8; ++j) dt[i][j] += ch[i][j];
    }
    const float* cnh = cn + (h << 9);
#pragma unroll
    for (int i = 0; i < 4; ++i) {
        float bestv = cnh[s0] - 2.0f * dt[i][0];
        int bestz = s0;
#pragma unroll
        for (int j = 1; j < 8; ++j) {
            float scv = cnh[s0 + j] - 2.0f * dt[i][j];
            if (scv < bestv) { bestv = scv; bestz = s0 + j; }
        }
#pragma unroll
        for (int m = 32; m > 0; m >>= 1) {
            float ov = __shfl_xor(bestv, m);
            int   oz = __shfl_xor(bestz, m);
            if (ov < bestv || (ov == bestv && oz < bestz)) { bestv = ov; bestz = oz; }
        }
        float2 cz = *(const float2*)(cb + ((size_t)(h << 9) + bestz) * 128 + (ln << 1));
        size_t dst = (size_t)bh * 131072 + (size_t)(512 + l4 + i) * 128 + (ln << 1);
        us2 hh, ll;
        unsigned short h0 = bf16_rne(cz.x);
        hh[0] = h0; ll[0] = bf16_rne(cz.x - bf16_tof(h0));
        unsigned short h1 = bf16_rne(cz.y);
        hh[1] = h1; ll[1] = bf16_rne(cz.y - bf16_tof(h1));
        *(us2*)(Khi + dst) = hh;
        *(us2*)(Klo + dst) = ll;
    }
}

// ======== fused LN(128) + q offsets + hi/lo emission ========
__global__ __launch_bounds__(256) void ln_split_q_kernel(const float* __restrict__ qb,
        const float* __restrict__ xu, const float* __restrict__ xv,
        ushort_t* __restrict__ quh, ushort_t* __restrict__ qul,
        ushort_t* __restrict__ qvh) {
    int wv = threadIdx.x >> 6, ln = threadIdx.x & 63;
    int row = (blockIdx.x << 2) + wv;
    float2 x = *(const float2*)(qb + (size_t)row * 128 + (ln << 1));
    float s  = x.x + x.y;
    float ss = x.x*x.x + x.y*x.y;
#pragma unroll
    for (int m = 32; m > 0; m >>= 1) { s += __shfl_xor(s, m); ss += __shfl_xor(ss, m); }
    float mu  = s * (1.0f/128.0f);
    float var = ss * (1.0f/128.0f) - mu*mu;
    float r = rsqrtf(var + 1e-6f);
    x.x = (x.x - mu) * r; x.y = (x.y - mu) * r;
    int h = (row >> 9) & 7, d = ln << 1;
    float a0 = x.x + xu[(h << 7) + d];
    float a1 = x.y + xu[(h << 7) + d + 1];
    float b0 = x.x + xv[(h << 7) + d];
    float b1 = x.y + xv[(h << 7) + d + 1];
    size_t off = (size_t)row * 128 + d;
    us2 h2, l2, v2;
    unsigned short ah0 = bf16_rne(a0);
    h2[0] = ah0; l2[0] = bf16_rne(a0 - bf16_tof(ah0));
    unsigned short ah1 = bf16_rne(a1);
    h2[1] = ah1; l2[1] = bf16_rne(a1 - bf16_tof(ah1));
    v2[0] = bf16_rne(b0); v2[1] = bf16_rne(b1);
    *(us2*)(quh + off) = h2;
    *(us2*)(qul + off) = l2;
    *(us2*)(qvh + off) = v2;
}

// ======== vtsplit (unchanged) ========
__global__ __launch_bounds__(256) void vtsplit_kernel(const float* __restrict__ srcA,
        const float* __restrict__ srcB, ushort_t* __restrict__ hi, ushort_t* __restrict__ lo, int NK) {
    __shared__ float T[64][132];
    int bh = blockIdx.x, kt = blockIdx.y, t = threadIdx.x;
    for (int i = t; i < 2048; i += 256) {
        int r = i >> 5, c4 = (i & 31) << 2;
        int key = (kt << 6) + r;
        const float* s = (key < 512) ? (srcA + ((size_t)bh * 512 + key) * 128 + c4)
                                     : (srcB + ((size_t)bh * 512 + (key - 512)) * 128 + c4);
        *(float4*)&T[r][c4] = ld4(s);
    }
    __syncthreads();
    for (int i = t; i < 1024; i += 256) {
        int vc = i >> 3, kk = (i & 7) << 3;
        us8 h8, l8;
#pragma unroll
        for (int j = 0; j < 8; ++j) {
            float x = T[kk + j][vc];
            unsigned short hh = bf16_rne(x);
            h8[j] = hh; l8[j] = bf16_rne(x - bf16_tof(hh));
        }
        size_t off = ((size_t)bh * 128 + vc) * NK + (kt << 6) + kk;
        *(us8*)(hi + off) = h8;
        *(us8*)(lo + off) = l8;
    }
}

// ======== merged misc preps: xl_k K-split / cbk C-split / xl_r cvt / agg_l bias ========
// role by block range: [0,16384) koff; [16384,18432) csplit; [18432,22528) rcvt; [22528,22656) cbias
__global__ __launch_bounds__(256) void prep_misc_kernel(
        const float* __restrict__ xl_k, ushort_t* __restrict__ Khi, ushort_t* __restrict__ Klo,
        const float* __restrict__ cbk,  ushort_t* __restrict__ Chi, ushort_t* __restrict__ Clo,
        const float* __restrict__ xl_r, ushort_t* __restrict__ Rhi,
        const float* __restrict__ agg_l, float* __restrict__ cbias) {
    int blk = blockIdx.x, t = threadIdx.x;
    if (blk < 16384) {
        int idx = blk * 256 + t;
        int bh = idx >> 16, rem = idx & 65535;
        size_t dst = ((size_t)bh << 17) + rem;   // rowoff = 0
        float x = xl_k[idx];
        unsigned short h = bf16_rne(x);
        Khi[dst] = h; Klo[dst] = bf16_rne(x - bf16_tof(h));
    } else if (blk < 18432) {
        int idx = (blk - 16384) * 256 + t;
        float x = cbk[idx];
        unsigned short h = bf16_rne(x);
        Chi[idx] = h; Clo[idx] = bf16_rne(x - bf16_tof(h));
    } else if (blk < 22528) {
        int idx = (blk - 18432) * 256 + t;
        Rhi[idx] = bf16_rne(xl_r[idx]);
    } else {
        int idx = (blk - 22528) * 256 + t;
        float v = agg_l[idx];
        cbias[idx] = (v > 0.0f) ? __logf(fmaxf(v, 1e-30f)) : -INF30;
    }
}

// ======== attn10: shuffle-free online softmax; epilogue emits Awh/Awl (unchanged) ========
#define PSTR 40
__global__ __launch_bounds__(256, 2) void attn10_kernel(
        const ushort_t* __restrict__ Qu_hi, const ushort_t* __restrict__ Qu_lo,
        const ushort_t* __restrict__ Qv_hi,
        const ushort_t* __restrict__ K_hi,  const ushort_t* __restrict__ K_lo,
        const ushort_t* __restrict__ C_hi,  const ushort_t* __restrict__ C_lo,
        const ushort_t* __restrict__ Vt_hi, const ushort_t* __restrict__ Vt_lo,
        const ushort_t* __restrict__ At_hi, const ushort_t* __restrict__ At_lo,
        const ushort_t* __restrict__ R_hi,
        const float* __restrict__ cbias, const float* __restrict__ gbuf,
        ushort_t* __restrict__ Awh, ushort_t* __restrict__ Awl) {
    __shared__ __align__(16) ushort_t KS[2][2][32 * 128];
    __shared__ __align__(16) ushort_t VS[2][2][128 * 32];
    __shared__ __align__(16) ushort_t Phs[4][16 * PSTR];
    __shared__ __align__(16) ushort_t Pls[4][16 * PSTR];

    int t = threadIdx.x;
    int wvid = t >> 6, ln = t & 63;
    int col = ln & 15, quad = ln >> 4;
    int blk = blockIdx.x;
    int xcd = blk & 7, idx = blk >> 3;
    int bh = ((idx >> 3) << 3) + xcd;
    int j = idx & 7;
    int jt = ((wvid & 1) ? (15 - j) : j) + ((wvid & 2) ? 16 : 0);
    int l0 = jt << 4;
    int h = bh & 7, b = bh >> 3;

    int nt2own = (l0 + 47) >> 5;
    int nt2max = (((31 - j) << 4) + 47) >> 5;
    int Tt = 32 + nt2max;

    size_t qb = ((size_t)bh * 512 + l0 + col) * 128 + quad * 8;
    bf16x8 quh[4], qul[4], qvf[4];
#pragma unroll
    for (int s = 0; s < 4; ++s) {
        quh[s] = ldb8(Qu_hi + qb + 32 * s);
        qul[s] = ldb8(Qu_lo + qb + 32 * s);
        qvf[s] = ldb8(Qv_hi + qb + 32 * s);
    }
    bf16x8 onesv;
#pragma unroll
    for (int i = 0; i < 8; ++i) onesv[i] = (short)0x3F80;

    f32x4 O[8];
#pragma unroll
    for (int u = 0; u < 8; ++u) O[u] = (f32x4){0.f, 0.f, 0.f, 0.f};
    f32x4 Oe = (f32x4){0.f, 0.f, 0.f, 0.f};
    float mrun[4];
#pragma unroll
    for (int r = 0; r < 4; ++r) mrun[r] = -INF30;

    ushort_t* Ph = Phs[wvid];
    ushort_t* Pl = Pls[wvid];

    {
        const ushort_t* nkh = K_hi + ((size_t)bh * 1024) * 128;
        const ushort_t* nkl = K_lo + ((size_t)bh * 1024) * 128;
#pragma unroll
        for (int m = 0; m < 2; ++m) {
            int r = wvid * 8 + m * 4 + (ln >> 4);
            int c = ln & 15;
            us8 vh8 = *(const us8*)(nkh + (size_t)r * 128 + c * 8);
            us8 vl8 = *(const us8*)(nkl + (size_t)r * 128 + c * 8);
            int dst = r * 128 + ((c ^ (r & 7)) << 3);
            *(us8*)&KS[0][0][dst] = vh8;
            *(us8*)&KS[0][1][dst] = vl8;
        }
        const ushort_t* vhp = Vt_hi + ((size_t)bh << 17);
        const ushort_t* vlp = Vt_lo + ((size_t)bh << 17);
#pragma unroll
        for (int m = 0; m < 2; ++m) {
            int dV = wvid * 128 + m * 64 + ln;
            int v = dV >> 2, c = dV & 3;
            us8 vh8 = *(const us8*)(vhp + (size_t)v * 1024 + c * 8);
            us8 vl8 = *(const us8*)(vlp + (size_t)v * 1024 + c * 8);
            int dst = v * 32 + ((c ^ ((v >> 1) & 3)) << 3);
            *(us8*)&VS[0][0][dst] = vh8;
            *(us8*)&VS[0][1][dst] = vl8;
        }
    }
    bf16x8 rg[3][4];
    {
        int jt0 = 496 - l0;
#pragma unroll
        for (int u = 0; u < 3; ++u) {
            int jr = jt0 + 16 * u + col;
            jr = (jr > 1023) ? 1023 : jr;
            const ushort_t* rp = R_hi + ((size_t)(h << 10) + jr) * 128 + quad * 8;
#pragma unroll
            for (int s = 0; s < 4; ++s) rg[u][s] = ldb8(rp + 32 * s);
        }
    }
    __syncthreads();
    int cur = 0;

    for (int ti = 0; ti < Tt; ++ti) {
        int seg, w0;
        if (ti < 16)      { seg = 0; w0 = ti << 5; }
        else if (ti < 32) { seg = 1; w0 = (ti - 16) << 5; }
        else              { seg = 2; w0 = (ti - 32) << 5; }
        bool act = (seg != 2) || ((ti - 32) < nt2own);

        int tn = ti + 1;
        bool hasNext = tn < Tt;
        int seg_n = 0, w0_n = 0;
        if (tn < 16)      { seg_n = 0; w0_n = tn << 5; }
        else if (tn < 32) { seg_n = 1; w0_n = (tn - 16) << 5; }
        else              { seg_n = 2; w0_n = (tn - 32) << 5; }
        bool act_n = hasNext && ((seg_n != 2) || ((tn - 32) < nt2own));

        us8 krh[2], krl[2], vrh[2], vrl[2];
        if (hasNext) {
            const ushort_t *nkh, *nkl;
            if (seg_n == 0)      { nkh = K_hi + ((size_t)bh * 1024 + w0_n) * 128;
                                   nkl = K_lo + ((size_t)bh * 1024 + w0_n) * 128; }
            else if (seg_n == 1) { nkh = C_hi + ((size_t)(h << 9) + w0_n) * 128;
                                   nkl = C_lo + ((size_t)(h << 9) + w0_n) * 128; }
            else                 { nkh = K_hi + ((size_t)bh * 1024 + 512 + w0_n) * 128;
                                   nkl = K_lo + ((size_t)bh * 1024 + 512 + w0_n) * 128; }
#pragma unroll
            for (int m = 0; m < 2; ++m) {
                int r = wvid * 8 + m * 4 + (ln >> 4);
                int c = ln & 15;
                krh[m] = *(const us8*)(nkh + (size_t)r * 128 + c * 8);
                krl[m] = *(const us8*)(nkl + (size_t)r * 128 + c * 8);
            }
            const ushort_t *vhp, *vlp; size_t vstr; int wbase;
            if (seg_n == 0)      { vhp = Vt_hi + ((size_t)bh << 17); vlp = Vt_lo + ((size_t)bh << 17); vstr = 1024; wbase = w0_n; }
            else if (seg_n == 1) { vhp = At_hi + ((size_t)bh << 16); vlp = At_lo + ((size_t)bh << 16); vstr = 512;  wbase = w0_n; }
            else                 { vhp = Vt_hi + ((size_t)bh << 17); vlp = Vt_lo + ((size_t)bh << 17); vstr = 1024; wbase = 512 + w0_n; }
#pragma unroll
            for (int m = 0; m < 2; ++m) {
                int dV = wvid * 128 + m * 64 + ln;
                int v = dV >> 2, c = dV & 3;
                vrh[m] = *(const us8*)(vhp + (size_t)v * vstr + wbase + c * 8);
                vrl[m] = *(const us8*)(vlp + (size_t)v * vstr + wbase + c * 8);
            }
        }

        f32x4 Gacc[3];
        f32x4 S[2];
        if (act && seg != 1) {
#pragma unroll
            for (int u = 0; u < 3; ++u) {
                f32x4 acc = (f32x4){0.f, 0.f, 0.f, 0.f};
                acc = MFMA16(qvf[0], rg[u][0], acc);
                acc = MFMA16(qvf[1], rg[u][1], acc);
                acc = MFMA16(qvf[2], rg[u][2], acc);
                acc = MFMA16(qvf[3], rg[u][3], acc);
                Gacc[u] = acc;
            }
        }

        if (act_n && seg_n != 1) {
            int jt0n = ((seg_n == 0) ? w0_n : (512 + w0_n)) + 496 - l0;
#pragma unroll
            for (int u = 0; u < 3; ++u) {
                int jr = jt0n + 16 * u + col;
                jr = (jr > 1023) ? 1023 : jr;
                const ushort_t* rp = R_hi + ((size_t)(h << 10) + jr) * 128 + quad * 8;
#pragma unroll
                for (int s = 0; s < 4; ++s) rg[u][s] = ldb8(rp + 32 * s);
            }
        }

        if (act) {
            S[0] = (f32x4){0.f, 0.f, 0.f, 0.f};
            S[1] = (f32x4){0.f, 0.f, 0.f, 0.f};
            const ushort_t* KH = KS[cur][0];
            const ushort_t* KL = KS[cur][1];
            int swz = col & 7;
            __builtin_amdgcn_s_setprio(1);
#pragma unroll
            for (int s = 0; s < 4; ++s) {
                int cofs = ((quad + 4 * s) ^ swz) << 3;
                bf16x8 k0h = *(const bf16x8*)&KH[col * 128 + cofs];
                bf16x8 k0l = *(const bf16x8*)&KL[col * 128 + cofs];
                bf16x8 k1h = *(const bf16x8*)&KH[(16 + col) * 128 + cofs];
                bf16x8 k1l = *(const bf16x8*)&KL[(16 + col) * 128 + cofs];
                S[0] = MFMA16(quh[s], k0h, S[0]);
                S[0] = MFMA16(qul[s], k0h, S[0]);
                S[0] = MFMA16(quh[s], k0l, S[0]);
                S[1] = MFMA16(quh[s], k1h, S[1]);
                S[1] = MFMA16(qul[s], k1h, S[1]);
                S[1] = MFMA16(quh[s], k1l, S[1]);
            }
            __builtin_amdgcn_s_setprio(0);
        }

        bf16x8 pah = {}, pal = {};
        if (act) {
            float bias0 = 0.f, bias1 = 0.f;
            if (seg == 1) {
                bias0 = cbias[(size_t)(bh << 9) + w0 + col];
                bias1 = cbias[(size_t)(bh << 9) + w0 + 16 + col];
            }
#pragma unroll
            for (int t2 = 0; t2 < 2; ++t2) {
#pragma unroll
                for (int r = 0; r < 4; ++r) {
                    int row = 4 * quad + r;
                    float sv = S[t2][r];
                    if (seg != 1) {
                        int d = col + 15 - row;
                        int src = quad * 16 + (d & 15);
                        float g0 = __shfl(Gacc[t2][r], src);
                        float g1 = __shfl(Gacc[t2 + 1][r], src);
                        float gv = (d >= 16) ? g1 : g0;
                        sv = (sv + gv) * INV_TAU;
                        if (seg == 2 && (w0 + 16 * t2 + col > l0 + row)) sv = -INF30;
                    } else {
                        sv = sv * INV_TAU + ((t2 == 0) ? bias0 : bias1);
                    }
                    S[t2][r] = sv;
                }
            }
            float mx[4];
            float need = -INF30;
#pragma unroll
            for (int r = 0; r < 4; ++r) {
                mx[r] = fmaxf(S[0][r], S[1][r]);
                need = fmaxf(need, mx[r] - mrun[r]);
            }
            if (__any(need > 8.0f)) {
#pragma unroll
                for (int r = 0; r < 4; ++r) {
                    float mv = mx[r];
#pragma unroll
                    for (int m = 8; m > 0; m >>= 1) mv = fmaxf(mv, __shfl_xor(mv, m));
                    float mnew = fmaxf(mrun[r], mv);
                    float alpha = __expf(mrun[r] - mnew);
                    mrun[r] = mnew;
                    Oe[r] *= alpha;
#pragma unroll
                    for (int u = 0; u < 8; ++u) O[u][r] *= alpha;
                }
            }
#pragma unroll
            for (int r = 0; r < 4; ++r) {
                float p0 = __expf(S[0][r] - mrun[r]);
                float p1 = __expf(S[1][r] - mrun[r]);
                int row = 4 * quad + r;
                unsigned short h0 = bf16_rne(p0);
                Ph[row * PSTR + col] = h0;
                Pl[row * PSTR + col] = bf16_rne(p0 - bf16_tof(h0));
                unsigned short h1 = bf16_rne(p1);
                Ph[row * PSTR + 16 + col] = h1;
                Pl[row * PSTR + 16 + col] = bf16_rne(p1 - bf16_tof(h1));
            }
            pah = *(const bf16x8*)&Ph[col * PSTR + quad * 8];
            pal = *(const bf16x8*)&Pl[col * PSTR + quad * 8];
        }

        if (act) {
            const ushort_t* VH = VS[cur][0];
            const ushort_t* VL = VS[cur][1];
            int vswz = (quad ^ ((col >> 1) & 3)) << 3;
            __builtin_amdgcn_s_setprio(1);
#pragma unroll
            for (int u = 0; u < 8; ++u) {
                int vrow = 16 * u + col;
                bf16x8 vbh = *(const bf16x8*)&VH[vrow * 32 + vswz];
                bf16x8 vbl = *(const bf16x8*)&VL[vrow * 32 + vswz];
                O[u] = MFMA16(pah, vbh, O[u]);
                O[u] = MFMA16(pal, vbh, O[u]);
                O[u] = MFMA16(pah, vbl, O[u]);
            }
            Oe = MFMA16(pah, onesv, Oe);
            Oe = MFMA16(pal, onesv, Oe);
            __builtin_amdgcn_s_setprio(0);
        }

        if (hasNext) {
#pragma unroll
            for (int m = 0; m < 2; ++m) {
                int r = wvid * 8 + m * 4 + (ln >> 4);
                int c = ln & 15;
                int dst = r * 128 + ((c ^ (r & 7)) << 3);
                *(us8*)&KS[cur ^ 1][0][dst] = krh[m];
                *(us8*)&KS[cur ^ 1][1][dst] = krl[m];
            }
#pragma unroll
            for (int m = 0; m < 2; ++m) {
                int dV = wvid * 128 + m * 64 + ln;
                int v = dV >> 2, c = dV & 3;
                int dst = v * 32 + ((c ^ ((v >> 1) & 3)) << 3);
                *(us8*)&VS[cur ^ 1][0][dst] = vrh[m];
                *(us8*)&VS[cur ^ 1][1][dst] = vrl[m];
            }
        }

        __syncthreads();
        cur ^= 1;
    }

#pragma unroll
    for (int r = 0; r < 4; ++r) {
        int row = quad * 4 + r;
        float linv = 1.0f / Oe[r];
#pragma unroll
        for (int u = 0; u < 8; ++u) {
            size_t gi = ((size_t)b * 512 + l0 + row) * 1024 + (h << 7) + 16 * u + col;
            float val = O[u][r] * linv * gbuf[gi];
            unsigned short hv = bf16_rne(val);
            Awh[gi] = hv;
            Awl[gi] = bf16_rne(val - bf16_tof(hv));
        }
    }
}

extern "C" void kernel_launch(void* const* d_in, const int* in_sizes, int n_in,
                              void* d_out, int out_size, void* d_ws, size_t ws_size,
                              hipStream_t stream) {
    const float* x_in  = (const float*)d_in[0];
    const float* xl_k  = (const float*)d_in[2];
    const float* xl_v  = (const float*)d_in[3];
    const float* agg_u = (const float*)d_in[4];
    const float* agg_l = (const float*)d_in[5];
    const float* W_q   = (const float*)d_in[6];
    const float* W_kvg = (const float*)d_in[7];
    const float* W_res = (const float*)d_in[8];
    const float* x_u   = (const float*)d_in[9];
    const float* x_v   = (const float*)d_in[10];
    const float* xl_r  = (const float*)d_in[11];
    const float* cbk   = (const float*)d_in[12];
    float* out = (float*)d_out;
    char* wb = (char*)d_ws;

    float*  x_t   = (float*)(wb);                       // 16 MB [alias: K_hi]
    float*  qbuf  = (float*)(wb + 16777216ul);          // 16 MB [alias: Vt_lo]
    float*  kbuf  = (float*)(wb + 33554432ul);          // 16 MB [alias: Vt_hi]
    float*  vbuf  = (float*)(wb + 50331648ul);          // 16 MB [alias: At_hi+At_lo]
    float*  gbuf  = (float*)(wb + 67108864ul);          // 16 MB
    float*  wvg   = (float*)(wb + 83886080ul);          // 16 MB [Ah+Al pre-attn; Awh+Awl post]
    float*  cT    = (float*)(wb + 100663296ul);         // 2 MB  [alias: C_hi+C_lo]
    float*  cnm   = (float*)(wb + 102760448ul);         // 16 KB
    ushort_t* Qu_hi = (ushort_t*)(wb + 102776832ul);    // 8 MB  [alias: Wtq pre-split]
    ushort_t* Qu_lo = (ushort_t*)(wb + 111165440ul);    // 8 MB  [alias: Wtvg pre-split]
    ushort_t* Qv_hi = (ushort_t*)(wb + 119554048ul);    // 8 MB  [alias: Wtres post-attn]
    ushort_t* K_lo  = (ushort_t*)(wb + 136331264ul);    // 16 MB
    ushort_t* R_hi  = (ushort_t*)(wb + 153108480ul);    // 2 MB
    float*  cbias   = (float*)(wb + 157302784ul);       // 128 KB

    ushort_t* K_hi  = (ushort_t*)x_t;
    ushort_t* Vt_hi = (ushort_t*)kbuf;
    ushort_t* Vt_lo = (ushort_t*)qbuf;
    ushort_t* At_hi = (ushort_t*)vbuf;
    ushort_t* At_lo = (ushort_t*)(wb + 50331648ul + 8388608ul);
    ushort_t* C_hi  = (ushort_t*)cT;
    ushort_t* C_lo  = (ushort_t*)(wb + 100663296ul + 1048576ul);

    ushort_t* Ah      = (ushort_t*)wvg;
    ushort_t* Al      = (ushort_t*)(wb + 83886080ul + 8388608ul);
    ushort_t* Awh     = (ushort_t*)wvg;
    ushort_t* Awl     = (ushort_t*)(wb + 83886080ul + 8388608ul);
    ushort_t* Wtq_hi  = (ushort_t*)Qu_hi;
    ushort_t* Wtq_lo  = (ushort_t*)(wb + 102776832ul + 2097152ul);
    ushort_t* Wtvg_hi = (ushort_t*)Qu_lo;
    ushort_t* Wtvg_lo = (ushort_t*)(wb + 111165440ul + 4194304ul);
    ushort_t* Wtres_hi = (ushort_t*)Qv_hi;
    ushort_t* Wtres_lo = (ushort_t*)(wb + 119554048ul + 2097152ul);

    // 1) input LN with fused bf16 split
    ln_dm_kernel<<<4096, 256, 0, stream>>>(x_in, x_t, Ah, Al);
    // 2) merged weight splits (W_q + W_kvg)
    wtsplit_dual_kernel<<<dim3(48, 16), 256, 0, stream>>>(W_q, W_kvg, Wtq_hi, Wtq_lo, Wtvg_hi, Wtvg_lo);
    // 3) projections (128x64 tiles: 2-4 blocks/CU)
    gemm_bf16_kernel<<<dim3(16, 32), 256, 0, stream>>>(Ah, Al, Wtq_hi, Wtq_lo, 0, qbuf, nullptr);
    gemm_bf16_kernel<<<dim3(32, 32), 256, 0, stream>>>(Ah, Al, Wtvg_hi, Wtvg_lo, 1, vbuf, gbuf);
    gemm_kernel<<<dim3(16, 32), 256, 0, stream>>>(x_t, W_kvg, 3072, 0, kbuf, nullptr, nullptr);
    // 4) codebook prep + VQ (LN(k) fused, K split emitted in place)
    cbtn_kernel<<<1024, 256, 0, stream>>>(cbk, cT, cnm);
    vq_kernel<<<2048, 256, 0, stream>>>(kbuf, cT, cnm, cbk, K_hi, K_lo);
    // 5) attention preps
    ln_split_q_kernel<<<8192, 256, 0, stream>>>(qbuf, x_u, x_v, Qu_hi, Qu_lo, Qv_hi);
    vtsplit_kernel<<<dim3(64, 16), 256, 0, stream>>>(xl_v, vbuf, Vt_hi, Vt_lo, 1024);
    vtsplit_kernel<<<dim3(64, 8), 256, 0, stream>>>(agg_u, agg_u, At_hi, At_lo, 512);
    prep_misc_kernel<<<22656, 256, 0, stream>>>(xl_k, K_hi, K_lo, cbk, C_hi, C_lo,
                                                xl_r, R_hi, agg_l, cbias);
    // 6) fused attention (epilogue emits Awh/Awl for the output GEMM)
    attn10_kernel<<<512, 256, 0, stream>>>(Qu_hi, Qu_lo, Qv_hi, K_hi, K_lo, C_hi, C_lo,
                                           Vt_hi, Vt_lo, At_hi, At_lo, R_hi,
                                           cbias, gbuf, Awh, Awl);
    // 7) output projection
    wtsplit_kernel<<<dim3(16, 16), 256, 0, stream>>>(W_res, 1024, 0, Wtres_hi, Wtres_lo);
    gemm_bf16_kernel<<<dim3(16, 32), 256, 0, stream>>>(Awh, Awl, Wtres_hi, Wtres_lo, 2, out, nullptr);
}

// Round 10
// 712.858 us; speedup vs baseline: 1.8547x; 1.0009x over previous
//
#include <hip/hip_runtime.h>

#define INF30 1e30f
#define INV_TAU 0.08838834764831845f

typedef unsigned short ushort_t;
typedef __attribute__((ext_vector_type(8))) short bf16x8;
typedef __attribute__((ext_vector_type(4))) float f32x4;
typedef __attribute__((ext_vector_type(8))) unsigned short us8;
typedef __attribute__((ext_vector_type(4))) unsigned short us4;
typedef __attribute__((ext_vector_type(2))) unsigned short us2;

__device__ __forceinline__ float4 ld4(const float* p) { return *(const float4*)p; }

__device__ __forceinline__ unsigned short bf16_rne(float x) {
    unsigned int u = __float_as_uint(x);
    unsigned int r = u + 0x7fffu + ((u >> 16) & 1u);
    return (unsigned short)(r >> 16);
}
__device__ __forceinline__ float bf16_tof(unsigned short h) {
    return __uint_as_float(((unsigned int)h) << 16);
}
__device__ __forceinline__ bf16x8 ldb8(const ushort_t* p) { return *(const bf16x8*)p; }

#define MFMA16(a, b, c) __builtin_amdgcn_mfma_f32_16x16x32_bf16((a), (b), (c), 0, 0, 0)

// ======== LayerNorm over DM=1024 with fused bf16 hi/lo emission ========
__global__ __launch_bounds__(256) void ln_dm_kernel(const float* __restrict__ x, float* __restrict__ y,
                                                    ushort_t* __restrict__ Ah, ushort_t* __restrict__ Al) {
    size_t row = blockIdx.x;
    const float4* xr = (const float4*)(x + row * 1024);
    float4 v = xr[threadIdx.x];
    float s  = v.x + v.y + v.z + v.w;
    float ss = v.x*v.x + v.y*v.y + v.z*v.z + v.w*v.w;
#pragma unroll
    for (int off = 32; off > 0; off >>= 1) {
        s  += __shfl_down(s, off);
        ss += __shfl_down(ss, off);
    }
    __shared__ float rs[4], rss[4];
    int wv = threadIdx.x >> 6, ln = threadIdx.x & 63;
    if (ln == 0) { rs[wv] = s; rss[wv] = ss; }
    __syncthreads();
    s  = rs[0] + rs[1] + rs[2] + rs[3];
    ss = rss[0] + rss[1] + rss[2] + rss[3];
    float mu  = s * (1.0f/1024.0f);
    float var = ss * (1.0f/1024.0f) - mu*mu;
    float r = rsqrtf(var + 1e-6f);
    float4 o;
    o.x = (v.x - mu) * r; o.y = (v.y - mu) * r; o.z = (v.z - mu) * r; o.w = (v.w - mu) * r;
    ((float4*)(y + row * 1024))[threadIdx.x] = o;
    float ov[4] = {o.x, o.y, o.z, o.w};
    us4 h4, l4v;
#pragma unroll
    for (int j = 0; j < 4; ++j) {
        unsigned short hh = bf16_rne(ov[j]);
        h4[j] = hh; l4v[j] = bf16_rne(ov[j] - bf16_tof(hh));
    }
    size_t off = row * 1024 + threadIdx.x * 4;
    *(us4*)(Ah + off) = h4;
    *(us4*)(Al + off) = l4v;
}

// ======== fp32 GEMM, 128x64 tile, 8x4/thread, double-buffered single-barrier ========
// attn9 pipeline pattern: compute buf[cur], write next chunk to buf[cur^1], ONE barrier.
// Same kt/kk/FMA order per output element -> bit-identical.
__global__ __launch_bounds__(256) void gemm_kernel(const float* __restrict__ A, const float* __restrict__ W,
                                                   int N, int mode,
                                                   float* __restrict__ o0, float* __restrict__ o1,
                                                   float* __restrict__ o2) {
    __shared__ float As[2][16][128];
    __shared__ float Bs[2][16][64];
    int t = threadIdx.x;
    int col0 = blockIdx.x << 6;
    int row0 = blockIdx.y << 7;
    int tx = t & 15, ty = t >> 4;
    int arow = t >> 1, akq = (t & 1) * 8;
    int bkr = t >> 4, bcq = (t & 15) * 4;
    const float* Ap = A + (size_t)(row0 + arow) * 1024 + akq;
    const float* Wp = W + (size_t)bkr * N + col0 + bcq;
    float acc[8][4];
#pragma unroll
    for (int i = 0; i < 8; ++i)
#pragma unroll
        for (int j = 0; j < 4; ++j) acc[i][j] = 0.0f;

    // prologue: stage kt=0 into buf 0
    {
        float4 a0 = ld4(Ap), a1 = ld4(Ap + 4);
        float4 b0 = ld4(Wp);
        As[0][akq+0][arow] = a0.x; As[0][akq+1][arow] = a0.y;
        As[0][akq+2][arow] = a0.z; As[0][akq+3][arow] = a0.w;
        As[0][akq+4][arow] = a1.x; As[0][akq+5][arow] = a1.y;
        As[0][akq+6][arow] = a1.z; As[0][akq+7][arow] = a1.w;
        *(float4*)&Bs[0][bkr][bcq] = b0;
    }
    __syncthreads();
    int cur = 0;

    for (int kt = 0; kt < 64; ++kt) {
        float4 a0n, a1n, b0n;
        if (kt < 63) {
            a0n = ld4(Ap + (kt + 1) * 16);
            a1n = ld4(Ap + (kt + 1) * 16 + 4);
            b0n = ld4(Wp + (size_t)(kt + 1) * 16 * N);
        }
#pragma unroll
        for (int kk = 0; kk < 16; ++kk) {
            float4 av0 = *(float4*)&As[cur][kk][ty * 4];
            float4 av1 = *(float4*)&As[cur][kk][64 + ty * 4];
            float4 bv0 = *(float4*)&Bs[cur][kk][tx * 4];
            float a8[8] = {av0.x, av0.y, av0.z, av0.w, av1.x, av1.y, av1.z, av1.w};
            float b4[4] = {bv0.x, bv0.y, bv0.z, bv0.w};
#pragma unroll
            for (int i = 0; i < 8; ++i)
#pragma unroll
                for (int j = 0; j < 4; ++j) acc[i][j] += a8[i] * b4[j];
        }
        if (kt < 63) {
            int nb = cur ^ 1;
            As[nb][akq+0][arow] = a0n.x; As[nb][akq+1][arow] = a0n.y;
            As[nb][akq+2][arow] = a0n.z; As[nb][akq+3][arow] = a0n.w;
            As[nb][akq+4][arow] = a1n.x; As[nb][akq+5][arow] = a1n.y;
            As[nb][akq+6][arow] = a1n.z; As[nb][akq+7][arow] = a1n.w;
            *(float4*)&Bs[nb][bkr][bcq] = b0n;
        }
        __syncthreads();
        cur ^= 1;
    }

#pragma unroll
    for (int i = 0; i < 8; ++i) {
        int rr = row0 + ((i < 4) ? (ty * 4 + i) : (64 + ty * 4 + i - 4));
        int b = rr >> 9, l = rr & 511;
#pragma unroll
        for (int j = 0; j < 4; ++j) {
            int cc = col0 + tx * 4 + j;
            float vv = acc[i][j];
            if (mode == 0) {
                o0[((size_t)((b<<3) + (cc>>7)) * 512 + l) * 128 + (cc & 127)] = vv;
            } else if (mode == 1) {
                if (cc < 1024) o0[((size_t)((b<<3) + (cc>>7)) * 512 + l) * 128 + (cc & 127)] = vv;
                else o1[(size_t)rr * 1024 + (cc - 1024)] = vv / (1.0f + __expf(-vv));
            } else {
                o0[(size_t)rr * 1024 + cc] = vv;
            }
        }
    }
}

// ======== weight transpose + bf16 hi/lo split (single) ========
__global__ __launch_bounds__(256) void wtsplit_kernel(const float* __restrict__ W, int Ntot, int c0,
                                                      ushort_t* __restrict__ th, ushort_t* __restrict__ tl) {
    __shared__ float T[64][68];
    int n0 = blockIdx.x << 6, k0 = blockIdx.y << 6, t = threadIdx.x;
    for (int i = t; i < 1024; i += 256) {
        int kk = i >> 4, nn4 = (i & 15) << 2;
        *(float4*)&T[kk][nn4] = ld4(W + (size_t)(k0 + kk) * Ntot + c0 + n0 + nn4);
    }
    __syncthreads();
    for (int i = t; i < 512; i += 256) {
        int nn = i >> 3, kc = (i & 7) << 3;
        us8 h8, l8;
#pragma unroll
        for (int j = 0; j < 8; ++j) {
            float x = T[kc + j][nn];
            unsigned short hh = bf16_rne(x);
            h8[j] = hh; l8[j] = bf16_rne(x - bf16_tof(hh));
        }
        size_t off = (size_t)(n0 + nn) * 1024 + k0 + kc;
        *(us8*)(th + off) = h8;
        *(us8*)(tl + off) = l8;
    }
}

// ======== dual weight split: W_q (bx<16) and W_kvg (bx>=16) in one launch ========
__global__ __launch_bounds__(256) void wtsplit_dual_kernel(const float* __restrict__ Wq, const float* __restrict__ Wkvg,
                                                           ushort_t* __restrict__ qh, ushort_t* __restrict__ ql,
                                                           ushort_t* __restrict__ vh, ushort_t* __restrict__ vl) {
    __shared__ float T[64][68];
    int bx = blockIdx.x, t = threadIdx.x;
    const float* W; int Ntot, c0, n0; ushort_t *th, *tl;
    if (bx < 16) { W = Wq;   Ntot = 1024; c0 = 0;    n0 = bx << 6;        th = qh; tl = ql; }
    else         { W = Wkvg; Ntot = 3072; c0 = 1024; n0 = (bx - 16) << 6; th = vh; tl = vl; }
    int k0 = blockIdx.y << 6;
    for (int i = t; i < 1024; i += 256) {
        int kk = i >> 4, nn4 = (i & 15) << 2;
        *(float4*)&T[kk][nn4] = ld4(W + (size_t)(k0 + kk) * Ntot + c0 + n0 + nn4);
    }
    __syncthreads();
    for (int i = t; i < 512; i += 256) {
        int nn = i >> 3, kc = (i & 7) << 3;
        us8 h8, l8;
#pragma unroll
        for (int j = 0; j < 8; ++j) {
            float x = T[kc + j][nn];
            unsigned short hh = bf16_rne(x);
            h8[j] = hh; l8[j] = bf16_rne(x - bf16_tof(hh));
        }
        size_t off = (size_t)(n0 + nn) * 1024 + k0 + kc;
        *(us8*)(th + off) = h8;
        *(us8*)(tl + off) = l8;
    }
}

// ======== bf16 3-term split GEMM, 128x64 tile, double-buffered single-barrier ========
// LDS 60 KB -> 2 blocks/CU. Per K-chunk: issue next-chunk loads, MFMA from buf[cur],
// ds_write buf[cur^1], ONE barrier (attn9 pattern). Accumulation order unchanged.
#define GSTRIDE 40
__global__ __launch_bounds__(256) void gemm_bf16_kernel(
        const ushort_t* __restrict__ Ah, const ushort_t* __restrict__ Al,
        const ushort_t* __restrict__ Bth, const ushort_t* __restrict__ Btl,
        int mode, float* __restrict__ o0, float* __restrict__ o1) {
    __shared__ ushort_t LA[2][2][128 * GSTRIDE];
    __shared__ ushort_t LB[2][2][64 * GSTRIDE];
    int t = threadIdx.x;
    int col0 = blockIdx.x << 6, row0 = blockIdx.y << 7;
    int wvid = t >> 6, ln = t & 63;
    int lcol = ln & 15, quad = ln >> 4;
    int qm = wvid >> 1, qn = wvid & 1;

    int arow = t >> 2, ach = t & 3;          // A staging: 128 rows x 4 chunks (x2 rounds)
    int brow = t >> 2, bch = t & 3;          // B staging: 64 rows x 4 chunks
    size_t gaBase = (size_t)(row0 + arow) * 1024 + ach * 8;
    size_t gbBase = (size_t)(col0 + brow) * 1024 + bch * 8;

    f32x4 C[4][2];
#pragma unroll
    for (int i = 0; i < 4; ++i)
#pragma unroll
        for (int j = 0; j < 2; ++j) C[i][j] = (f32x4){0.f, 0.f, 0.f, 0.f};

    // prologue: stage chunk 0 into buf 0
    {
#pragma unroll
        for (int v = 0; v < 2; ++v) {
            int cid = t + 256 * v;
            int row = cid >> 2, ch = cid & 3;
            size_t ga = (size_t)(row0 + row) * 1024 + ch * 8;
            us8 rh = *(const us8*)(Ah + ga);
            us8 rl = *(const us8*)(Al + ga);
            *(us8*)&LA[0][0][row * GSTRIDE + ch * 8] = rh;
            *(us8*)&LA[0][1][row * GSTRIDE + ch * 8] = rl;
        }
        us8 rh = *(const us8*)(Bth + gbBase);
        us8 rl = *(const us8*)(Btl + gbBase);
        *(us8*)&LB[0][0][brow * GSTRIDE + bch * 8] = rh;
        *(us8*)&LB[0][1][brow * GSTRIDE + bch * 8] = rl;
    }
    __syncthreads();
    int cur = 0;

    for (int kc = 0; kc < 32; ++kc) {
        int k0n = (kc + 1) << 5;
        us8 ra[2][2], rb[2];
        if (kc < 31) {
#pragma unroll
            for (int v = 0; v < 2; ++v) {
                int cid = t + 256 * v;
                int row = cid >> 2, ch = cid & 3;
                size_t ga = (size_t)(row0 + row) * 1024 + k0n + ch * 8;
                ra[v][0] = *(const us8*)(Ah + ga);
                ra[v][1] = *(const us8*)(Al + ga);
            }
            rb[0] = *(const us8*)(Bth + gbBase + k0n);
            rb[1] = *(const us8*)(Btl + gbBase + k0n);
        }

        bf16x8 afh[4], afl[4], bfh[2], bfl[2];
#pragma unroll
        for (int i = 0; i < 4; ++i) {
            int r = qm * 64 + i * 16 + lcol;
            afh[i] = *(const bf16x8*)&LA[cur][0][r * GSTRIDE + quad * 8];
            afl[i] = *(const bf16x8*)&LA[cur][1][r * GSTRIDE + quad * 8];
        }
#pragma unroll
        for (int j = 0; j < 2; ++j) {
            int c = qn * 32 + j * 16 + lcol;
            bfh[j] = *(const bf16x8*)&LB[cur][0][c * GSTRIDE + quad * 8];
            bfl[j] = *(const bf16x8*)&LB[cur][1][c * GSTRIDE + quad * 8];
        }
#pragma unroll
        for (int i = 0; i < 4; ++i)
#pragma unroll
            for (int j = 0; j < 2; ++j) {
                C[i][j] = MFMA16(afh[i], bfh[j], C[i][j]);
                C[i][j] = MFMA16(afl[i], bfh[j], C[i][j]);
                C[i][j] = MFMA16(afh[i], bfl[j], C[i][j]);
            }

        if (kc < 31) {
            int nb = cur ^ 1;
#pragma unroll
            for (int v = 0; v < 2; ++v) {
                int cid = t + 256 * v;
                int row = cid >> 2, ch = cid & 3;
                *(us8*)&LA[nb][0][row * GSTRIDE + ch * 8] = ra[v][0];
                *(us8*)&LA[nb][1][row * GSTRIDE + ch * 8] = ra[v][1];
            }
            *(us8*)&LB[nb][0][brow * GSTRIDE + bch * 8] = rb[0];
            *(us8*)&LB[nb][1][brow * GSTRIDE + bch * 8] = rb[1];
        }
        __syncthreads();
        cur ^= 1;
    }

#pragma unroll
    for (int i = 0; i < 4; ++i) {
#pragma unroll
        for (int r = 0; r < 4; ++r) {
            int rr = row0 + qm * 64 + 16 * i + quad * 4 + r;
            int b = rr >> 9, l = rr & 511;
#pragma unroll
            for (int j = 0; j < 2; ++j) {
                int cc = col0 + qn * 32 + 16 * j + lcol;
                float vv = C[i][j][r];
                if (mode == 0) {
                    o0[((size_t)((b<<3) + (cc>>7)) * 512 + l) * 128 + (cc & 127)] = vv;
                } else if (mode == 1) {
                    if (cc < 1024) o0[((size_t)((b<<3) + (cc>>7)) * 512 + l) * 128 + (cc & 127)] = vv;
                    else o1[(size_t)rr * 1024 + (cc - 1024)] = vv / (1.0f + __expf(-vv));
                } else {
                    o0[(size_t)rr * 1024 + cc] = vv;
                }
            }
        }
    }
}

// ======== codebook transpose + norms, single pass ========
__global__ __launch_bounds__(256) void cbtn_kernel(const float* __restrict__ cb, float* __restrict__ cT,
                                                   float* __restrict__ cn) {
    int wv = threadIdx.x >> 6, ln = threadIdx.x & 63;
    int row = (blockIdx.x << 2) + wv;
    float2 x = *(const float2*)(cb + (size_t)row * 128 + (ln << 1));
    float ss = x.x*x.x + x.y*x.y;
#pragma unroll
    for (int m = 32; m > 0; m >>= 1) ss += __shfl_xor(ss, m);
    if (ln == 0) cn[row] = ss;
    int h = row >> 9, s = row & 511, d = ln << 1;
    cT[((size_t)((h << 7) + d)) * 512 + s] = x.x;
    cT[((size_t)((h << 7) + d + 1)) * 512 + s] = x.y;
}

// ======== VQ argmin, fused LN(k) in-register, direct K hi/lo emission rows 512+ ========
__global__ __launch_bounds__(256) void vq_kernel(const float* __restrict__ kb, const float* __restrict__ cT,
                                                 const float* __restrict__ cn, const float* __restrict__ cb,
                                                 ushort_t* __restrict__ Khi, ushort_t* __restrict__ Klo) {
    __shared__ float sK[4][4][128];
    int wv = threadIdx.x >> 6, ln = threadIdx.x & 63;
    int gw = (blockIdx.x << 2) + wv;
    int bh = gw >> 7;
    int l4 = (gw & 127) << 2;
    int h = bh & 7;
    size_t r0 = ((size_t)bh << 9) + l4;
    float2 kreg[4];
#pragma unroll
    for (int i = 0; i < 4; ++i)
        kreg[i] = *(const float2*)(kb + (r0 + i) * 128 + (ln << 1));
#pragma unroll
    for (int i = 0; i < 4; ++i) {
        float s  = kreg[i].x + kreg[i].y;
        float ss = kreg[i].x*kreg[i].x + kreg[i].y*kreg[i].y;
#pragma unroll
        for (int m = 32; m > 0; m >>= 1) { s += __shfl_xor(s, m); ss += __shfl_xor(ss, m); }
        float mu  = s * (1.0f/128.0f);
        float var = ss * (1.0f/128.0f) - mu*mu;
        float rr = rsqrtf(var + 1e-6f);
        kreg[i].x = (kreg[i].x - mu) * rr;
        kreg[i].y = (kreg[i].y - mu) * rr;
        sK[wv][i][(ln<<1)]   = kreg[i].x;
        sK[wv][i][(ln<<1)+1] = kreg[i].y;
    }
    __syncthreads();
    const float* ct = cT + ((size_t)h << 7) * 512;
    int s0 = ln << 3;
    float dt[4][8];
#pragma unroll
    for (int i = 0; i < 4; ++i)
#pragma unroll
        for (int j = 0; j < 8; ++j) dt[i][j] = 0.0f;

    for (int dc = 0; dc < 4; ++dc) {
        float ch[4][8];
#pragma unroll
        for (int i = 0; i < 4; ++i)
#pragma unroll
            for (int j = 0; j < 8; ++j) ch[i][j] = 0.0f;
#pragma unroll 4
        for (int d = dc * 32; d < dc * 32 + 32; ++d) {
            float4 c0 = ld4(ct + (size_t)d * 512 + s0);
            float4 c1 = ld4(ct + (size_t)d * 512 + s0 + 4);
#pragma unroll
            for (int i = 0; i < 4; ++i) {
                float kd = sK[wv][i][d];
                ch[i][0] += kd * c0.x; ch[i][1] += kd * c0.y; ch[i][2] += kd * c0.z; ch[i][3] += kd * c0.w;
                ch[i][4] += kd * c1.x; ch[i][5] += kd * c1.y; ch[i][6] += kd * c1.z; ch[i][7] += kd * c1.w;
            }
        }
#pragma unroll
        for (int i = 0; i < 4; ++i)
#pragma unroll
            for (int j = 0; j < 8; ++j) dt[i][j] += ch[i][j];
    }
    const float* cnh = cn + (h << 9);
#pragma unroll
    for (int i = 0; i < 4; ++i) {
        float bestv = cnh[s0] - 2.0f * dt[i][0];
        int bestz = s0;
#pragma unroll
        for (int j = 1; j < 8; ++j) {
            float scv = cnh[s0 + j] - 2.0f * dt[i][j];
            if (scv < bestv) { bestv = scv; bestz = s0 + j; }
        }
#pragma unroll
        for (int m = 32; m > 0; m >>= 1) {
            float ov = __shfl_xor(bestv, m);
            int   oz = __shfl_xor(bestz, m);
            if (ov < bestv || (ov == bestv && oz < bestz)) { bestv = ov; bestz = oz; }
        }
        float2 cz = *(const float2*)(cb + ((size_t)(h << 9) + bestz) * 128 + (ln << 1));
        size_t dst = (size_t)bh * 131072 + (size_t)(512 + l4 + i) * 128 + (ln << 1);
        us2 hh, ll;
        unsigned short h0 = bf16_rne(cz.x);
        hh[0] = h0; ll[0] = bf16_rne(cz.x - bf16_tof(h0));
        unsigned short h1 = bf16_rne(cz.y);
        hh[1] = h1; ll[1] = bf16_rne(cz.y - bf16_tof(h1));
        *(us2*)(Khi + dst) = hh;
        *(us2*)(Klo + dst) = ll;
    }
}

// ======== fused LN(128) + q offsets + hi/lo emission ========
__global__ __launch_bounds__(256) void ln_split_q_kernel(const float* __restrict__ qb,
        const float* __restrict__ xu, const float* __restrict__ xv,
        ushort_t* __restrict__ quh, ushort_t* __restrict__ qul,
        ushort_t* __restrict__ qvh) {
    int wv = threadIdx.x >> 6, ln = threadIdx.x & 63;
    int row = (blockIdx.x << 2) + wv;
    float2 x = *(const float2*)(qb + (size_t)row * 128 + (ln << 1));
    float s  = x.x + x.y;
    float ss = x.x*x.x + x.y*x.y;
#pragma unroll
    for (int m = 32; m > 0; m >>= 1) { s += __shfl_xor(s, m); ss += __shfl_xor(ss, m); }
    float mu  = s * (1.0f/128.0f);
    float var = ss * (1.0f/128.0f) - mu*mu;
    float r = rsqrtf(var + 1e-6f);
    x.x = (x.x - mu) * r; x.y = (x.y - mu) * r;
    int h = (row >> 9) & 7, d = ln << 1;
    float a0 = x.x + xu[(h << 7) + d];
    float a1 = x.y + xu[(h << 7) + d + 1];
    float b0 = x.x + xv[(h << 7) + d];
    float b1 = x.y + xv[(h << 7) + d + 1];
    size_t off = (size_t)row * 128 + d;
    us2 h2, l2, v2;
    unsigned short ah0 = bf16_rne(a0);
    h2[0] = ah0; l2[0] = bf16_rne(a0 - bf16_tof(ah0));
    unsigned short ah1 = bf16_rne(a1);
    h2[1] = ah1; l2[1] = bf16_rne(a1 - bf16_tof(ah1));
    v2[0] = bf16_rne(b0); v2[1] = bf16_rne(b1);
    *(us2*)(quh + off) = h2;
    *(us2*)(qul + off) = l2;
    *(us2*)(qvh + off) = v2;
}

// ======== vtsplit (unchanged) ========
__global__ __launch_bounds__(256) void vtsplit_kernel(const float* __restrict__ srcA,
        const float* __restrict__ srcB, ushort_t* __restrict__ hi, ushort_t* __restrict__ lo, int NK) {
    __shared__ float T[64][132];
    int bh = blockIdx.x, kt = blockIdx.y, t = threadIdx.x;
    for (int i = t; i < 2048; i += 256) {
        int r = i >> 5, c4 = (i & 31) << 2;
        int key = (kt << 6) + r;
        const float* s = (key < 512) ? (srcA + ((size_t)bh * 512 + key) * 128 + c4)
                                     : (srcB + ((size_t)bh * 512 + (key - 512)) * 128 + c4);
        *(float4*)&T[r][c4] = ld4(s);
    }
    __syncthreads();
    for (int i = t; i < 1024; i += 256) {
        int vc = i >> 3, kk = (i & 7) << 3;
        us8 h8, l8;
#pragma unroll
        for (int j = 0; j < 8; ++j) {
            float x = T[kk + j][vc];
            unsigned short hh = bf16_rne(x);
            h8[j] = hh; l8[j] = bf16_rne(x - bf16_tof(hh));
        }
        size_t off = ((size_t)bh * 128 + vc) * NK + (kt << 6) + kk;
        *(us8*)(hi + off) = h8;
        *(us8*)(lo + off) = l8;
    }
}

// ======== merged misc preps: xl_k K-split / cbk C-split / xl_r cvt / agg_l bias ========
__global__ __launch_bounds__(256) void prep_misc_kernel(
        const float* __restrict__ xl_k, ushort_t* __restrict__ Khi, ushort_t* __restrict__ Klo,
        const float* __restrict__ cbk,  ushort_t* __restrict__ Chi, ushort_t* __restrict__ Clo,
        const float* __restrict__ xl_r, ushort_t* __restrict__ Rhi,
        const float* __restrict__ agg_l, float* __restrict__ cbias) {
    int blk = blockIdx.x, t = threadIdx.x;
    if (blk < 16384) {
        int idx = blk * 256 + t;
        int bh = idx >> 16, rem = idx & 65535;
        size_t dst = ((size_t)bh << 17) + rem;   // rowoff = 0
        float x = xl_k[idx];
        unsigned short h = bf16_rne(x);
        Khi[dst] = h; Klo[dst] = bf16_rne(x - bf16_tof(h));
    } else if (blk < 18432) {
        int idx = (blk - 16384) * 256 + t;
        float x = cbk[idx];
        unsigned short h = bf16_rne(x);
        Chi[idx] = h; Clo[idx] = bf16_rne(x - bf16_tof(h));
    } else if (blk < 22528) {
        int idx = (blk - 18432) * 256 + t;
        Rhi[idx] = bf16_rne(xl_r[idx]);
    } else {
        int idx = (blk - 22528) * 256 + t;
        float v = agg_l[idx];
        cbias[idx] = (v > 0.0f) ? __logf(fmaxf(v, 1e-30f)) : -INF30;
    }
}

// ======== attn10: shuffle-free online softmax; epilogue emits Awh/Awl (unchanged) ========
#define PSTR 40
__global__ __launch_bounds__(256, 2) void attn10_kernel(
        const ushort_t* __restrict__ Qu_hi, const ushort_t* __restrict__ Qu_lo,
        const ushort_t* __restrict__ Qv_hi,
        const ushort_t* __restrict__ K_hi,  const ushort_t* __restrict__ K_lo,
        const ushort_t* __restrict__ C_hi,  const ushort_t* __restrict__ C_lo,
        const ushort_t* __restrict__ Vt_hi, const ushort_t* __restrict__ Vt_lo,
        const ushort_t* __restrict__ At_hi, const ushort_t* __restrict__ At_lo,
        const ushort_t* __restrict__ R_hi,
        const float* __restrict__ cbias, const float* __restrict__ gbuf,
        ushort_t* __restrict__ Awh, ushort_t* __restrict__ Awl) {
    __shared__ __align__(16) ushort_t KS[2][2][32 * 128];
    __shared__ __align__(16) ushort_t VS[2][2][128 * 32];
    __shared__ __align__(16) ushort_t Phs[4][16 * PSTR];
    __shared__ __align__(16) ushort_t Pls[4][16 * PSTR];

    int t = threadIdx.x;
    int wvid = t >> 6, ln = t & 63;
    int col = ln & 15, quad = ln >> 4;
    int blk = blockIdx.x;
    int xcd = blk & 7, idx = blk >> 3;
    int bh = ((idx >> 3) << 3) + xcd;
    int j = idx & 7;
    int jt = ((wvid & 1) ? (15 - j) : j) + ((wvid & 2) ? 16 : 0);
    int l0 = jt << 4;
    int h = bh & 7, b = bh >> 3;

    int nt2own = (l0 + 47) >> 5;
    int nt2max = (((31 - j) << 4) + 47) >> 5;
    int Tt = 32 + nt2max;

    size_t qb = ((size_t)bh * 512 + l0 + col) * 128 + quad * 8;
    bf16x8 quh[4], qul[4], qvf[4];
#pragma unroll
    for (int s = 0; s < 4; ++s) {
        quh[s] = ldb8(Qu_hi + qb + 32 * s);
        qul[s] = ldb8(Qu_lo + qb + 32 * s);
        qvf[s] = ldb8(Qv_hi + qb + 32 * s);
    }
    bf16x8 onesv;
#pragma unroll
    for (int i = 0; i < 8; ++i) onesv[i] = (short)0x3F80;

    f32x4 O[8];
#pragma unroll
    for (int u = 0; u < 8; ++u) O[u] = (f32x4){0.f, 0.f, 0.f, 0.f};
    f32x4 Oe = (f32x4){0.f, 0.f, 0.f, 0.f};
    float mrun[4];
#pragma unroll
    for (int r = 0; r < 4; ++r) mrun[r] = -INF30;

    ushort_t* Ph = Phs[wvid];
    ushort_t* Pl = Pls[wvid];

    {
        const ushort_t* nkh = K_hi + ((size_t)bh * 1024) * 128;
        const ushort_t* nkl = K_lo + ((size_t)bh * 1024) * 128;
#pragma unroll
        for (int m = 0; m < 2; ++m) {
            int r = wvid * 8 + m * 4 + (ln >> 4);
            int c = ln & 15;
            us8 vh8 = *(const us8*)(nkh + (size_t)r * 128 + c * 8);
            us8 vl8 = *(const us8*)(nkl + (size_t)r * 128 + c * 8);
            int dst = r * 128 + ((c ^ (r & 7)) << 3);
            *(us8*)&KS[0][0][dst] = vh8;
            *(us8*)&KS[0][1][dst] = vl8;
        }
        const ushort_t* vhp = Vt_hi + ((size_t)bh << 17);
        const ushort_t* vlp = Vt_lo + ((size_t)bh << 17);
#pragma unroll
        for (int m = 0; m < 2; ++m) {
            int dV = wvid * 128 + m * 64 + ln;
            int v = dV >> 2, c = dV & 3;
            us8 vh8 = *(const us8*)(vhp + (size_t)v * 1024 + c * 8);
            us8 vl8 = *(const us8*)(vlp + (size_t)v * 1024 + c * 8);
            int dst = v * 32 + ((c ^ ((v >> 1) & 3)) << 3);
            *(us8*)&VS[0][0][dst] = vh8;
            *(us8*)&VS[0][1][dst] = vl8;
        }
    }
    bf16x8 rg[3][4];
    {
        int jt0 = 496 - l0;
#pragma unroll
        for (int u = 0; u < 3; ++u) {
            int jr = jt0 + 16 * u + col;
            jr = (jr > 1023) ? 1023 : jr;
            const ushort_t* rp = R_hi + ((size_t)(h << 10) + jr) * 128 + quad * 8;
#pragma unroll
            for (int s = 0; s < 4; ++s) rg[u][s] = ldb8(rp + 32 * s);
        }
    }
    __syncthreads();
    int cur = 0;

    for (int ti = 0; ti < Tt; ++ti) {
        int seg, w0;
        if (ti < 16)      { seg = 0; w0 = ti << 5; }
        else if (ti < 32) { seg = 1; w0 = (ti - 16) << 5; }
        else              { seg = 2; w0 = (ti - 32) << 5; }
        bool act = (seg != 2) || ((ti - 32) < nt2own);

        int tn = ti + 1;
        bool hasNext = tn < Tt;
        int seg_n = 0, w0_n = 0;
        if (tn < 16)      { seg_n = 0; w0_n = tn << 5; }
        else if (tn < 32) { seg_n = 1; w0_n = (tn - 16) << 5; }
        else              { seg_n = 2; w0_n = (tn - 32) << 5; }
        bool act_n = hasNext && ((seg_n != 2) || ((tn - 32) < nt2own));

        us8 krh[2], krl[2], vrh[2], vrl[2];
        if (hasNext) {
            const ushort_t *nkh, *nkl;
            if (seg_n == 0)      { nkh = K_hi + ((size_t)bh * 1024 + w0_n) * 128;
                                   nkl = K_lo + ((size_t)bh * 1024 + w0_n) * 128; }
            else if (seg_n == 1) { nkh = C_hi + ((size_t)(h << 9) + w0_n) * 128;
                                   nkl = C_lo + ((size_t)(h << 9) + w0_n) * 128; }
            else                 { nkh = K_hi + ((size_t)bh * 1024 + 512 + w0_n) * 128;
                                   nkl = K_lo + ((size_t)bh * 1024 + 512 + w0_n) * 128; }
#pragma unroll
            for (int m = 0; m < 2; ++m) {
                int r = wvid * 8 + m * 4 + (ln >> 4);
                int c = ln & 15;
                krh[m] = *(const us8*)(nkh + (size_t)r * 128 + c * 8);
                krl[m] = *(const us8*)(nkl + (size_t)r * 128 + c * 8);
            }
            const ushort_t *vhp, *vlp; size_t vstr; int wbase;
            if (seg_n == 0)      { vhp = Vt_hi + ((size_t)bh << 17); vlp = Vt_lo + ((size_t)bh << 17); vstr = 1024; wbase = w0_n; }
            else if (seg_n == 1) { vhp = At_hi + ((size_t)bh << 16); vlp = At_lo + ((size_t)bh << 16); vstr = 512;  wbase = w0_n; }
            else                 { vhp = Vt_hi + ((size_t)bh << 17); vlp = Vt_lo + ((size_t)bh << 17); vstr = 1024; wbase = 512 + w0_n; }
#pragma unroll
            for (int m = 0; m < 2; ++m) {
                int dV = wvid * 128 + m * 64 + ln;
                int v = dV >> 2, c = dV & 3;
                vrh[m] = *(const us8*)(vhp + (size_t)v * vstr + wbase + c * 8);
                vrl[m] = *(const us8*)(vlp + (size_t)v * vstr + wbase + c * 8);
            }
        }

        f32x4 Gacc[3];
        f32x4 S[2];
        if (act && seg != 1) {
#pragma unroll
            for (int u = 0; u < 3; ++u) {
                f32x4 acc = (f32x4){0.f, 0.f, 0.f, 0.f};
                acc = MFMA16(qvf[0], rg[u][0], acc);
                acc = MFMA16(qvf[1], rg[u][1], acc);
                acc = MFMA16(qvf[2], rg[u][2], acc);
                acc = MFMA16(qvf[3], rg[u][3], acc);
                Gacc[u] = acc;
            }
        }

        if (act_n && seg_n != 1) {
            int jt0n = ((seg_n == 0) ? w0_n : (512 + w0_n)) + 496 - l0;
#pragma unroll
            for (int u = 0; u < 3; ++u) {
                int jr = jt0n + 16 * u + col;
                jr = (jr > 1023) ? 1023 : jr;
                const ushort_t* rp = R_hi + ((size_t)(h << 10) + jr) * 128 + quad * 8;
#pragma unroll
                for (int s = 0; s < 4; ++s) rg[u][s] = ldb8(rp + 32 * s);
            }
        }

        if (act) {
            S[0] = (f32x4){0.f, 0.f, 0.f, 0.f};
            S[1] = (f32x4){0.f, 0.f, 0.f, 0.f};
            const ushort_t* KH = KS[cur][0];
            const ushort_t* KL = KS[cur][1];
            int swz = col & 7;
            __builtin_amdgcn_s_setprio(1);
#pragma unroll
            for (int s = 0; s < 4; ++s) {
                int cofs = ((quad + 4 * s) ^ swz) << 3;
                bf16x8 k0h = *(const bf16x8*)&KH[col * 128 + cofs];
                bf16x8 k0l = *(const bf16x8*)&KL[col * 128 + cofs];
                bf16x8 k1h = *(const bf16x8*)&KH[(16 + col) * 128 + cofs];
                bf16x8 k1l = *(const bf16x8*)&KL[(16 + col) * 128 + cofs];
                S[0] = MFMA16(quh[s], k0h, S[0]);
                S[0] = MFMA16(qul[s], k0h, S[0]);
                S[0] = MFMA16(quh[s], k0l, S[0]);
                S[1] = MFMA16(quh[s], k1h, S[1]);
                S[1] = MFMA16(qul[s], k1h, S[1]);
                S[1] = MFMA16(quh[s], k1l, S[1]);
            }
            __builtin_amdgcn_s_setprio(0);
        }

        bf16x8 pah = {}, pal = {};
        if (act) {
            float bias0 = 0.f, bias1 = 0.f;
            if (seg == 1) {
                bias0 = cbias[(size_t)(bh << 9) + w0 + col];
                bias1 = cbias[(size_t)(bh << 9) + w0 + 16 + col];
            }
#pragma unroll
            for (int t2 = 0; t2 < 2; ++t2) {
#pragma unroll
                for (int r = 0; r < 4; ++r) {
                    int row = 4 * quad + r;
                    float sv = S[t2][r];
                    if (seg != 1) {
                        int d = col + 15 - row;
                        int src = quad * 16 + (d & 15);
                        float g0 = __shfl(Gacc[t2][r], src);
                        float g1 = __shfl(Gacc[t2 + 1][r], src);
                        float gv = (d >= 16) ? g1 : g0;
                        sv = (sv + gv) * INV_TAU;
                        if (seg == 2 && (w0 + 16 * t2 + col > l0 + row)) sv = -INF30;
                    } else {
                        sv = sv * INV_TAU + ((t2 == 0) ? bias0 : bias1);
                    }
                    S[t2][r] = sv;
                }
            }
            float mx[4];
            float need = -INF30;
#pragma unroll
            for (int r = 0; r < 4; ++r) {
                mx[r] = fmaxf(S[0][r], S[1][r]);
                need = fmaxf(need, mx[r] - mrun[r]);
            }
            if (__any(need > 8.0f)) {
#pragma unroll
                for (int r = 0; r < 4; ++r) {
                    float mv = mx[r];
#pragma unroll
                    for (int m = 8; m > 0; m >>= 1) mv = fmaxf(mv, __shfl_xor(mv, m));
                    float mnew = fmaxf(mrun[r], mv);
                    float alpha = __expf(mrun[r] - mnew);
                    mrun[r] = mnew;
                    Oe[r] *= alpha;
#pragma unroll
                    for (int u = 0; u < 8; ++u) O[u][r] *= alpha;
                }
            }
#pragma unroll
            for (int r = 0; r < 4; ++r) {
                float p0 = __expf(S[0][r] - mrun[r]);
                float p1 = __expf(S[1][r] - mrun[r]);
                int row = 4 * quad + r;
                unsigned short h0 = bf16_rne(p0);
                Ph[row * PSTR + col] = h0;
                Pl[row * PSTR + col] = bf16_rne(p0 - bf16_tof(h0));
                unsigned short h1 = bf16_rne(p1);
                Ph[row * PSTR + 16 + col] = h1;
                Pl[row * PSTR + 16 + col] = bf16_rne(p1 - bf16_tof(h1));
            }
            pah = *(const bf16x8*)&Ph[col * PSTR + quad * 8];
            pal = *(const bf16x8*)&Pl[col * PSTR + quad * 8];
        }

        if (act) {
            const ushort_t* VH = VS[cur][0];
            const ushort_t* VL = VS[cur][1];
            int vswz = (quad ^ ((col >> 1) & 3)) << 3;
            __builtin_amdgcn_s_setprio(1);
#pragma unroll
            for (int u = 0; u < 8; ++u) {
                int vrow = 16 * u + col;
                bf16x8 vbh = *(const bf16x8*)&VH[vrow * 32 + vswz];
                bf16x8 vbl = *(const bf16x8*)&VL[vrow * 32 + vswz];
                O[u] = MFMA16(pah, vbh, O[u]);
                O[u] = MFMA16(pal, vbh, O[u]);
                O[u] = MFMA16(pah, vbl, O[u]);
            }
            Oe = MFMA16(pah, onesv, Oe);
            Oe = MFMA16(pal, onesv, Oe);
            __builtin_amdgcn_s_setprio(0);
        }

        if (hasNext) {
#pragma unroll
            for (int m = 0; m < 2; ++m) {
                int r = wvid * 8 + m * 4 + (ln >> 4);
                int c = ln & 15;
                int dst = r * 128 + ((c ^ (r & 7)) << 3);
                *(us8*)&KS[cur ^ 1][0][dst] = krh[m];
                *(us8*)&KS[cur ^ 1][1][dst] = krl[m];
            }
#pragma unroll
            for (int m = 0; m < 2; ++m) {
                int dV = wvid * 128 + m * 64 + ln;
                int v = dV >> 2, c = dV & 3;
                int dst = v * 32 + ((c ^ ((v >> 1) & 3)) << 3);
                *(us8*)&VS[cur ^ 1][0][dst] = vrh[m];
                *(us8*)&VS[cur ^ 1][1][dst] = vrl[m];
            }
        }

        __syncthreads();
        cur ^= 1;
    }

#pragma unroll
    for (int r = 0; r < 4; ++r) {
        int row = quad * 4 + r;
        float linv = 1.0f / Oe[r];
#pragma unroll
        for (int u = 0; u < 8; ++u) {
            size_t gi = ((size_t)b * 512 + l0 + row) * 1024 + (h << 7) + 16 * u + col;
            float val = O[u][r] * linv * gbuf[gi];
            unsigned short hv = bf16_rne(val);
            Awh[gi] = hv;
            Awl[gi] = bf16_rne(val - bf16_tof(hv));
        }
    }
}

extern "C" void kernel_launch(void* const* d_in, const int* in_sizes, int n_in,
                              void* d_out, int out_size, void* d_ws, size_t ws_size,
                              hipStream_t stream) {
    const float* x_in  = (const float*)d_in[0];
    const float* xl_k  = (const float*)d_in[2];
    const float* xl_v  = (const float*)d_in[3];
    const float* agg_u = (const float*)d_in[4];
    const float* agg_l = (const float*)d_in[5];
    const float* W_q   = (const float*)d_in[6];
    const float* W_kvg = (const float*)d_in[7];
    const float* W_res = (const float*)d_in[8];
    const float* x_u   = (const float*)d_in[9];
    const float* x_v   = (const float*)d_in[10];
    const float* xl_r  = (const float*)d_in[11];
    const float* cbk   = (const float*)d_in[12];
    float* out = (float*)d_out;
    char* wb = (char*)d_ws;

    float*  x_t   = (float*)(wb);                       // 16 MB [alias: K_hi]
    float*  qbuf  = (float*)(wb + 16777216ul);          // 16 MB [alias: Vt_lo]
    float*  kbuf  = (float*)(wb + 33554432ul);          // 16 MB [alias: Vt_hi]
    float*  vbuf  = (float*)(wb + 50331648ul);          // 16 MB [alias: At_hi+At_lo]
    float*  gbuf  = (float*)(wb + 67108864ul);          // 16 MB
    float*  wvg   = (float*)(wb + 83886080ul);          // 16 MB [Ah+Al pre-attn; Awh+Awl post]
    float*  cT    = (float*)(wb + 100663296ul);         // 2 MB  [alias: C_hi+C_lo]
    float*  cnm   = (float*)(wb + 102760448ul);         // 16 KB
    ushort_t* Qu_hi = (ushort_t*)(wb + 102776832ul);    // 8 MB  [alias: Wtq pre-split]
    ushort_t* Qu_lo = (ushort_t*)(wb + 111165440ul);    // 8 MB  [alias: Wtvg pre-split]
    ushort_t* Qv_hi = (ushort_t*)(wb + 119554048ul);    // 8 MB  [alias: Wtres post-attn]
    ushort_t* K_lo  = (ushort_t*)(wb + 136331264ul);    // 16 MB
    ushort_t* R_hi  = (ushort_t*)(wb + 153108480ul);    // 2 MB
    float*  cbias   = (float*)(wb + 157302784ul);       // 128 KB

    ushort_t* K_hi  = (ushort_t*)x_t;
    ushort_t* Vt_hi = (ushort_t*)kbuf;
    ushort_t* Vt_lo = (ushort_t*)qbuf;
    ushort_t* At_hi = (ushort_t*)vbuf;
    ushort_t* At_lo = (ushort_t*)(wb + 50331648ul + 8388608ul);
    ushort_t* C_hi  = (ushort_t*)cT;
    ushort_t* C_lo  = (ushort_t*)(wb + 100663296ul + 1048576ul);

    ushort_t* Ah      = (ushort_t*)wvg;
    ushort_t* Al      = (ushort_t*)(wb + 83886080ul + 8388608ul);
    ushort_t* Awh     = (ushort_t*)wvg;
    ushort_t* Awl     = (ushort_t*)(wb + 83886080ul + 8388608ul);
    ushort_t* Wtq_hi  = (ushort_t*)Qu_hi;
    ushort_t* Wtq_lo  = (ushort_t*)(wb + 102776832ul + 2097152ul);
    ushort_t* Wtvg_hi = (ushort_t*)Qu_lo;
    ushort_t* Wtvg_lo = (ushort_t*)(wb + 111165440ul + 4194304ul);
    ushort_t* Wtres_hi = (ushort_t*)Qv_hi;
    ushort_t* Wtres_lo = (ushort_t*)(wb + 119554048ul + 2097152ul);

    // 1) input LN with fused bf16 split
    ln_dm_kernel<<<4096, 256, 0, stream>>>(x_in, x_t, Ah, Al);
    // 2) merged weight splits (W_q + W_kvg)
    wtsplit_dual_kernel<<<dim3(48, 16), 256, 0, stream>>>(W_q, W_kvg, Wtq_hi, Wtq_lo, Wtvg_hi, Wtvg_lo);
    // 3) projections (double-buffered single-barrier pipelines)
    gemm_bf16_kernel<<<dim3(16, 32), 256, 0, stream>>>(Ah, Al, Wtq_hi, Wtq_lo, 0, qbuf, nullptr);
    gemm_bf16_kernel<<<dim3(32, 32), 256, 0, stream>>>(Ah, Al, Wtvg_hi, Wtvg_lo, 1, vbuf, gbuf);
    gemm_kernel<<<dim3(16, 32), 256, 0, stream>>>(x_t, W_kvg, 3072, 0, kbuf, nullptr, nullptr);
    // 4) codebook prep + VQ (LN(k) fused, K split emitted in place)
    cbtn_kernel<<<1024, 256, 0, stream>>>(cbk, cT, cnm);
    vq_kernel<<<2048, 256, 0, stream>>>(kbuf, cT, cnm, cbk, K_hi, K_lo);
    // 5) attention preps
    ln_split_q_kernel<<<8192, 256, 0, stream>>>(qbuf, x_u, x_v, Qu_hi, Qu_lo, Qv_hi);
    vtsplit_kernel<<<dim3(64, 16), 256, 0, stream>>>(xl_v, vbuf, Vt_hi, Vt_lo, 1024);
    vtsplit_kernel<<<dim3(64, 8), 256, 0, stream>>>(agg_u, agg_u, At_hi, At_lo, 512);
    prep_misc_kernel<<<22656, 256, 0, stream>>>(xl_k, K_hi, K_lo, cbk, C_hi, C_lo,
                                                xl_r, R_hi, agg_l, cbias);
    // 6) fused attention (epilogue emits Awh/Awl for the output GEMM)
    attn10_kernel<<<512, 256, 0, stream>>>(Qu_hi, Qu_lo, Qv_hi, K_hi, K_lo, C_hi, C_lo,
                                           Vt_hi, Vt_lo, At_hi, At_lo, R_hi,
                                           cbias, gbuf, Awh, Awl);
    // 7) output projection
    wtsplit_kernel<<<dim3(16, 16), 256, 0, stream>>>(W_res, 1024, 0, Wtres_hi, Wtres_lo);
    gemm_bf16_kernel<<<dim3(16, 32), 256, 0, stream>>>(Awh, Awl, Wtres_hi, Wtres_lo, 2, out, nullptr);
}